// Round 2
// baseline (561.009 us; speedup 1.0000x reference)
//
#include <hip/hip_runtime.h>
#include <hip/hip_bf16.h>
#include <cstdint>

#define B_ 8
#define N_ 256
#define CS_ 512
#define H_ 8
#define D_ 64
#define K_ 32
#define NB_ 65
#define CT_ 2048
#define WL_ 0.70710678118654752f

// ---------------- block-wide reductions (256 threads = 4 waves of 64) ------
__device__ __forceinline__ float blockReduceSum(float v, float* red) {
#pragma unroll
  for (int o = 32; o > 0; o >>= 1) v += __shfl_xor(v, o, 64);
  int w = threadIdx.x >> 6;
  __syncthreads();                      // protect red[] from previous use
  if ((threadIdx.x & 63) == 0) red[w] = v;
  __syncthreads();
  return red[0] + red[1] + red[2] + red[3];
}

__device__ __forceinline__ float blockReduceMax(float v, float* red) {
#pragma unroll
  for (int o = 32; o > 0; o >>= 1) v = fmaxf(v, __shfl_xor(v, o, 64));
  int w = threadIdx.x >> 6;
  __syncthreads();
  if ((threadIdx.x & 63) == 0) red[w] = v;
  __syncthreads();
  return fmaxf(fmaxf(red[0], red[1]), fmaxf(red[2], red[3]));
}

// ---------------- generic tiled f32 GEMM: C[M,N] = A[M,K]@B[K,N] ----------
// flags: bit0 = add bias[col], bit1 = relu.  M%64==0, N%64==0, K%16==0.
__global__ __launch_bounds__(256) void gemm_f32(
    const float* __restrict__ A, const float* __restrict__ Bm,
    const float* __restrict__ bias, float* __restrict__ C,
    int M, int Nc, int Kd, int flags) {
  __shared__ float As[16][64];   // As[k][m]
  __shared__ float Bs[16][64];   // Bs[k][n]
  int tid = threadIdx.x;
  int bm = blockIdx.y * 64, bn = blockIdx.x * 64;
  int trow = (tid >> 4) << 2, tcol = (tid & 15) << 2;
  int arow = tid >> 2, ac4 = (tid & 3) << 2;
  int brow = tid >> 4, bc4 = (tid & 15) << 2;
  float acc[4][4] = {};
  for (int k0 = 0; k0 < Kd; k0 += 16) {
    float4 av = *(const float4*)(A + (size_t)(bm + arow) * Kd + k0 + ac4);
    float4 bv = *(const float4*)(Bm + (size_t)(k0 + brow) * Nc + bn + bc4);
    __syncthreads();   // previous iteration's reads done before overwrite
    As[ac4 + 0][arow] = av.x; As[ac4 + 1][arow] = av.y;
    As[ac4 + 2][arow] = av.z; As[ac4 + 3][arow] = av.w;
    *(float4*)&Bs[brow][bc4] = bv;
    __syncthreads();
#pragma unroll
    for (int k = 0; k < 16; ++k) {
      float4 a4 = *(const float4*)&As[k][trow];
      float4 b4 = *(const float4*)&Bs[k][tcol];
      float ar[4] = {a4.x, a4.y, a4.z, a4.w};
      float br[4] = {b4.x, b4.y, b4.z, b4.w};
#pragma unroll
      for (int i = 0; i < 4; ++i)
#pragma unroll
        for (int j = 0; j < 4; ++j) acc[i][j] += ar[i] * br[j];
    }
  }
  for (int i = 0; i < 4; ++i) {
    float vals[4];
#pragma unroll
    for (int j = 0; j < 4; ++j) {
      float v = acc[i][j];
      if (flags & 1) v += bias[bn + tcol + j];
      if (flags & 2) v = fmaxf(v, 0.f);
      vals[j] = v;
    }
    *(float4*)(C + (size_t)(bm + trow + i) * Nc + bn + tcol) = *(float4*)vals;
  }
}

// ---------------- [B,N,D*H] -> [B,H,N,D], col = d*H+h --------------------
__global__ __launch_bounds__(256) void reshape_qkv(
    const float* __restrict__ qp, const float* __restrict__ kp,
    const float* __restrict__ vp, float* __restrict__ qh,
    float* __restrict__ kh, float* __restrict__ vh) {
  int idx = blockIdx.x * 256 + threadIdx.x;   // [0, 1<<20)
  const float* src; float* dst;
  if (blockIdx.y == 0)      { src = qp; dst = qh; }
  else if (blockIdx.y == 1) { src = kp; dst = kh; }
  else                      { src = vp; dst = vh; }
  int d = idx & 63, n = (idx >> 6) & 255, h = (idx >> 14) & 7, b = idx >> 17;
  dst[idx] = src[(size_t)(b * 256 + n) * 512 + d * 8 + h];
}

// ---------------- attention: logits + softmax + a + o_pair ----------------
// grid = B*H*(N/64) blocks of 256 threads; thread j owns column j.
// masks arrive as int32 (harness converts integer/bool inputs to int).
__global__ __launch_bounds__(256) void attn_kernel(
    const float* __restrict__ qh, const float* __restrict__ kh,
    const int* __restrict__ masks, const float* __restrict__ wb,
    float* __restrict__ a_out, float* __restrict__ opair) {
  int blk = blockIdx.x;
  int it = blk & 3, bh = blk >> 2;
  int h = bh & 7, b = bh >> 3;
  int i0 = it * 64;
  __shared__ float Qs[64][64];
  __shared__ float red[4];
  __shared__ float op_row[NB_];
  int tid = threadIdx.x;
  // thread j keeps K row j in registers (64 VGPRs)
  float kreg[64];
  const float* krow = kh + ((size_t)bh * N_ + tid) * D_;
#pragma unroll
  for (int d4 = 0; d4 < 16; ++d4) {
    float4 v = *(const float4*)(krow + d4 * 4);
    kreg[d4 * 4 + 0] = v.x; kreg[d4 * 4 + 1] = v.y;
    kreg[d4 * 4 + 2] = v.z; kreg[d4 * 4 + 3] = v.w;
  }
  const float* qbase = qh + ((size_t)bh * N_ + i0) * D_;
  for (int idx = tid; idx < 64 * 16; idx += 256) {
    int row = idx >> 4, c4 = (idx & 15) << 2;
    *(float4*)&Qs[row][c4] = *(const float4*)(qbase + row * 64 + c4);
  }
  __syncthreads();
  int j = tid;
  float mf_j = (masks[b * N_ + j] != 0) ? 1.f : 0.f;
  for (int ii = 0; ii < 64; ++ii) {
    int i = i0 + ii;
    float mf_i = (masks[b * N_ + i] != 0) ? 1.f : 0.f;
    float dot = 0.f;
#pragma unroll
    for (int d4 = 0; d4 < 16; ++d4) {
      float4 q4 = *(const float4*)&Qs[ii][d4 * 4];
      dot += q4.x * kreg[d4 * 4 + 0] + q4.y * kreg[d4 * 4 + 1] +
             q4.z * kreg[d4 * 4 + 2] + q4.w * kreg[d4 * 4 + 3];
    }
    int diff = i - j;
    int cb = diff; if (cb < -K_) cb = -K_; if (cb > K_) cb = K_; cb += K_;
    float sq = mf_i * mf_j;
    float l = WL_ * (dot * 0.125f + wb[cb * H_ + h] * sq) - 1e9f * (1.f - sq);
    float mx = blockReduceMax(l, red);
    float e = __expf(l - mx);
    float s = blockReduceSum(e, red);
    float a = e / s;
    a_out[((size_t)bh * N_ + i) * N_ + j] = a;
    // o_pair row: interior bins are unique j; bins 0 and 2K are masked sums
    float val = a * sq;
    if (tid < NB_) op_row[tid] = 0.f;
    __syncthreads();
    if (diff > -K_ && diff < K_) op_row[cb] = val;
    float s0  = blockReduceSum(diff <= -K_ ? val : 0.f, red);
    float s64 = blockReduceSum(diff >=  K_ ? val : 0.f, red);
    if (tid == 0) { op_row[0] = s0; op_row[2 * K_] = s64; }
    __syncthreads();
    if (tid < NB_) opair[((size_t)bh * N_ + i) * NB_ + tid] = op_row[tid];
    __syncthreads();
  }
}

// ---------------- o[b,h,i,d] = sum_j a[b,h,i,j] * v[b,h,j,d] --------------
__global__ __launch_bounds__(256) void av_kernel(
    const float* __restrict__ a, const float* __restrict__ vh,
    float* __restrict__ o) {
  int bh = blockIdx.x;
  int i0 = blockIdx.y * 16;
  __shared__ float As[16][260];
  int tid = threadIdx.x;
  const float* abase = a + ((size_t)bh * N_ + i0) * N_;
  for (int idx = tid; idx < 16 * 64; idx += 256) {
    int r = idx >> 6, c4 = (idx & 63) << 2;
    *(float4*)&As[r][c4] = *(const float4*)(abase + r * N_ + c4);
  }
  __syncthreads();
  int d = tid & 63, ig = tid >> 6;
  const float* vbase = vh + (size_t)bh * N_ * D_ + d;
  float acc[4] = {0.f, 0.f, 0.f, 0.f};
  for (int jj = 0; jj < N_; ++jj) {
    float vv = vbase[jj * D_];
#pragma unroll
    for (int r = 0; r < 4; ++r) acc[r] += As[ig * 4 + r][jj] * vv;
  }
  for (int r = 0; r < 4; ++r)
    o[((size_t)bh * N_ + i0 + ig * 4 + r) * D_ + d] = acc[r];
}

// ---------------- pad wo [1032,512] -> [1040,512] (zeros) -----------------
__global__ void pad_wo(const float* __restrict__ wo, float* __restrict__ wop) {
  int idx = blockIdx.x * 256 + threadIdx.x;
  if (idx >= 1040 * 512) return;
  int r = idx >> 9;
  wop[idx] = (r < 1032) ? wo[idx] : 0.f;
}

// ---------------- pack concat([op, ov]) into [2048, 1040] -----------------
__global__ void pack_cat(const float* __restrict__ opair,
                         const float* __restrict__ o, float* __restrict__ cat) {
  int idx = blockIdx.x * 256 + threadIdx.x;
  if (idx >= 2048 * 1040) return;
  int m = idx / 1040, kk = idx - m * 1040;
  int b = m >> 8, n = m & 255;
  float v = 0.f;
  if (kk < 520) {
    int h = kk / 65, c = kk - h * 65;
    v = opair[(((size_t)(b * 8 + h) * 256) + n) * 65 + c];
  } else if (kk < 1032) {
    int k2 = kk - 520;
    int h = k2 >> 6, d = k2 & 63;
    v = o[(((size_t)(b * 8 + h) * 256) + n) * 64 + d];
  }
  cat[idx] = v;
}

// ---------------- out = LayerNorm(x1 + x2) * g + b ------------------------
__global__ __launch_bounds__(256) void ln_kernel(
    const float* __restrict__ x1, const float* __restrict__ x2,
    const float* __restrict__ g, const float* __restrict__ bta,
    float* __restrict__ out) {
  __shared__ float red[4];
  int row = blockIdx.x, tid = threadIdx.x;
  const float* p1 = x1 + (size_t)row * 512;
  const float* p2 = x2 + (size_t)row * 512;
  float v0 = p1[tid] + p2[tid];
  float v1 = p1[tid + 256] + p2[tid + 256];
  float s  = blockReduceSum(v0 + v1, red);
  float sq = blockReduceSum(v0 * v0 + v1 * v1, red);
  float mean = s * (1.f / 512.f);
  float var = sq * (1.f / 512.f) - mean * mean;
  float inv = rsqrtf(var + 1e-5f);
  out[(size_t)row * 512 + tid]       = (v0 - mean) * inv * g[tid] + bta[tid];
  out[(size_t)row * 512 + tid + 256] = (v1 - mean) * inv * g[tid + 256] + bta[tid + 256];
}

extern "C" void kernel_launch(void* const* d_in, const int* in_sizes, int n_in,
                              void* d_out, int out_size, void* d_ws, size_t ws_size,
                              hipStream_t stream) {
  const float* s     = (const float*)d_in[0];
  const int*   masks = (const int*)d_in[1];   // bool input delivered as int32
  const float* wq = (const float*)d_in[2];
  const float* wk = (const float*)d_in[3];
  const float* wv = (const float*)d_in[4];
  const float* wb = (const float*)d_in[5];
  const float* wo = (const float*)d_in[6];
  const float* bo = (const float*)d_in[7];
  const float* ln1_g = (const float*)d_in[8];
  const float* ln1_b = (const float*)d_in[9];
  const float* w1 = (const float*)d_in[10];
  const float* b1 = (const float*)d_in[11];
  const float* w2 = (const float*)d_in[12];
  const float* b2 = (const float*)d_in[13];
  const float* ln2_g = (const float*)d_in[14];
  const float* ln2_b = (const float*)d_in[15];

  float* out_x = (float*)d_out;              // [8,256,512]  = 1,048,576
  float* out_a = out_x + 1048576;            // [8,8,256,256] = 4,194,304

  // workspace layout (floats), regions reused across phases:
  float* ws    = (float*)d_ws;
  float* qp    = ws + 0;         // phase A   (dead after reshape)
  float* kp    = ws + 1048576;
  float* vp    = ws + 2097152;
  float* qhb   = ws + 3145728;   // dead after attn
  float* khb   = ws + 4194304;   // dead after attn
  float* vhb   = ws + 5242880;   // dead after av
  float* opair = ws + 6291456;   // 1,064,960
  float* obuf  = ws + 7356416;   // 1,048,576
  float* hbuf  = ws + 8404992;   // 4,194,304  (FFN hidden)
  float* cat   = ws + 0;         // reuse qp/kp/vp region: 2,129,920
  float* wop   = ws + 2129920;   // 532,480 (still inside old qp..vp)
  float* embd  = ws + 3145728;   // reuse qhb
  float* xbuf  = ws + 4194304;   // reuse khb
  float* ff    = ws + 5242880;   // reuse vhb

  dim3 blk(256);
  // 1. QKV projections  [2048,512] @ [512,512]
  gemm_f32<<<dim3(8, 32), blk, 0, stream>>>(s, wq, nullptr, qp, 2048, 512, 512, 0);
  gemm_f32<<<dim3(8, 32), blk, 0, stream>>>(s, wk, nullptr, kp, 2048, 512, 512, 0);
  gemm_f32<<<dim3(8, 32), blk, 0, stream>>>(s, wv, nullptr, vp, 2048, 512, 512, 0);
  // 2. head layout [B,H,N,D]
  reshape_qkv<<<dim3(4096, 3), blk, 0, stream>>>(qp, kp, vp, qhb, khb, vhb);
  // 3. logits + softmax -> a (straight into d_out), o_pair
  attn_kernel<<<dim3(256), blk, 0, stream>>>(qhb, khb, masks, wb, out_a, opair);
  // 4. o = a @ v
  av_kernel<<<dim3(64, 16), blk, 0, stream>>>(out_a, vhb, obuf);
  // 5. pack concat + padded wo, then output projection (+bo)
  pad_wo<<<dim3((1040 * 512 + 255) / 256), blk, 0, stream>>>(wo, wop);
  pack_cat<<<dim3((2048 * 1040 + 255) / 256), blk, 0, stream>>>(opair, obuf, cat);
  gemm_f32<<<dim3(8, 32), blk, 0, stream>>>(cat, wop, bo, embd, 2048, 512, 1040, 1);
  // 6. x = LN(s + embd)
  ln_kernel<<<dim3(2048), blk, 0, stream>>>(s, embd, ln1_g, ln1_b, xbuf);
  // 7. FFN
  gemm_f32<<<dim3(32, 32), blk, 0, stream>>>(xbuf, w1, b1, hbuf, 2048, 2048, 512, 3);
  gemm_f32<<<dim3(8, 32), blk, 0, stream>>>(hbuf, w2, b2, ff, 2048, 512, 2048, 1);
  // 8. out = LN(x + ff)
  ln_kernel<<<dim3(2048), blk, 0, stream>>>(xbuf, ff, ln2_g, ln2_b, out_x);
}

// Round 3
// 363.305 us; speedup vs baseline: 1.5442x; 1.5442x over previous
//
#include <hip/hip_runtime.h>
#include <hip/hip_bf16.h>
#include <cstdint>

#define B_ 8
#define N_ 256
#define CS_ 512
#define H_ 8
#define D_ 64
#define K_ 32
#define NB_ 65
#define CT_ 2048
#define WL_ 0.70710678118654752f

typedef __attribute__((ext_vector_type(8))) short bf16x8;
typedef __attribute__((ext_vector_type(4))) float f32x4;

#define GLOBAL_AS __attribute__((address_space(1)))
#define LDS_AS __attribute__((address_space(3)))

__device__ __forceinline__ void async16(void* lds, const void* g) {
  __builtin_amdgcn_global_load_lds((const GLOBAL_AS uint32_t*)g,
                                   (LDS_AS uint32_t*)lds, 16, 0, 0);
}

// ---------------- block-wide reductions (256 threads = 4 waves of 64) ------
__device__ __forceinline__ float blockReduceSum(float v, float* red) {
#pragma unroll
  for (int o = 32; o > 0; o >>= 1) v += __shfl_xor(v, o, 64);
  int w = threadIdx.x >> 6;
  __syncthreads();
  if ((threadIdx.x & 63) == 0) red[w] = v;
  __syncthreads();
  return red[0] + red[1] + red[2] + red[3];
}

__device__ __forceinline__ float blockReduceMax(float v, float* red) {
#pragma unroll
  for (int o = 32; o > 0; o >>= 1) v = fmaxf(v, __shfl_xor(v, o, 64));
  int w = threadIdx.x >> 6;
  __syncthreads();
  if ((threadIdx.x & 63) == 0) red[w] = v;
  __syncthreads();
  return fmaxf(fmaxf(red[0], red[1]), fmaxf(red[2], red[3]));
}

// ---------------- bf16 MFMA GEMM: C[M,N] = A[M,K] @ Bt[N,K]^T -------------
// A,Bt bf16 row-major. 128x128 tile, BK=64, mfma 16x16x32.
// flags: 1=+bias[col], 2=relu, 4=write bf16 Cb, 8=write f32 C.
// M%128==0, N%128==0, K%64==0. XOR-swizzled LDS (granule ^= row&7).
__global__ __launch_bounds__(256) void gemm_bf16(
    const ushort* __restrict__ A, const ushort* __restrict__ Bt,
    const float* __restrict__ bias, float* __restrict__ C,
    ushort* __restrict__ Cb, int M, int Nc, int Kd, int flags) {
  __shared__ ushort As[128 * 64];
  __shared__ ushort Bs[128 * 64];
  int tid = threadIdx.x;
  int bm = blockIdx.y * 128, bn = blockIdx.x * 128;
  int w = tid >> 6, l = tid & 63;
  int wr = (w >> 1) * 64, wc = (w & 1) * 64;   // wave's 64x64 quadrant
  int lm = l & 15, lq = l >> 4;
  int srow = tid >> 3;        // 0..31: row within staging round
  int sg = tid & 7;           // physical granule (16B) within row

  f32x4 acc[4][4];
#pragma unroll
  for (int i = 0; i < 4; ++i)
#pragma unroll
    for (int j = 0; j < 4; ++j) acc[i][j] = (f32x4){0.f, 0.f, 0.f, 0.f};

  for (int k0 = 0; k0 < Kd; k0 += 64) {
    __syncthreads();   // all waves done reading previous tile
#pragma unroll
    for (int r = 0; r < 4; ++r) {
      int row = r * 32 + srow;
      int gl = sg ^ (row & 7);   // source granule so physical slot sg holds it
      async16(&As[row * 64 + sg * 8],
              A + (size_t)(bm + row) * Kd + k0 + gl * 8);
      async16(&Bs[row * 64 + sg * 8],
              Bt + (size_t)(bn + row) * Kd + k0 + gl * 8);
    }
    __syncthreads();   // vmcnt(0) drain + barrier: tile visible
#pragma unroll
    for (int kk = 0; kk < 2; ++kk) {
      bf16x8 af[4], bfr[4];
#pragma unroll
      for (int i = 0; i < 4; ++i) {
        int ma = wr + 16 * i + lm;
        af[i] = *(const bf16x8*)&As[ma * 64 + ((kk * 4 + lq) ^ (ma & 7)) * 8];
        int nb = wc + 16 * i + lm;
        bfr[i] = *(const bf16x8*)&Bs[nb * 64 + ((kk * 4 + lq) ^ (nb & 7)) * 8];
      }
#pragma unroll
      for (int i = 0; i < 4; ++i)
#pragma unroll
        for (int j = 0; j < 4; ++j)
          acc[i][j] = __builtin_amdgcn_mfma_f32_16x16x32_bf16(
              af[i], bfr[j], acc[i][j], 0, 0, 0);
    }
  }
  // epilogue: C/D layout col=lane&15, row=(lane>>4)*4+reg
#pragma unroll
  for (int j = 0; j < 4; ++j) {
    int col = bn + wc + 16 * j + lm;
    float bv = (flags & 1) ? bias[col] : 0.f;
#pragma unroll
    for (int i = 0; i < 4; ++i) {
#pragma unroll
      for (int r = 0; r < 4; ++r) {
        int row = bm + wr + 16 * i + lq * 4 + r;
        float v = acc[i][j][r] + bv;
        if (flags & 2) v = fmaxf(v, 0.f);
        if (flags & 8) C[(size_t)row * Nc + col] = v;
        if (flags & 4) {
          __hip_bfloat16 hb = __float2bfloat16(v);
          Cb[(size_t)row * Nc + col] = *(ushort*)&hb;
        }
      }
    }
  }
}

// ---------------- transpose+convert: dst[c][k] = (k<R)? src[k][c] : 0 -----
// src f32 [R,C]; dst bf16 [C,Kpad]. grid (ceil(C/32), ceil(Kpad/32)), 256 thr.
__global__ __launch_bounds__(256) void transpose_cvt(
    const float* __restrict__ src, __hip_bfloat16* __restrict__ dst,
    int R, int C, int Kpad) {
  __shared__ float tile[32][33];
  int c0 = blockIdx.x * 32, r0 = blockIdx.y * 32;
  int tx = threadIdx.x & 31, ty = threadIdx.x >> 5;  // 32x8
#pragma unroll
  for (int yy = 0; yy < 32; yy += 8) {
    int r = r0 + ty + yy, c = c0 + tx;
    tile[ty + yy][tx] = (r < R && c < C) ? src[(size_t)r * C + c] : 0.f;
  }
  __syncthreads();
#pragma unroll
  for (int yy = 0; yy < 32; yy += 8) {
    int cc = c0 + ty + yy, k = r0 + tx;
    if (cc < C && k < Kpad)
      dst[(size_t)cc * Kpad + k] = __float2bfloat16(tile[tx][ty + yy]);
  }
}

// ---------------- f32 -> bf16 elementwise (n divisible by 4) --------------
__global__ void cvt_bf16(const float* __restrict__ src,
                         __hip_bfloat16* __restrict__ dst, int n4) {
  int i = blockIdx.x * 256 + threadIdx.x;
  if (i >= n4) return;
  float4 v = ((const float4*)src)[i];
  dst[i * 4 + 0] = __float2bfloat16(v.x);
  dst[i * 4 + 1] = __float2bfloat16(v.y);
  dst[i * 4 + 2] = __float2bfloat16(v.z);
  dst[i * 4 + 3] = __float2bfloat16(v.w);
}

// ---------------- [B,N,1536] qkv -> [B,H,N,D] x3, col=base+d*8+h ----------
__global__ __launch_bounds__(256) void reshape_qkv(
    const float* __restrict__ qkv, float* __restrict__ qh,
    float* __restrict__ kh, float* __restrict__ vh) {
  int idx = blockIdx.x * 256 + threadIdx.x;   // [0, 1<<20)
  float* dst;
  int base = blockIdx.y * 512;
  if (blockIdx.y == 0)      dst = qh;
  else if (blockIdx.y == 1) dst = kh;
  else                      dst = vh;
  int d = idx & 63, n = (idx >> 6) & 255, h = (idx >> 14) & 7, b = idx >> 17;
  dst[idx] = qkv[(size_t)(b * 256 + n) * 1536 + base + d * 8 + h];
}

// ---------------- attention: logits + softmax + a + o_pair ----------------
__global__ __launch_bounds__(256) void attn_kernel(
    const float* __restrict__ qh, const float* __restrict__ kh,
    const int* __restrict__ masks, const float* __restrict__ wb,
    float* __restrict__ a_out, float* __restrict__ opair) {
  int blk = blockIdx.x;
  int it = blk & 3, bh = blk >> 2;
  int h = bh & 7, b = bh >> 3;
  int i0 = it * 64;
  __shared__ float Qs[64][64];
  __shared__ float red[4];
  __shared__ float op_row[NB_];
  int tid = threadIdx.x;
  float kreg[64];
  const float* krow = kh + ((size_t)bh * N_ + tid) * D_;
#pragma unroll
  for (int d4 = 0; d4 < 16; ++d4) {
    float4 v = *(const float4*)(krow + d4 * 4);
    kreg[d4 * 4 + 0] = v.x; kreg[d4 * 4 + 1] = v.y;
    kreg[d4 * 4 + 2] = v.z; kreg[d4 * 4 + 3] = v.w;
  }
  const float* qbase = qh + ((size_t)bh * N_ + i0) * D_;
  for (int idx = tid; idx < 64 * 16; idx += 256) {
    int row = idx >> 4, c4 = (idx & 15) << 2;
    *(float4*)&Qs[row][c4] = *(const float4*)(qbase + row * 64 + c4);
  }
  __syncthreads();
  int j = tid;
  float mf_j = (masks[b * N_ + j] != 0) ? 1.f : 0.f;
  for (int ii = 0; ii < 64; ++ii) {
    int i = i0 + ii;
    float mf_i = (masks[b * N_ + i] != 0) ? 1.f : 0.f;
    float dot = 0.f;
#pragma unroll
    for (int d4 = 0; d4 < 16; ++d4) {
      float4 q4 = *(const float4*)&Qs[ii][d4 * 4];
      dot += q4.x * kreg[d4 * 4 + 0] + q4.y * kreg[d4 * 4 + 1] +
             q4.z * kreg[d4 * 4 + 2] + q4.w * kreg[d4 * 4 + 3];
    }
    int diff = i - j;
    int cb = diff; if (cb < -K_) cb = -K_; if (cb > K_) cb = K_; cb += K_;
    float sq = mf_i * mf_j;
    float l = WL_ * (dot * 0.125f + wb[cb * H_ + h] * sq) - 1e9f * (1.f - sq);
    float mx = blockReduceMax(l, red);
    float e = __expf(l - mx);
    float s = blockReduceSum(e, red);
    float a = e / s;
    a_out[((size_t)bh * N_ + i) * N_ + j] = a;
    float val = a * sq;
    if (tid < NB_) op_row[tid] = 0.f;
    __syncthreads();
    if (diff > -K_ && diff < K_) op_row[cb] = val;
    float s0  = blockReduceSum(diff <= -K_ ? val : 0.f, red);
    float s64 = blockReduceSum(diff >=  K_ ? val : 0.f, red);
    if (tid == 0) { op_row[0] = s0; op_row[2 * K_] = s64; }
    __syncthreads();
    if (tid < NB_) opair[((size_t)bh * N_ + i) * NB_ + tid] = op_row[tid];
    __syncthreads();
  }
}

// ---------------- o[b,h,i,d] = sum_j a[b,h,i,j] * v[b,h,j,d] --------------
__global__ __launch_bounds__(256) void av_kernel(
    const float* __restrict__ a, const float* __restrict__ vh,
    float* __restrict__ o) {
  int bh = blockIdx.x;
  int i0 = blockIdx.y * 16;
  __shared__ float As[16][260];
  int tid = threadIdx.x;
  const float* abase = a + ((size_t)bh * N_ + i0) * N_;
  for (int idx = tid; idx < 16 * 64; idx += 256) {
    int r = idx >> 6, c4 = (idx & 63) << 2;
    *(float4*)&As[r][c4] = *(const float4*)(abase + r * N_ + c4);
  }
  __syncthreads();
  int d = tid & 63, ig = tid >> 6;
  const float* vbase = vh + (size_t)bh * N_ * D_ + d;
  float acc[4] = {0.f, 0.f, 0.f, 0.f};
  for (int jj = 0; jj < N_; ++jj) {
    float vv = vbase[jj * D_];
#pragma unroll
    for (int r = 0; r < 4; ++r) acc[r] += As[ig * 4 + r][jj] * vv;
  }
  for (int r = 0; r < 4; ++r)
    o[((size_t)bh * N_ + i0 + ig * 4 + r) * D_ + d] = acc[r];
}

// ---------------- pack concat([op, ov]) -> bf16 [2048, 1088] --------------
__global__ void pack_cat(const float* __restrict__ opair,
                         const float* __restrict__ o,
                         __hip_bfloat16* __restrict__ cat) {
  int idx = blockIdx.x * 256 + threadIdx.x;
  if (idx >= 2048 * 1088) return;
  int m = idx / 1088, kk = idx - m * 1088;
  int b = m >> 8, n = m & 255;
  float v = 0.f;
  if (kk < 520) {
    int h = kk / 65, c = kk - h * 65;
    v = opair[(((size_t)(b * 8 + h) * 256) + n) * 65 + c];
  } else if (kk < 1032) {
    int k2 = kk - 520;
    int h = k2 >> 6, d = k2 & 63;
    v = o[(((size_t)(b * 8 + h) * 256) + n) * 64 + d];
  }
  cat[idx] = __float2bfloat16(v);
}

// ---------------- out = LayerNorm(x1 + x2) * g + b  (+opt bf16 copy) ------
__global__ __launch_bounds__(256) void ln_kernel(
    const float* __restrict__ x1, const float* __restrict__ x2,
    const float* __restrict__ g, const float* __restrict__ bta,
    float* __restrict__ out, __hip_bfloat16* __restrict__ out_bf) {
  __shared__ float red[4];
  int row = blockIdx.x, tid = threadIdx.x;
  const float* p1 = x1 + (size_t)row * 512;
  const float* p2 = x2 + (size_t)row * 512;
  float v0 = p1[tid] + p2[tid];
  float v1 = p1[tid + 256] + p2[tid + 256];
  float s  = blockReduceSum(v0 + v1, red);
  float sq = blockReduceSum(v0 * v0 + v1 * v1, red);
  float mean = s * (1.f / 512.f);
  float var = sq * (1.f / 512.f) - mean * mean;
  float inv = rsqrtf(var + 1e-5f);
  float o0 = (v0 - mean) * inv * g[tid] + bta[tid];
  float o1 = (v1 - mean) * inv * g[tid + 256] + bta[tid + 256];
  out[(size_t)row * 512 + tid]       = o0;
  out[(size_t)row * 512 + tid + 256] = o1;
  if (out_bf) {
    out_bf[(size_t)row * 512 + tid]       = __float2bfloat16(o0);
    out_bf[(size_t)row * 512 + tid + 256] = __float2bfloat16(o1);
  }
}

extern "C" void kernel_launch(void* const* d_in, const int* in_sizes, int n_in,
                              void* d_out, int out_size, void* d_ws, size_t ws_size,
                              hipStream_t stream) {
  const float* s     = (const float*)d_in[0];
  const int*   masks = (const int*)d_in[1];
  const float* wq = (const float*)d_in[2];
  const float* wk = (const float*)d_in[3];
  const float* wv = (const float*)d_in[4];
  const float* wb = (const float*)d_in[5];
  const float* wo = (const float*)d_in[6];
  const float* bo = (const float*)d_in[7];
  const float* ln1_g = (const float*)d_in[8];
  const float* ln1_b = (const float*)d_in[9];
  const float* w1 = (const float*)d_in[10];
  const float* b1 = (const float*)d_in[11];
  const float* w2 = (const float*)d_in[12];
  const float* b2 = (const float*)d_in[13];
  const float* ln2_g = (const float*)d_in[14];
  const float* ln2_b = (const float*)d_in[15];

  float* out_x = (float*)d_out;              // [8,256,512]
  float* out_a = out_x + 1048576;            // [8,8,256,256]

  // workspace layout (float-index offsets; bf16 buffers cast from float*):
  float* ws    = (float*)d_ws;
  float* qkv   = ws + 0;         // [2048,1536] f32 (dead after reshape)
  float* qhb   = ws + 3145728;   // dead after attn
  float* khb   = ws + 4194304;   // dead after attn
  float* vhb   = ws + 5242880;   // dead after av
  float* opair = ws + 6291456;   // 1,064,960 f
  float* obuf  = ws + 7356416;   // 1,048,576 f
  __hip_bfloat16* h_bf   = (__hip_bfloat16*)(ws + 8404992);   // [2048,2048] bf16 (2,097,152 f)
  __hip_bfloat16* s_bf   = (__hip_bfloat16*)(ws + 8404992);   // overlay: dead before FFN1
  __hip_bfloat16* wqkvT  = (__hip_bfloat16*)(ws + 10502144);  // [1536,512]  (393,216 f)
  __hip_bfloat16* wopT   = (__hip_bfloat16*)(ws + 10895360);  // [512,1088]  (278,528 f)
  __hip_bfloat16* w1T    = (__hip_bfloat16*)(ws + 11173888);  // [2048,512]  (524,288 f)
  __hip_bfloat16* w2T    = (__hip_bfloat16*)(ws + 11698176);  // [512,2048]  (524,288 f)
  // reuses of dead regions:
  float* embd = ws + 0;                                  // in old qkv
  float* xbuf = ws + 1048576;                            // in old qkv
  float* ff   = ws + 2097152;                            // in old qkv
  __hip_bfloat16* x_bf   = (__hip_bfloat16*)(ws + 3145728);   // old qhb
  __hip_bfloat16* cat_bf = (__hip_bfloat16*)(ws + 4194304);   // old khb+vhb (1,114,112 f)

  dim3 blk(256);
  // 0. weight transposes + s conversion (bf16 prep)
  cvt_bf16<<<dim3(1024), blk, 0, stream>>>(s, s_bf, 262144);
  transpose_cvt<<<dim3(16, 16), blk, 0, stream>>>(wq, wqkvT,              512, 512, 512);
  transpose_cvt<<<dim3(16, 16), blk, 0, stream>>>(wk, wqkvT + 512 * 512,  512, 512, 512);
  transpose_cvt<<<dim3(16, 16), blk, 0, stream>>>(wv, wqkvT + 1024 * 512, 512, 512, 512);
  transpose_cvt<<<dim3(16, 34), blk, 0, stream>>>(wo, wopT, 1032, 512, 1088);
  transpose_cvt<<<dim3(64, 16), blk, 0, stream>>>(w1, w1T, 512, 2048, 512);
  transpose_cvt<<<dim3(16, 64), blk, 0, stream>>>(w2, w2T, 2048, 512, 2048);
  // 1. fused QKV projection: [2048,1536] = s_bf @ wqkvT^T
  gemm_bf16<<<dim3(12, 16), blk, 0, stream>>>(
      (const ushort*)s_bf, (const ushort*)wqkvT, nullptr, qkv, nullptr,
      2048, 1536, 512, 8);
  // 2. head layout
  reshape_qkv<<<dim3(4096, 3), blk, 0, stream>>>(qkv, qhb, khb, vhb);
  // 3. attention
  attn_kernel<<<dim3(256), blk, 0, stream>>>(qhb, khb, masks, wb, out_a, opair);
  // 4. o = a @ v
  av_kernel<<<dim3(64, 16), blk, 0, stream>>>(out_a, vhb, obuf);
  // 5. concat pack (bf16, K padded to 1088) + output projection
  pack_cat<<<dim3((2048 * 1088 + 255) / 256), blk, 0, stream>>>(opair, obuf, cat_bf);
  gemm_bf16<<<dim3(4, 16), blk, 0, stream>>>(
      (const ushort*)cat_bf, (const ushort*)wopT, bo, embd, nullptr,
      2048, 512, 1088, 1 | 8);
  // 6. x = LN(s + embd)  (f32 + bf16)
  ln_kernel<<<dim3(2048), blk, 0, stream>>>(s, embd, ln1_g, ln1_b, xbuf, x_bf);
  // 7. FFN
  gemm_bf16<<<dim3(16, 16), blk, 0, stream>>>(
      (const ushort*)x_bf, (const ushort*)w1T, b1, nullptr, (ushort*)h_bf,
      2048, 2048, 512, 1 | 2 | 4);
  gemm_bf16<<<dim3(4, 16), blk, 0, stream>>>(
      (const ushort*)h_bf, (const ushort*)w2T, b2, ff, nullptr,
      2048, 512, 2048, 1 | 8);
  // 8. out = LN(x + ff)
  ln_kernel<<<dim3(2048), blk, 0, stream>>>(xbuf, ff, ln2_g, ln2_b, out_x, nullptr);
}

// Round 4
// 295.361 us; speedup vs baseline: 1.8994x; 1.2300x over previous
//
#include <hip/hip_runtime.h>
#include <hip/hip_bf16.h>
#include <cstdint>

#define B_ 8
#define N_ 256
#define CS_ 512
#define H_ 8
#define D_ 64
#define K_ 32
#define NB_ 65
#define CT_ 2048
#define WL_ 0.70710678118654752f

typedef __attribute__((ext_vector_type(8))) short bf16x8;
typedef __attribute__((ext_vector_type(4))) float f32x4;

#define GLOBAL_AS __attribute__((address_space(1)))
#define LDS_AS __attribute__((address_space(3)))

__device__ __forceinline__ void async16(void* lds, const void* g) {
  __builtin_amdgcn_global_load_lds((const GLOBAL_AS uint32_t*)g,
                                   (LDS_AS uint32_t*)lds, 16, 0, 0);
}

// ---------------- bf16 MFMA GEMM: C[M,N] = A[M,K] @ Bt[N,K]^T -------------
// flags: 1=+bias[col], 2=relu, 4=write bf16 Cb, 8=write f32 C,
//        16=qkv head-layout scatter (C = base of q|k|v [3][B,H,N,D] f32).
// M%128==0, N%128==0, K%64==0. XOR-swizzled LDS (granule ^= row&7).
__global__ __launch_bounds__(256) void gemm_bf16(
    const ushort* __restrict__ A, const ushort* __restrict__ Bt,
    const float* __restrict__ bias, float* __restrict__ C,
    ushort* __restrict__ Cb, int M, int Nc, int Kd, int flags) {
  __shared__ ushort As[128 * 64];
  __shared__ ushort Bs[128 * 64];
  int tid = threadIdx.x;
  int bm = blockIdx.y * 128, bn = blockIdx.x * 128;
  int w = tid >> 6, l = tid & 63;
  int wr = (w >> 1) * 64, wc = (w & 1) * 64;   // wave's 64x64 quadrant
  int lm = l & 15, lq = l >> 4;
  int srow = tid >> 3;        // 0..31: row within staging round
  int sg = tid & 7;           // physical granule (16B) within row

  f32x4 acc[4][4];
#pragma unroll
  for (int i = 0; i < 4; ++i)
#pragma unroll
    for (int j = 0; j < 4; ++j) acc[i][j] = (f32x4){0.f, 0.f, 0.f, 0.f};

  for (int k0 = 0; k0 < Kd; k0 += 64) {
    __syncthreads();
#pragma unroll
    for (int r = 0; r < 4; ++r) {
      int row = r * 32 + srow;
      int gl = sg ^ (row & 7);
      async16(&As[row * 64 + sg * 8],
              A + (size_t)(bm + row) * Kd + k0 + gl * 8);
      async16(&Bs[row * 64 + sg * 8],
              Bt + (size_t)(bn + row) * Kd + k0 + gl * 8);
    }
    __syncthreads();
#pragma unroll
    for (int kk = 0; kk < 2; ++kk) {
      bf16x8 af[4], bfr[4];
#pragma unroll
      for (int i = 0; i < 4; ++i) {
        int ma = wr + 16 * i + lm;
        af[i] = *(const bf16x8*)&As[ma * 64 + ((kk * 4 + lq) ^ (ma & 7)) * 8];
        int nb = wc + 16 * i + lm;
        bfr[i] = *(const bf16x8*)&Bs[nb * 64 + ((kk * 4 + lq) ^ (nb & 7)) * 8];
      }
#pragma unroll
      for (int i = 0; i < 4; ++i)
#pragma unroll
        for (int j = 0; j < 4; ++j)
          acc[i][j] = __builtin_amdgcn_mfma_f32_16x16x32_bf16(
              af[i], bfr[j], acc[i][j], 0, 0, 0);
    }
  }
  // epilogue: C/D layout col=lane&15, row=(lane>>4)*4+reg
#pragma unroll
  for (int j = 0; j < 4; ++j) {
    int col = bn + wc + 16 * j + lm;
    float bv = (flags & 1) ? bias[col] : 0.f;
#pragma unroll
    for (int i = 0; i < 4; ++i) {
#pragma unroll
      for (int r = 0; r < 4; ++r) {
        int row = bm + wr + 16 * i + lq * 4 + r;
        float v = acc[i][j][r] + bv;
        if (flags & 2) v = fmaxf(v, 0.f);
        if (flags & 8) C[(size_t)row * Nc + col] = v;
        if (flags & 4) {
          __hip_bfloat16 hb = __float2bfloat16(v);
          Cb[(size_t)row * Nc + col] = *(ushort*)&hb;
        }
        if (flags & 16) {
          int which = col >> 9, c = col & 511;
          int d2 = c >> 3, hh = c & 7;
          int bb = row >> 8, nn = row & 255;
          C[(size_t)which * 1048576 +
            (((size_t)(bb * 8 + hh) * 256) + nn) * 64 + d2] = v;
        }
      }
    }
  }
}

// ---------------- transpose+convert: dst[c][k] = (k<R)? src[k][c] : 0 -----
__global__ __launch_bounds__(256) void transpose_cvt(
    const float* __restrict__ src, __hip_bfloat16* __restrict__ dst,
    int R, int C, int Kpad) {
  __shared__ float tile[32][33];
  int c0 = blockIdx.x * 32, r0 = blockIdx.y * 32;
  int tx = threadIdx.x & 31, ty = threadIdx.x >> 5;  // 32x8
#pragma unroll
  for (int yy = 0; yy < 32; yy += 8) {
    int r = r0 + ty + yy, c = c0 + tx;
    tile[ty + yy][tx] = (r < R && c < C) ? src[(size_t)r * C + c] : 0.f;
  }
  __syncthreads();
#pragma unroll
  for (int yy = 0; yy < 32; yy += 8) {
    int cc = c0 + ty + yy, k = r0 + tx;
    if (cc < C && k < Kpad)
      dst[(size_t)cc * Kpad + k] = __float2bfloat16(tile[tx][ty + yy]);
  }
}

// fused wq/wk/wv transpose: all [512,512], dst strided by z*512*512
__global__ __launch_bounds__(256) void transpose_cvt3(
    const float* __restrict__ wq, const float* __restrict__ wk,
    const float* __restrict__ wv, __hip_bfloat16* __restrict__ dst) {
  __shared__ float tile[32][33];
  const float* src = (blockIdx.z == 0) ? wq : (blockIdx.z == 1) ? wk : wv;
  __hip_bfloat16* d = dst + (size_t)blockIdx.z * 512 * 512;
  int c0 = blockIdx.x * 32, r0 = blockIdx.y * 32;
  int tx = threadIdx.x & 31, ty = threadIdx.x >> 5;
#pragma unroll
  for (int yy = 0; yy < 32; yy += 8)
    tile[ty + yy][tx] = src[(size_t)(r0 + ty + yy) * 512 + c0 + tx];
  __syncthreads();
#pragma unroll
  for (int yy = 0; yy < 32; yy += 8)
    d[(size_t)(c0 + ty + yy) * 512 + r0 + tx] = __float2bfloat16(tile[tx][ty + yy]);
}

// ---------------- f32 -> bf16 elementwise (n divisible by 4) --------------
__global__ void cvt_bf16(const float* __restrict__ src,
                         __hip_bfloat16* __restrict__ dst, int n4) {
  int i = blockIdx.x * 256 + threadIdx.x;
  if (i >= n4) return;
  float4 v = ((const float4*)src)[i];
  dst[i * 4 + 0] = __float2bfloat16(v.x);
  dst[i * 4 + 1] = __float2bfloat16(v.y);
  dst[i * 4 + 2] = __float2bfloat16(v.z);
  dst[i * 4 + 3] = __float2bfloat16(v.w);
}

// ---------------- attention: logits + softmax + a + o_pair ----------------
// 512 blocks: (bh, 32-row i-tile). Thread tid owns column j=tid.
// 4 rows per round, 4 barriers per round; all reductions wave-local shuffles.
__global__ __launch_bounds__(256) void attn_kernel(
    const float* __restrict__ qh, const float* __restrict__ kh,
    const int* __restrict__ masks, const float* __restrict__ wb,
    float* __restrict__ a_out, float* __restrict__ opair) {
  int blk = blockIdx.x;
  int it = blk & 7, bh = blk >> 3;
  int h = bh & 7, b = bh >> 3;
  int i0 = it * 32;
  __shared__ float Qs[32][64];
  __shared__ float wbs[NB_];
  __shared__ float mfs[32];
  __shared__ float redmax[4][4];
  __shared__ float redsum[4][4];
  __shared__ float redb[4][4][2];
  __shared__ float op_rows[260];
  int tid = threadIdx.x;
  int w = tid >> 6, lane = tid & 63;
  // K row tid in registers
  float kreg[64];
  const float* krow = kh + ((size_t)bh * N_ + tid) * D_;
#pragma unroll
  for (int d4 = 0; d4 < 16; ++d4) {
    float4 v = *(const float4*)(krow + d4 * 4);
    kreg[d4 * 4 + 0] = v.x; kreg[d4 * 4 + 1] = v.y;
    kreg[d4 * 4 + 2] = v.z; kreg[d4 * 4 + 3] = v.w;
  }
  const float* qbase = qh + ((size_t)bh * N_ + i0) * D_;
  for (int idx = tid; idx < 32 * 16; idx += 256) {
    int row = idx >> 4, c4 = (idx & 15) << 2;
    *(float4*)&Qs[row][c4] = *(const float4*)(qbase + row * 64 + c4);
  }
  if (tid < NB_) wbs[tid] = wb[tid * H_ + h];
  if (tid < 32) mfs[tid] = (masks[b * N_ + i0 + tid] != 0) ? 1.f : 0.f;
  __syncthreads();
  int j = tid;
  float mf_j = (masks[b * N_ + j] != 0) ? 1.f : 0.f;

  for (int rr = 0; rr < 8; ++rr) {
    int ib = rr * 4;
    float lv[4], ev[4], sqv[4];
    // ---- phase A: dots + wave-max partials; zero op_rows
#pragma unroll
    for (int r = 0; r < 4; ++r) {
      int ii = ib + r, i = i0 + ii;
      float dot = 0.f;
#pragma unroll
      for (int d4 = 0; d4 < 16; ++d4) {
        float4 q4 = *(const float4*)&Qs[ii][d4 * 4];
        dot += q4.x * kreg[d4 * 4 + 0] + q4.y * kreg[d4 * 4 + 1] +
               q4.z * kreg[d4 * 4 + 2] + q4.w * kreg[d4 * 4 + 3];
      }
      int diff = i - j;
      int cb = diff < -K_ ? 0 : (diff > K_ ? 2 * K_ : diff + K_);
      float sq = mfs[ii] * mf_j;
      sqv[r] = sq;
      lv[r] = WL_ * (dot * 0.125f + wbs[cb] * sq) - 1e9f * (1.f - sq);
      float m = lv[r];
#pragma unroll
      for (int o = 32; o > 0; o >>= 1) m = fmaxf(m, __shfl_xor(m, o, 64));
      if (lane == 0) redmax[w][r] = m;
    }
    op_rows[tid] = 0.f;
    if (tid < 4) op_rows[256 + tid] = 0.f;
    __syncthreads();   // bar 1
    // ---- phase B: combine max, exp, wave-sum partials
#pragma unroll
    for (int r = 0; r < 4; ++r) {
      float mx = fmaxf(fmaxf(redmax[0][r], redmax[1][r]),
                       fmaxf(redmax[2][r], redmax[3][r]));
      ev[r] = __expf(lv[r] - mx);
      float sv = ev[r];
#pragma unroll
      for (int o = 32; o > 0; o >>= 1) sv += __shfl_xor(sv, o, 64);
      if (lane == 0) redsum[w][r] = sv;
    }
    __syncthreads();   // bar 2
    // ---- phase C: a stores + interior scatter + boundary partials
#pragma unroll
    for (int r = 0; r < 4; ++r) {
      int ii = ib + r, i = i0 + ii;
      float s = redsum[0][r] + redsum[1][r] + redsum[2][r] + redsum[3][r];
      float a = ev[r] / s;
      a_out[((size_t)bh * N_ + i) * N_ + j] = a;
      float val = a * sqv[r];
      int diff = i - j;
      if (diff > -K_ && diff < K_) op_rows[r * NB_ + diff + K_] = val;
      float p0 = (diff <= -K_) ? val : 0.f;
      float p1 = (diff >=  K_) ? val : 0.f;
#pragma unroll
      for (int o = 32; o > 0; o >>= 1) {
        p0 += __shfl_xor(p0, o, 64);
        p1 += __shfl_xor(p1, o, 64);
      }
      if (lane == 0) { redb[w][r][0] = p0; redb[w][r][1] = p1; }
    }
    __syncthreads();   // bar 3
    // ---- phase D: coalesced opair store (4 rows x 65 bins = 260 slots)
#pragma unroll
    for (int pass = 0; pass < 2; ++pass) {
      int slot = pass == 0 ? tid : 256 + tid;
      if (pass == 1 && tid >= 4) break;
      int r = slot / 65, c = slot - r * 65;
      float v = op_rows[slot];
      if (c == 0)       v = redb[0][r][0] + redb[1][r][0] + redb[2][r][0] + redb[3][r][0];
      else if (c == 64) v = redb[0][r][1] + redb[1][r][1] + redb[2][r][1] + redb[3][r][1];
      opair[((size_t)bh * N_ + i0 + ib) * NB_ + slot] = v;
    }
    __syncthreads();   // bar 4: op_rows safe to re-zero next round
  }
}

// ---------------- o[b,h,i,d] = sum_j a[b,h,i,j] * v[b,h,j,d] --------------
__global__ __launch_bounds__(256) void av_kernel(
    const float* __restrict__ a, const float* __restrict__ vh,
    float* __restrict__ o) {
  int bh = blockIdx.x;
  int i0 = blockIdx.y * 16;
  __shared__ float As[16][260];
  int tid = threadIdx.x;
  const float* abase = a + ((size_t)bh * N_ + i0) * N_;
  for (int idx = tid; idx < 16 * 64; idx += 256) {
    int r = idx >> 6, c4 = (idx & 63) << 2;
    *(float4*)&As[r][c4] = *(const float4*)(abase + r * N_ + c4);
  }
  __syncthreads();
  int d = tid & 63, ig = tid >> 6;
  const float* vbase = vh + (size_t)bh * N_ * D_ + d;
  float acc[4] = {0.f, 0.f, 0.f, 0.f};
  for (int jj = 0; jj < N_; ++jj) {
    float vv = vbase[jj * D_];
#pragma unroll
    for (int r = 0; r < 4; ++r) acc[r] += As[ig * 4 + r][jj] * vv;
  }
  for (int r = 0; r < 4; ++r)
    o[((size_t)bh * N_ + i0 + ig * 4 + r) * D_ + d] = acc[r];
}

// ---------------- pack concat([op, ov]) -> bf16 [2048, 1088] --------------
__global__ void pack_cat(const float* __restrict__ opair,
                         const float* __restrict__ o,
                         __hip_bfloat16* __restrict__ cat) {
  int idx = blockIdx.x * 256 + threadIdx.x;
  if (idx >= 2048 * 1088) return;
  int m = idx / 1088, kk = idx - m * 1088;
  int b = m >> 8, n = m & 255;
  float v = 0.f;
  if (kk < 520) {
    int h = kk / 65, c = kk - h * 65;
    v = opair[(((size_t)(b * 8 + h) * 256) + n) * 65 + c];
  } else if (kk < 1032) {
    int k2 = kk - 520;
    int h = k2 >> 6, d = k2 & 63;
    v = o[(((size_t)(b * 8 + h) * 256) + n) * 64 + d];
  }
  cat[idx] = __float2bfloat16(v);
}

// ---------------- block reduce for LN ------------------------------------
__device__ __forceinline__ float lnReduceSum(float v, float* red) {
#pragma unroll
  for (int o = 32; o > 0; o >>= 1) v += __shfl_xor(v, o, 64);
  int w = threadIdx.x >> 6;
  __syncthreads();
  if ((threadIdx.x & 63) == 0) red[w] = v;
  __syncthreads();
  return red[0] + red[1] + red[2] + red[3];
}

// ---------------- out = LayerNorm(x1 + x2) * g + b  (+opt bf16 copy) ------
__global__ __launch_bounds__(256) void ln_kernel(
    const float* __restrict__ x1, const float* __restrict__ x2,
    const float* __restrict__ g, const float* __restrict__ bta,
    float* __restrict__ out, __hip_bfloat16* __restrict__ out_bf) {
  __shared__ float red[4];
  int row = blockIdx.x, tid = threadIdx.x;
  const float* p1 = x1 + (size_t)row * 512;
  const float* p2 = x2 + (size_t)row * 512;
  float v0 = p1[tid] + p2[tid];
  float v1 = p1[tid + 256] + p2[tid + 256];
  float s  = lnReduceSum(v0 + v1, red);
  float sq = lnReduceSum(v0 * v0 + v1 * v1, red);
  float mean = s * (1.f / 512.f);
  float var = sq * (1.f / 512.f) - mean * mean;
  float inv = rsqrtf(var + 1e-5f);
  float o0 = (v0 - mean) * inv * g[tid] + bta[tid];
  float o1 = (v1 - mean) * inv * g[tid + 256] + bta[tid + 256];
  out[(size_t)row * 512 + tid]       = o0;
  out[(size_t)row * 512 + tid + 256] = o1;
  if (out_bf) {
    out_bf[(size_t)row * 512 + tid]       = __float2bfloat16(o0);
    out_bf[(size_t)row * 512 + tid + 256] = __float2bfloat16(o1);
  }
}

extern "C" void kernel_launch(void* const* d_in, const int* in_sizes, int n_in,
                              void* d_out, int out_size, void* d_ws, size_t ws_size,
                              hipStream_t stream) {
  const float* s     = (const float*)d_in[0];
  const int*   masks = (const int*)d_in[1];
  const float* wq = (const float*)d_in[2];
  const float* wk = (const float*)d_in[3];
  const float* wv = (const float*)d_in[4];
  const float* wb = (const float*)d_in[5];
  const float* wo = (const float*)d_in[6];
  const float* bo = (const float*)d_in[7];
  const float* ln1_g = (const float*)d_in[8];
  const float* ln1_b = (const float*)d_in[9];
  const float* w1 = (const float*)d_in[10];
  const float* b1 = (const float*)d_in[11];
  const float* w2 = (const float*)d_in[12];
  const float* b2 = (const float*)d_in[13];
  const float* ln2_g = (const float*)d_in[14];
  const float* ln2_b = (const float*)d_in[15];

  float* out_x = (float*)d_out;              // [8,256,512]
  float* out_a = out_x + 1048576;            // [8,8,256,256]

  // workspace layout (float-index offsets):
  float* ws    = (float*)d_ws;
  float* qhb   = ws + 3145728;   // [B,H,N,D] f32; khb/vhb contiguous after
  float* khb   = ws + 4194304;
  float* vhb   = ws + 5242880;
  float* opair = ws + 6291456;   // 1,064,960 f
  float* obuf  = ws + 7356416;   // 1,048,576 f
  __hip_bfloat16* h_bf   = (__hip_bfloat16*)(ws + 8404992);   // [2048,2048] bf16
  __hip_bfloat16* s_bf   = (__hip_bfloat16*)(ws + 8404992);   // overlay: dead before FFN1
  __hip_bfloat16* wqkvT  = (__hip_bfloat16*)(ws + 10502144);  // [1536,512]
  __hip_bfloat16* wopT   = (__hip_bfloat16*)(ws + 10895360);  // [512,1088]
  __hip_bfloat16* w1T    = (__hip_bfloat16*)(ws + 11173888);  // [2048,512]
  __hip_bfloat16* w2T    = (__hip_bfloat16*)(ws + 11698176);  // [512,2048]
  float* embd = ws + 0;
  float* xbuf = ws + 1048576;
  float* ff   = ws + 2097152;
  __hip_bfloat16* x_bf   = (__hip_bfloat16*)(ws + 3145728);   // reuse qhb (dead post-attn)
  __hip_bfloat16* cat_bf = (__hip_bfloat16*)(ws + 4194304);   // reuse khb+vhb

  dim3 blk(256);
  // 0. weight transposes + s conversion
  cvt_bf16<<<dim3(1024), blk, 0, stream>>>(s, s_bf, 262144);
  transpose_cvt3<<<dim3(16, 16, 3), blk, 0, stream>>>(wq, wk, wv, wqkvT);
  transpose_cvt<<<dim3(16, 34), blk, 0, stream>>>(wo, wopT, 1032, 512, 1088);
  transpose_cvt<<<dim3(64, 16), blk, 0, stream>>>(w1, w1T, 512, 2048, 512);
  transpose_cvt<<<dim3(16, 64), blk, 0, stream>>>(w2, w2T, 2048, 512, 2048);
  // 1. fused QKV projection, epilogue scatters straight to [B,H,N,D]
  gemm_bf16<<<dim3(12, 16), blk, 0, stream>>>(
      (const ushort*)s_bf, (const ushort*)wqkvT, nullptr, qhb, nullptr,
      2048, 1536, 512, 16);
  // 2. attention (a -> d_out, opair)
  attn_kernel<<<dim3(512), blk, 0, stream>>>(qhb, khb, masks, wb, out_a, opair);
  // 3. o = a @ v
  av_kernel<<<dim3(64, 16), blk, 0, stream>>>(out_a, vhb, obuf);
  // 4. concat pack + output projection
  pack_cat<<<dim3((2048 * 1088 + 255) / 256), blk, 0, stream>>>(opair, obuf, cat_bf);
  gemm_bf16<<<dim3(4, 16), blk, 0, stream>>>(
      (const ushort*)cat_bf, (const ushort*)wopT, bo, embd, nullptr,
      2048, 512, 1088, 1 | 8);
  // 5. x = LN(s + embd)
  ln_kernel<<<dim3(2048), blk, 0, stream>>>(s, embd, ln1_g, ln1_b, xbuf, x_bf);
  // 6. FFN
  gemm_bf16<<<dim3(16, 16), blk, 0, stream>>>(
      (const ushort*)x_bf, (const ushort*)w1T, b1, nullptr, (ushort*)h_bf,
      2048, 2048, 512, 1 | 2 | 4);
  gemm_bf16<<<dim3(4, 16), blk, 0, stream>>>(
      (const ushort*)h_bf, (const ushort*)w2T, b2, ff, nullptr,
      2048, 512, 2048, 1 | 8);
  // 7. out = LN(x + ff)
  ln_kernel<<<dim3(2048), blk, 0, stream>>>(xbuf, ff, ln2_g, ln2_b, out_x, nullptr);
}

// Round 5
// 251.211 us; speedup vs baseline: 2.2332x; 1.1758x over previous
//
#include <hip/hip_runtime.h>
#include <hip/hip_bf16.h>
#include <cstdint>

#define B_ 8
#define N_ 256
#define CS_ 512
#define H_ 8
#define D_ 64
#define K_ 32
#define NB_ 65
#define CT_ 2048
#define WL_ 0.70710678118654752f

typedef __attribute__((ext_vector_type(8))) short bf16x8;
typedef __attribute__((ext_vector_type(4))) float f32x4;

#define GLOBAL_AS __attribute__((address_space(1)))
#define LDS_AS __attribute__((address_space(3)))

__device__ __forceinline__ void async16(void* lds, const void* g) {
  __builtin_amdgcn_global_load_lds((const GLOBAL_AS uint32_t*)g,
                                   (LDS_AS uint32_t*)lds, 16, 0, 0);
}

// ---------------- bf16 MFMA GEMM: C[M,N] = A[M,K] @ Bt[N,K]^T -------------
// flags: 1=+bias[col], 2=relu, 4=write bf16 Cb, 8=write f32 C,
//        16=qkv head-layout bf16 scatter (Cb = base of q|k|v [3][B,H,N,D]).
__global__ __launch_bounds__(256) void gemm_bf16(
    const ushort* __restrict__ A, const ushort* __restrict__ Bt,
    const float* __restrict__ bias, float* __restrict__ C,
    ushort* __restrict__ Cb, int M, int Nc, int Kd, int flags) {
  __shared__ ushort As[128 * 64];
  __shared__ ushort Bs[128 * 64];
  int tid = threadIdx.x;
  int bm = blockIdx.y * 128, bn = blockIdx.x * 128;
  int w = tid >> 6, l = tid & 63;
  int wr = (w >> 1) * 64, wc = (w & 1) * 64;
  int lm = l & 15, lq = l >> 4;
  int srow = tid >> 3;
  int sg = tid & 7;

  f32x4 acc[4][4];
#pragma unroll
  for (int i = 0; i < 4; ++i)
#pragma unroll
    for (int j = 0; j < 4; ++j) acc[i][j] = (f32x4){0.f, 0.f, 0.f, 0.f};

  for (int k0 = 0; k0 < Kd; k0 += 64) {
    __syncthreads();
#pragma unroll
    for (int r = 0; r < 4; ++r) {
      int row = r * 32 + srow;
      int gl = sg ^ (row & 7);
      async16(&As[row * 64 + sg * 8],
              A + (size_t)(bm + row) * Kd + k0 + gl * 8);
      async16(&Bs[row * 64 + sg * 8],
              Bt + (size_t)(bn + row) * Kd + k0 + gl * 8);
    }
    __syncthreads();
#pragma unroll
    for (int kk = 0; kk < 2; ++kk) {
      bf16x8 af[4], bfr[4];
#pragma unroll
      for (int i = 0; i < 4; ++i) {
        int ma = wr + 16 * i + lm;
        af[i] = *(const bf16x8*)&As[ma * 64 + ((kk * 4 + lq) ^ (ma & 7)) * 8];
        int nb = wc + 16 * i + lm;
        bfr[i] = *(const bf16x8*)&Bs[nb * 64 + ((kk * 4 + lq) ^ (nb & 7)) * 8];
      }
#pragma unroll
      for (int i = 0; i < 4; ++i)
#pragma unroll
        for (int j = 0; j < 4; ++j)
          acc[i][j] = __builtin_amdgcn_mfma_f32_16x16x32_bf16(
              af[i], bfr[j], acc[i][j], 0, 0, 0);
    }
  }
#pragma unroll
  for (int j = 0; j < 4; ++j) {
    int col = bn + wc + 16 * j + lm;
    float bv = (flags & 1) ? bias[col] : 0.f;
#pragma unroll
    for (int i = 0; i < 4; ++i) {
#pragma unroll
      for (int r = 0; r < 4; ++r) {
        int row = bm + wr + 16 * i + lq * 4 + r;
        float v = acc[i][j][r] + bv;
        if (flags & 2) v = fmaxf(v, 0.f);
        if (flags & 8) C[(size_t)row * Nc + col] = v;
        if (flags & 4) {
          __hip_bfloat16 hb = __float2bfloat16(v);
          Cb[(size_t)row * Nc + col] = *(ushort*)&hb;
        }
        if (flags & 16) {
          int which = col >> 9, c = col & 511;
          int d2 = c >> 3, hh = c & 7;
          int bb = row >> 8, nn = row & 255;
          __hip_bfloat16 hb = __float2bfloat16(v);
          Cb[(size_t)which * 1048576 +
             (((size_t)(bb * 8 + hh) * 256) + nn) * 64 + d2] = *(ushort*)&hb;
        }
      }
    }
  }
}

// ---------------- transpose+convert: dst[c][k] = (k<R)? src[k][c] : 0 -----
__global__ __launch_bounds__(256) void transpose_cvt(
    const float* __restrict__ src, __hip_bfloat16* __restrict__ dst,
    int R, int C, int Kpad) {
  __shared__ float tile[32][33];
  int c0 = blockIdx.x * 32, r0 = blockIdx.y * 32;
  int tx = threadIdx.x & 31, ty = threadIdx.x >> 5;
#pragma unroll
  for (int yy = 0; yy < 32; yy += 8) {
    int r = r0 + ty + yy, c = c0 + tx;
    tile[ty + yy][tx] = (r < R && c < C) ? src[(size_t)r * C + c] : 0.f;
  }
  __syncthreads();
#pragma unroll
  for (int yy = 0; yy < 32; yy += 8) {
    int cc = c0 + ty + yy, k = r0 + tx;
    if (cc < C && k < Kpad)
      dst[(size_t)cc * Kpad + k] = __float2bfloat16(tile[tx][ty + yy]);
  }
}

__global__ __launch_bounds__(256) void transpose_cvt3(
    const float* __restrict__ wq, const float* __restrict__ wk,
    const float* __restrict__ wv, __hip_bfloat16* __restrict__ dst) {
  __shared__ float tile[32][33];
  const float* src = (blockIdx.z == 0) ? wq : (blockIdx.z == 1) ? wk : wv;
  __hip_bfloat16* d = dst + (size_t)blockIdx.z * 512 * 512;
  int c0 = blockIdx.x * 32, r0 = blockIdx.y * 32;
  int tx = threadIdx.x & 31, ty = threadIdx.x >> 5;
#pragma unroll
  for (int yy = 0; yy < 32; yy += 8)
    tile[ty + yy][tx] = src[(size_t)(r0 + ty + yy) * 512 + c0 + tx];
  __syncthreads();
#pragma unroll
  for (int yy = 0; yy < 32; yy += 8)
    d[(size_t)(c0 + ty + yy) * 512 + r0 + tx] = __float2bfloat16(tile[tx][ty + yy]);
}

__global__ void cvt_bf16(const float* __restrict__ src,
                         __hip_bfloat16* __restrict__ dst, int n4) {
  int i = blockIdx.x * 256 + threadIdx.x;
  if (i >= n4) return;
  float4 v = ((const float4*)src)[i];
  dst[i * 4 + 0] = __float2bfloat16(v.x);
  dst[i * 4 + 1] = __float2bfloat16(v.y);
  dst[i * 4 + 2] = __float2bfloat16(v.z);
  dst[i * 4 + 3] = __float2bfloat16(v.w);
}

// ---------------- MFMA attention: S = Q@K^T, softmax, a -------------------
// 256 blocks = (bh:64) x (64-row strip:4). Wave w owns rows strip*64+w*16..+16,
// all 256 cols. Softmax is wave-internal (16-lane butterflies); 1 barrier.
__global__ __launch_bounds__(256) void attn_mfma(
    const ushort* __restrict__ qh, const ushort* __restrict__ kh,
    const int* __restrict__ masks, const float* __restrict__ wb,
    float* __restrict__ a_out) {
  int strip = blockIdx.x & 3, bh = blockIdx.x >> 2;
  int h = bh & 7, b = bh >> 3;
  __shared__ ushort Ks[256 * 64];   // 32 KB
  __shared__ ushort Qs[64 * 64];    // 8 KB
  __shared__ float wbs[NB_];
  __shared__ float mfj[256];
  int tid = threadIdx.x;
  int srow = tid >> 3, sg = tid & 7;
  // stage K (all 256 rows) and Q strip, XOR-swizzled
#pragma unroll
  for (int rr = 0; rr < 8; ++rr) {
    int row = rr * 32 + srow;
    int gl = sg ^ (row & 7);
    async16(&Ks[row * 64 + sg * 8],
            kh + ((size_t)bh * 256 + row) * 64 + gl * 8);
  }
#pragma unroll
  for (int rr = 0; rr < 2; ++rr) {
    int row = rr * 32 + srow;
    int gl = sg ^ (row & 7);
    async16(&Qs[row * 64 + sg * 8],
            qh + ((size_t)bh * 256 + strip * 64 + row) * 64 + gl * 8);
  }
  if (tid < NB_) wbs[tid] = wb[tid * H_ + h];
  mfj[tid] = (masks[b * 256 + tid] != 0) ? 1.f : 0.f;
  __syncthreads();

  int w = tid >> 6, l = tid & 63, lm = l & 15, lq = l >> 4;
  // Q fragments for this wave's 16-row m-tile
  bf16x8 qf[2];
#pragma unroll
  for (int kk = 0; kk < 2; ++kk) {
    int qrow = w * 16 + lm;
    qf[kk] = *(const bf16x8*)&Qs[qrow * 64 + ((kk * 4 + lq) ^ (qrow & 7)) * 8];
  }
  // S strip: 16 col-tiles
  f32x4 acc[16];
#pragma unroll
  for (int ct = 0; ct < 16; ++ct) {
    int krow = ct * 16 + lm;
    bf16x8 kf0 = *(const bf16x8*)&Ks[krow * 64 + ((lq) ^ (krow & 7)) * 8];
    bf16x8 kf1 = *(const bf16x8*)&Ks[krow * 64 + ((4 + lq) ^ (krow & 7)) * 8];
    f32x4 z = (f32x4){0.f, 0.f, 0.f, 0.f};
    z = __builtin_amdgcn_mfma_f32_16x16x32_bf16(qf[0], kf0, z, 0, 0, 0);
    acc[ct] = __builtin_amdgcn_mfma_f32_16x16x32_bf16(qf[1], kf1, z, 0, 0, 0);
  }
  // logits
  int ibase = strip * 64 + w * 16 + lq * 4;
  float mfi[4];
#pragma unroll
  for (int r = 0; r < 4; ++r) mfi[r] = mfj[ibase + r];
#pragma unroll
  for (int ct = 0; ct < 16; ++ct) {
    int j = ct * 16 + lm;
    float mj = mfj[j];
#pragma unroll
    for (int r = 0; r < 4; ++r) {
      int i = ibase + r;
      int diff = i - j;
      int cb = diff < -K_ ? 0 : (diff > K_ ? 2 * K_ : diff + K_);
      float sq = mfi[r] * mj;
      acc[ct][r] = WL_ * (acc[ct][r] * 0.125f + wbs[cb] * sq) - 1e9f * (1.f - sq);
    }
  }
  // row max over 256 cols: in-register over ct, then 16-lane butterfly
  float mx[4], sm[4];
#pragma unroll
  for (int r = 0; r < 4; ++r) {
    float m = acc[0][r];
#pragma unroll
    for (int ct = 1; ct < 16; ++ct) m = fmaxf(m, acc[ct][r]);
#pragma unroll
    for (int o = 1; o < 16; o <<= 1) m = fmaxf(m, __shfl_xor(m, o, 64));
    mx[r] = m;
  }
#pragma unroll
  for (int ct = 0; ct < 16; ++ct)
#pragma unroll
    for (int r = 0; r < 4; ++r) acc[ct][r] = __expf(acc[ct][r] - mx[r]);
#pragma unroll
  for (int r = 0; r < 4; ++r) {
    float s = 0.f;
#pragma unroll
    for (int ct = 0; ct < 16; ++ct) s += acc[ct][r];
#pragma unroll
    for (int o = 1; o < 16; o <<= 1) s += __shfl_xor(s, o, 64);
    sm[r] = 1.f / s;
  }
  // store a
#pragma unroll
  for (int ct = 0; ct < 16; ++ct) {
    int j = ct * 16 + lm;
#pragma unroll
    for (int r = 0; r < 4; ++r)
      a_out[((size_t)bh * 256 + ibase + r) * 256 + j] = acc[ct][r] * sm[r];
  }
}

// ---------------- o = a @ v (v bf16) + fused o_pair -----------------------
__global__ __launch_bounds__(256) void av_opair(
    const float* __restrict__ a, const ushort* __restrict__ vh,
    const int* __restrict__ masks, float* __restrict__ o,
    float* __restrict__ opair) {
  int bh = blockIdx.x, b = bh >> 3;
  int i0 = blockIdx.y * 16;
  __shared__ float As[16][260];
  __shared__ float mfs[256];
  int tid = threadIdx.x;
  const float* abase = a + ((size_t)bh * N_ + i0) * N_;
  for (int idx = tid; idx < 16 * 64; idx += 256) {
    int r = idx >> 6, c4 = (idx & 63) << 2;
    *(float4*)&As[r][c4] = *(const float4*)(abase + r * N_ + c4);
  }
  mfs[tid] = (masks[b * 256 + tid] != 0) ? 1.f : 0.f;
  __syncthreads();
  // o = a @ v
  int d = tid & 63, ig = tid >> 6;
  const ushort* vbase = vh + (size_t)bh * N_ * D_ + d;
  float acc[4] = {0.f, 0.f, 0.f, 0.f};
  for (int jj = 0; jj < N_; ++jj) {
    ushort u = vbase[jj * D_];
    union { uint32_t ui; float f; } cv; cv.ui = (uint32_t)u << 16;
    float vv = cv.f;
#pragma unroll
    for (int r = 0; r < 4; ++r) acc[r] += As[ig * 4 + r][jj] * vv;
  }
#pragma unroll
  for (int r = 0; r < 4; ++r)
    o[((size_t)bh * N_ + i0 + ig * 4 + r) * D_ + d] = acc[r];
  // o_pair: group g (16 lanes) handles row g
  int g = tid >> 4, gl = tid & 15;
  int i = i0 + g;
  float mi = mfs[i];
  float* aR = As[g];
  float* oprow = opair + ((size_t)bh * N_ + i) * NB_;
#pragma unroll
  for (int t = 0; t < 4; ++t) {
    int c = gl + 16 * t;
    if (c >= 1 && c <= 63) {
      int j = i - c + K_;
      float v = (j >= 0 && j < 256) ? aR[j] * mi * mfs[j] : 0.f;
      oprow[c] = v;
    }
  }
  float s0 = 0.f, s1 = 0.f;
  for (int j = gl; j < 256; j += 16) {
    float v = aR[j] * mfs[j];
    if (j >= i + K_) s0 += v;
    if (j <= i - K_) s1 += v;
  }
  s0 *= mi; s1 *= mi;
#pragma unroll
  for (int off = 1; off < 16; off <<= 1) {
    s0 += __shfl_xor(s0, off, 64);
    s1 += __shfl_xor(s1, off, 64);
  }
  if (gl == 0) { oprow[0] = s0; oprow[2 * K_] = s1; }
}

// ---------------- pack concat([op, ov]) -> bf16 [2048, 1088] --------------
__global__ void pack_cat(const float* __restrict__ opair,
                         const float* __restrict__ o,
                         __hip_bfloat16* __restrict__ cat) {
  int idx = blockIdx.x * 256 + threadIdx.x;
  if (idx >= 2048 * 1088) return;
  int m = idx / 1088, kk = idx - m * 1088;
  int b = m >> 8, n = m & 255;
  float v = 0.f;
  if (kk < 520) {
    int h = kk / 65, c = kk - h * 65;
    v = opair[(((size_t)(b * 8 + h) * 256) + n) * 65 + c];
  } else if (kk < 1032) {
    int k2 = kk - 520;
    int h = k2 >> 6, d = k2 & 63;
    v = o[(((size_t)(b * 8 + h) * 256) + n) * 64 + d];
  }
  cat[idx] = __float2bfloat16(v);
}

__device__ __forceinline__ float lnReduceSum(float v, float* red) {
#pragma unroll
  for (int o = 32; o > 0; o >>= 1) v += __shfl_xor(v, o, 64);
  int w = threadIdx.x >> 6;
  __syncthreads();
  if ((threadIdx.x & 63) == 0) red[w] = v;
  __syncthreads();
  return red[0] + red[1] + red[2] + red[3];
}

__global__ __launch_bounds__(256) void ln_kernel(
    const float* __restrict__ x1, const float* __restrict__ x2,
    const float* __restrict__ g, const float* __restrict__ bta,
    float* __restrict__ out, __hip_bfloat16* __restrict__ out_bf) {
  __shared__ float red[4];
  int row = blockIdx.x, tid = threadIdx.x;
  const float* p1 = x1 + (size_t)row * 512;
  const float* p2 = x2 + (size_t)row * 512;
  float v0 = p1[tid] + p2[tid];
  float v1 = p1[tid + 256] + p2[tid + 256];
  float s  = lnReduceSum(v0 + v1, red);
  float sq = lnReduceSum(v0 * v0 + v1 * v1, red);
  float mean = s * (1.f / 512.f);
  float var = sq * (1.f / 512.f) - mean * mean;
  float inv = rsqrtf(var + 1e-5f);
  float o0 = (v0 - mean) * inv * g[tid] + bta[tid];
  float o1 = (v1 - mean) * inv * g[tid + 256] + bta[tid + 256];
  out[(size_t)row * 512 + tid]       = o0;
  out[(size_t)row * 512 + tid + 256] = o1;
  if (out_bf) {
    out_bf[(size_t)row * 512 + tid]       = __float2bfloat16(o0);
    out_bf[(size_t)row * 512 + tid + 256] = __float2bfloat16(o1);
  }
}

extern "C" void kernel_launch(void* const* d_in, const int* in_sizes, int n_in,
                              void* d_out, int out_size, void* d_ws, size_t ws_size,
                              hipStream_t stream) {
  const float* s     = (const float*)d_in[0];
  const int*   masks = (const int*)d_in[1];
  const float* wq = (const float*)d_in[2];
  const float* wk = (const float*)d_in[3];
  const float* wv = (const float*)d_in[4];
  const float* wb = (const float*)d_in[5];
  const float* wo = (const float*)d_in[6];
  const float* bo = (const float*)d_in[7];
  const float* ln1_g = (const float*)d_in[8];
  const float* ln1_b = (const float*)d_in[9];
  const float* w1 = (const float*)d_in[10];
  const float* b1 = (const float*)d_in[11];
  const float* w2 = (const float*)d_in[12];
  const float* b2 = (const float*)d_in[13];
  const float* ln2_g = (const float*)d_in[14];
  const float* ln2_b = (const float*)d_in[15];

  float* out_x = (float*)d_out;              // [8,256,512]
  float* out_a = out_x + 1048576;            // [8,8,256,256]

  float* ws = (float*)d_ws;
  // qkv bf16 [3][B,H,N,D]: 3*1048576 ushorts = 1,572,864 floats
  ushort* qkv_bf = (ushort*)(ws + 3145728);              // 3145728..4718592
  ushort* q_bf = qkv_bf;
  ushort* k_bf = qkv_bf + 1048576;
  ushort* v_bf = qkv_bf + 2097152;
  float* opair = ws + 6291456;   // 1,064,960 f
  float* obuf  = ws + 7356416;   // 1,048,576 f
  __hip_bfloat16* h_bf   = (__hip_bfloat16*)(ws + 8404992);
  __hip_bfloat16* s_bf   = (__hip_bfloat16*)(ws + 8404992);   // dead before FFN1
  __hip_bfloat16* wqkvT  = (__hip_bfloat16*)(ws + 10502144);
  __hip_bfloat16* wopT   = (__hip_bfloat16*)(ws + 10895360);
  __hip_bfloat16* w1T    = (__hip_bfloat16*)(ws + 11173888);
  __hip_bfloat16* w2T    = (__hip_bfloat16*)(ws + 11698176);
  float* embd = ws + 0;
  float* xbuf = ws + 1048576;
  float* ff   = ws + 2097152;
  __hip_bfloat16* x_bf   = (__hip_bfloat16*)(ws + 3145728);   // over q/k (dead post-attn)
  __hip_bfloat16* cat_bf = (__hip_bfloat16*)(ws + 4194304);   // over v (dead post-av)

  dim3 blk(256);
  // 0. weight transposes + s conversion
  cvt_bf16<<<dim3(1024), blk, 0, stream>>>(s, s_bf, 262144);
  transpose_cvt3<<<dim3(16, 16, 3), blk, 0, stream>>>(wq, wk, wv, wqkvT);
  transpose_cvt<<<dim3(16, 34), blk, 0, stream>>>(wo, wopT, 1032, 512, 1088);
  transpose_cvt<<<dim3(64, 16), blk, 0, stream>>>(w1, w1T, 512, 2048, 512);
  transpose_cvt<<<dim3(16, 64), blk, 0, stream>>>(w2, w2T, 2048, 512, 2048);
  // 1. QKV projection -> bf16 head layout
  gemm_bf16<<<dim3(12, 16), blk, 0, stream>>>(
      (const ushort*)s_bf, (const ushort*)wqkvT, nullptr, nullptr,
      qkv_bf, 2048, 1536, 512, 16);
  // 2. MFMA attention -> a (d_out)
  attn_mfma<<<dim3(256), blk, 0, stream>>>(q_bf, k_bf, masks, wb, out_a);
  // 3. o = a @ v  + fused o_pair
  av_opair<<<dim3(64, 16), blk, 0, stream>>>(out_a, v_bf, masks, obuf, opair);
  // 4. concat pack + output projection
  pack_cat<<<dim3((2048 * 1088 + 255) / 256), blk, 0, stream>>>(opair, obuf, cat_bf);
  gemm_bf16<<<dim3(4, 16), blk, 0, stream>>>(
      (const ushort*)cat_bf, (const ushort*)wopT, bo, embd, nullptr,
      2048, 512, 1088, 1 | 8);
  // 5. x = LN(s + embd)
  ln_kernel<<<dim3(2048), blk, 0, stream>>>(s, embd, ln1_g, ln1_b, xbuf, x_bf);
  // 6. FFN
  gemm_bf16<<<dim3(16, 16), blk, 0, stream>>>(
      (const ushort*)x_bf, (const ushort*)w1T, b1, nullptr, (ushort*)h_bf,
      2048, 2048, 512, 1 | 2 | 4);
  gemm_bf16<<<dim3(4, 16), blk, 0, stream>>>(
      (const ushort*)h_bf, (const ushort*)w2T, b2, ff, nullptr,
      2048, 512, 2048, 1 | 8);
  // 7. out = LN(x + ff)
  ln_kernel<<<dim3(2048), blk, 0, stream>>>(xbuf, ff, ln2_g, ln2_b, out_x, nullptr);
}

// Round 6
// 207.243 us; speedup vs baseline: 2.7070x; 1.2122x over previous
//
#include <hip/hip_runtime.h>
#include <hip/hip_bf16.h>
#include <cstdint>

#define B_ 8
#define N_ 256
#define CS_ 512
#define H_ 8
#define D_ 64
#define K_ 32
#define NB_ 65
#define CT_ 2048
#define WL_ 0.70710678118654752f

typedef __attribute__((ext_vector_type(8))) short bf16x8;
typedef __attribute__((ext_vector_type(4))) float f32x4;

#define GLOBAL_AS __attribute__((address_space(1)))
#define LDS_AS __attribute__((address_space(3)))

__device__ __forceinline__ void async16(void* lds, const void* g) {
  __builtin_amdgcn_global_load_lds((const GLOBAL_AS uint32_t*)g,
                                   (LDS_AS uint32_t*)lds, 16, 0, 0);
}

// ---------------- bf16 MFMA GEMM: C[M,N] = A[M,K] @ Bt[N,K]^T -------------
// flags: 1=+bias[col] (slice 0 only), 2=relu, 4=write bf16 Cb, 8=write f32 C
//        (offset by slice z*M*Nc), 16=qkv head-layout bf16 scatter with
//        PERMUTED cols (col = which*512 + h*64 + d); q,k -> [B,H,N,D],
//        v -> transposed [B,H,D,N].
// Split-K via gridDim.z: slice z covers iters [z*T/S, (z+1)*T/S), T=Kd/64.
__global__ __launch_bounds__(256) void gemm_bf16(
    const ushort* __restrict__ A, const ushort* __restrict__ Bt,
    const float* __restrict__ bias, float* __restrict__ C,
    ushort* __restrict__ Cb, int M, int Nc, int Kd, int flags) {
  __shared__ ushort As[128 * 64];
  __shared__ ushort Bs[128 * 64];
  int tid = threadIdx.x;
  int bm = blockIdx.y * 128, bn = blockIdx.x * 128;
  int S = gridDim.z, z = blockIdx.z;
  int T = Kd >> 6;
  int it0 = (z * T) / S, it1 = ((z + 1) * T) / S;
  if (flags & 8) C += (size_t)z * M * Nc;
  int w = tid >> 6, l = tid & 63;
  int wr = (w >> 1) * 64, wc = (w & 1) * 64;
  int lm = l & 15, lq = l >> 4;
  int srow = tid >> 3;
  int sg = tid & 7;

  f32x4 acc[4][4];
#pragma unroll
  for (int i = 0; i < 4; ++i)
#pragma unroll
    for (int j = 0; j < 4; ++j) acc[i][j] = (f32x4){0.f, 0.f, 0.f, 0.f};

  for (int it = it0; it < it1; ++it) {
    int k0 = it << 6;
    __syncthreads();
#pragma unroll
    for (int r = 0; r < 4; ++r) {
      int row = r * 32 + srow;
      int gl = sg ^ (row & 7);
      async16(&As[row * 64 + sg * 8],
              A + (size_t)(bm + row) * Kd + k0 + gl * 8);
      async16(&Bs[row * 64 + sg * 8],
              Bt + (size_t)(bn + row) * Kd + k0 + gl * 8);
    }
    __syncthreads();
#pragma unroll
    for (int kk = 0; kk < 2; ++kk) {
      bf16x8 af[4], bfr[4];
#pragma unroll
      for (int i = 0; i < 4; ++i) {
        int ma = wr + 16 * i + lm;
        af[i] = *(const bf16x8*)&As[ma * 64 + ((kk * 4 + lq) ^ (ma & 7)) * 8];
        int nb = wc + 16 * i + lm;
        bfr[i] = *(const bf16x8*)&Bs[nb * 64 + ((kk * 4 + lq) ^ (nb & 7)) * 8];
      }
#pragma unroll
      for (int i = 0; i < 4; ++i)
#pragma unroll
        for (int j = 0; j < 4; ++j)
          acc[i][j] = __builtin_amdgcn_mfma_f32_16x16x32_bf16(
              af[i], bfr[j], acc[i][j], 0, 0, 0);
    }
  }
#pragma unroll
  for (int j = 0; j < 4; ++j) {
    int col = bn + wc + 16 * j + lm;
    float bv = ((flags & 1) && z == 0) ? bias[col] : 0.f;
#pragma unroll
    for (int i = 0; i < 4; ++i) {
#pragma unroll
      for (int r = 0; r < 4; ++r) {
        int row = bm + wr + 16 * i + lq * 4 + r;
        float v = acc[i][j][r] + bv;
        if (flags & 2) v = fmaxf(v, 0.f);
        if (flags & 8) C[(size_t)row * Nc + col] = v;
        if (flags & 4) {
          __hip_bfloat16 hb = __float2bfloat16(v);
          Cb[(size_t)row * Nc + col] = *(ushort*)&hb;
        }
        if (flags & 16) {
          int which = col >> 9, c = col & 511;
          int hh = c >> 6, d2 = c & 63;
          int bb = row >> 8, nn = row & 255;
          __hip_bfloat16 hb = __float2bfloat16(v);
          size_t dst;
          if (which == 2)  // v transposed [B,H,D,N]
            dst = (size_t)2 * 1048576 + (((size_t)(bb * 8 + hh) * 64) + d2) * 256 + nn;
          else
            dst = (size_t)which * 1048576 + (((size_t)(bb * 8 + hh) * 256) + nn) * 64 + d2;
          Cb[dst] = *(ushort*)&hb;
        }
      }
    }
  }
}

// ---------------- all weight transposes in one dispatch -------------------
// jobs: [0,768) wq/wk/wv (col-permuted to h*64+d), [768,1312) wo,
//       [1312,2336) w1, [2336,3360) w2
__global__ __launch_bounds__(256) void transpose_all(
    const float* __restrict__ wq, const float* __restrict__ wk,
    const float* __restrict__ wv, const float* __restrict__ wo,
    const float* __restrict__ w1, const float* __restrict__ w2,
    __hip_bfloat16* __restrict__ wqkvT, __hip_bfloat16* __restrict__ wopT,
    __hip_bfloat16* __restrict__ w1T, __hip_bfloat16* __restrict__ w2T) {
  __shared__ float tile[32][33];
  int blk = blockIdx.x;
  const float* src;
  __hip_bfloat16* dst;
  int R, C, Kpad, tX, tIdx, whichBase = -1;
  if (blk < 768) {
    int zz = blk >> 8; tIdx = blk & 255;
    src = zz == 0 ? wq : zz == 1 ? wk : wv;
    dst = wqkvT; whichBase = zz * 512; R = 512; C = 512; Kpad = 512; tX = 16;
  } else if (blk < 1312) {
    tIdx = blk - 768; src = wo; dst = wopT; R = 1032; C = 512; Kpad = 1088; tX = 16;
  } else if (blk < 2336) {
    tIdx = blk - 1312; src = w1; dst = w1T; R = 512; C = 2048; Kpad = 512; tX = 64;
  } else {
    tIdx = blk - 2336; src = w2; dst = w2T; R = 2048; C = 512; Kpad = 2048; tX = 16;
  }
  int c0 = (tIdx % tX) * 32, r0 = (tIdx / tX) * 32;
  int tx = threadIdx.x & 31, ty = threadIdx.x >> 5;
#pragma unroll
  for (int yy = 0; yy < 32; yy += 8) {
    int r = r0 + ty + yy, c = c0 + tx;
    tile[ty + yy][tx] = (r < R && c < C) ? src[(size_t)r * C + c] : 0.f;
  }
  __syncthreads();
#pragma unroll
  for (int yy = 0; yy < 32; yy += 8) {
    int cc = c0 + ty + yy, k = r0 + tx;
    if (cc < C && k < Kpad) {
      int n = (whichBase >= 0) ? (whichBase + (cc & 7) * 64 + (cc >> 3)) : cc;
      dst[(size_t)n * Kpad + k] = __float2bfloat16(tile[tx][ty + yy]);
    }
  }
}

__global__ void cvt_bf16(const float* __restrict__ src,
                         __hip_bfloat16* __restrict__ dst, int n4) {
  int i = blockIdx.x * 256 + threadIdx.x;
  if (i >= n4) return;
  float4 v = ((const float4*)src)[i];
  dst[i * 4 + 0] = __float2bfloat16(v.x);
  dst[i * 4 + 1] = __float2bfloat16(v.y);
  dst[i * 4 + 2] = __float2bfloat16(v.z);
  dst[i * 4 + 3] = __float2bfloat16(v.w);
}

// ---------------- MFMA attention: softmax(a) + a_bf16 + o_pair ------------
// 256 blocks = (bh:64) x (64-row strip:4); wave w owns 16 full rows.
__global__ __launch_bounds__(256) void attn_mfma(
    const ushort* __restrict__ qh, const ushort* __restrict__ kh,
    const int* __restrict__ masks, const float* __restrict__ wb,
    float* __restrict__ a_out, ushort* __restrict__ a_bf,
    float* __restrict__ opair) {
  int strip = blockIdx.x & 3, bh = blockIdx.x >> 2;
  int h = bh & 7, b = bh >> 3;
  __shared__ ushort Ks[256 * 64];
  __shared__ ushort Qs[64 * 64];
  __shared__ float wbs[NB_];
  __shared__ float mfj[256];
  int tid = threadIdx.x;
  int srow = tid >> 3, sg = tid & 7;
#pragma unroll
  for (int rr = 0; rr < 8; ++rr) {
    int row = rr * 32 + srow;
    int gl = sg ^ (row & 7);
    async16(&Ks[row * 64 + sg * 8],
            kh + ((size_t)bh * 256 + row) * 64 + gl * 8);
  }
#pragma unroll
  for (int rr = 0; rr < 2; ++rr) {
    int row = rr * 32 + srow;
    int gl = sg ^ (row & 7);
    async16(&Qs[row * 64 + sg * 8],
            qh + ((size_t)bh * 256 + strip * 64 + row) * 64 + gl * 8);
  }
  if (tid < NB_) wbs[tid] = wb[tid * H_ + h];
  mfj[tid] = (masks[b * 256 + tid] != 0) ? 1.f : 0.f;
  __syncthreads();

  int w = tid >> 6, l = tid & 63, lm = l & 15, lq = l >> 4;
  bf16x8 qf[2];
#pragma unroll
  for (int kk = 0; kk < 2; ++kk) {
    int qrow = w * 16 + lm;
    qf[kk] = *(const bf16x8*)&Qs[qrow * 64 + ((kk * 4 + lq) ^ (qrow & 7)) * 8];
  }
  f32x4 acc[16];
#pragma unroll
  for (int ct = 0; ct < 16; ++ct) {
    int krow = ct * 16 + lm;
    bf16x8 kf0 = *(const bf16x8*)&Ks[krow * 64 + ((lq) ^ (krow & 7)) * 8];
    bf16x8 kf1 = *(const bf16x8*)&Ks[krow * 64 + ((4 + lq) ^ (krow & 7)) * 8];
    f32x4 zf = (f32x4){0.f, 0.f, 0.f, 0.f};
    zf = __builtin_amdgcn_mfma_f32_16x16x32_bf16(qf[0], kf0, zf, 0, 0, 0);
    acc[ct] = __builtin_amdgcn_mfma_f32_16x16x32_bf16(qf[1], kf1, acc[ct] = zf, 0, 0, 0);
  }
  int ibase = strip * 64 + w * 16 + lq * 4;
  float mfi[4];
#pragma unroll
  for (int r = 0; r < 4; ++r) mfi[r] = mfj[ibase + r];
#pragma unroll
  for (int ct = 0; ct < 16; ++ct) {
    int j = ct * 16 + lm;
    float mj = mfj[j];
#pragma unroll
    for (int r = 0; r < 4; ++r) {
      int i = ibase + r;
      int diff = i - j;
      int cb = diff < -K_ ? 0 : (diff > K_ ? 2 * K_ : diff + K_);
      float sq = mfi[r] * mj;
      acc[ct][r] = WL_ * (acc[ct][r] * 0.125f + wbs[cb] * sq) - 1e9f * (1.f - sq);
    }
  }
  float mx[4], sm[4];
#pragma unroll
  for (int r = 0; r < 4; ++r) {
    float m = acc[0][r];
#pragma unroll
    for (int ct = 1; ct < 16; ++ct) m = fmaxf(m, acc[ct][r]);
#pragma unroll
    for (int o = 1; o < 16; o <<= 1) m = fmaxf(m, __shfl_xor(m, o, 64));
    mx[r] = m;
  }
#pragma unroll
  for (int ct = 0; ct < 16; ++ct)
#pragma unroll
    for (int r = 0; r < 4; ++r) acc[ct][r] = __expf(acc[ct][r] - mx[r]);
#pragma unroll
  for (int r = 0; r < 4; ++r) {
    float s = 0.f;
#pragma unroll
    for (int ct = 0; ct < 16; ++ct) s += acc[ct][r];
#pragma unroll
    for (int o = 1; o < 16; o <<= 1) s += __shfl_xor(s, o, 64);
    sm[r] = 1.f / s;
  }
  // store a (f32 + bf16), scatter interior o_pair bins, boundary partials
  float p0[4] = {0.f, 0.f, 0.f, 0.f}, p64[4] = {0.f, 0.f, 0.f, 0.f};
#pragma unroll
  for (int ct = 0; ct < 16; ++ct) {
    int j = ct * 16 + lm;
    float mj = mfj[j];
#pragma unroll
    for (int r = 0; r < 4; ++r) {
      int i = ibase + r;
      float aval = acc[ct][r] * sm[r];
      a_out[((size_t)bh * 256 + i) * 256 + j] = aval;
      __hip_bfloat16 hb = __float2bfloat16(aval);
      a_bf[((size_t)bh * 256 + i) * 256 + j] = *(ushort*)&hb;
      float val = aval * mfi[r] * mj;
      int diff = i - j;
      if (diff <= -K_)      p0[r] += val;
      else if (diff >= K_)  p64[r] += val;
      else opair[((size_t)bh * 256 + i) * NB_ + diff + K_] = val;
    }
  }
#pragma unroll
  for (int r = 0; r < 4; ++r)
#pragma unroll
    for (int o = 1; o < 16; o <<= 1) {
      p0[r]  += __shfl_xor(p0[r], o, 64);
      p64[r] += __shfl_xor(p64[r], o, 64);
    }
  if (lm == 0) {
#pragma unroll
    for (int r = 0; r < 4; ++r) {
      int i = ibase + r;
      opair[((size_t)bh * 256 + i) * NB_ + 0]      = p0[r];
      opair[((size_t)bh * 256 + i) * NB_ + 2 * K_] = p64[r];
    }
  }
  // zero interior bins whose source j is out of [0,256)
#pragma unroll
  for (int r = 0; r < 4; ++r) {
    int i = ibase + r;
#pragma unroll
    for (int t = 0; t < 4; ++t) {
      int c = 1 + lm + 16 * t;
      if (c < 64) {
        int j = i - c + K_;
        if (j < 0 || j > 255)
          opair[((size_t)bh * 256 + i) * NB_ + c] = 0.f;
      }
    }
  }
}

// ---------------- o = a_bf @ vT^T per (bh): M=128 tile, N=64, K=256 -------
__global__ __launch_bounds__(256) void av_mfma(
    const ushort* __restrict__ a_bf, const ushort* __restrict__ vT,
    float* __restrict__ o) {
  int bm = blockIdx.x * 128, bh = blockIdx.y;
  __shared__ ushort As[128 * 64];
  __shared__ ushort Bs[64 * 64];
  int tid = threadIdx.x;
  int w = tid >> 6, l = tid & 63, lm = l & 15, lq = l >> 4;
  int wr = (w >> 1) * 64, wc = (w & 1) * 32;
  int srow = tid >> 3, sg = tid & 7;
  const ushort* Abase = a_bf + (size_t)bh * 65536;
  const ushort* Bbase = vT + (size_t)bh * 16384;
  f32x4 acc[4][2];
#pragma unroll
  for (int i = 0; i < 4; ++i)
#pragma unroll
    for (int j = 0; j < 2; ++j) acc[i][j] = (f32x4){0.f, 0.f, 0.f, 0.f};
  for (int k0 = 0; k0 < 256; k0 += 64) {
    __syncthreads();
#pragma unroll
    for (int r = 0; r < 4; ++r) {
      int row = r * 32 + srow;
      int gl = sg ^ (row & 7);
      async16(&As[row * 64 + sg * 8],
              Abase + (size_t)(bm + row) * 256 + k0 + gl * 8);
    }
#pragma unroll
    for (int r = 0; r < 2; ++r) {
      int row = r * 32 + srow;
      int gl = sg ^ (row & 7);
      async16(&Bs[row * 64 + sg * 8],
              Bbase + (size_t)row * 256 + k0 + gl * 8);
    }
    __syncthreads();
#pragma unroll
    for (int kk = 0; kk < 2; ++kk) {
      bf16x8 af[4], bfr[2];
#pragma unroll
      for (int i = 0; i < 4; ++i) {
        int ma = wr + 16 * i + lm;
        af[i] = *(const bf16x8*)&As[ma * 64 + ((kk * 4 + lq) ^ (ma & 7)) * 8];
      }
#pragma unroll
      for (int j = 0; j < 2; ++j) {
        int nb = wc + 16 * j + lm;
        bfr[j] = *(const bf16x8*)&Bs[nb * 64 + ((kk * 4 + lq) ^ (nb & 7)) * 8];
      }
#pragma unroll
      for (int i = 0; i < 4; ++i)
#pragma unroll
        for (int j = 0; j < 2; ++j)
          acc[i][j] = __builtin_amdgcn_mfma_f32_16x16x32_bf16(
              af[i], bfr[j], acc[i][j], 0, 0, 0);
    }
  }
#pragma unroll
  for (int j = 0; j < 2; ++j) {
    int col = wc + 16 * j + lm;
#pragma unroll
    for (int i = 0; i < 4; ++i)
#pragma unroll
      for (int r = 0; r < 4; ++r) {
        int row = bm + wr + 16 * i + lq * 4 + r;
        o[((size_t)bh * 256 + row) * 64 + col] = acc[i][j][r];
      }
  }
}

// ---------------- pack concat([op, ov]) -> bf16 [2048, 1088] --------------
__global__ void pack_cat(const float* __restrict__ opair,
                         const float* __restrict__ o,
                         __hip_bfloat16* __restrict__ cat) {
  int idx = blockIdx.x * 256 + threadIdx.x;
  if (idx >= 2048 * 1088) return;
  int m = idx / 1088, kk = idx - m * 1088;
  int b = m >> 8, n = m & 255;
  float v = 0.f;
  if (kk < 520) {
    int h = kk / 65, c = kk - h * 65;
    v = opair[(((size_t)(b * 8 + h) * 256) + n) * 65 + c];
  } else if (kk < 1032) {
    int k2 = kk - 520;
    int h = k2 >> 6, d = k2 & 63;
    v = o[(((size_t)(b * 8 + h) * 256) + n) * 64 + d];
  }
  cat[idx] = __float2bfloat16(v);
}

__device__ __forceinline__ float lnReduceSum(float v, float* red) {
#pragma unroll
  for (int o = 32; o > 0; o >>= 1) v += __shfl_xor(v, o, 64);
  int w = threadIdx.x >> 6;
  __syncthreads();
  if ((threadIdx.x & 63) == 0) red[w] = v;
  __syncthreads();
  return red[0] + red[1] + red[2] + red[3];
}

// ---------------- out = LayerNorm(x1 + sum_s xp[s]) * g + b ---------------
__global__ __launch_bounds__(256) void ln_sum(
    const float* __restrict__ x1, const float* __restrict__ xp,
    int S, int stride, const float* __restrict__ g,
    const float* __restrict__ bta, float* __restrict__ out,
    __hip_bfloat16* __restrict__ out_bf) {
  __shared__ float red[4];
  int row = blockIdx.x, tid = threadIdx.x;
  size_t base = (size_t)row * 512;
  float v0 = x1[base + tid];
  float v1 = x1[base + tid + 256];
  for (int s = 0; s < S; ++s) {
    v0 += xp[(size_t)s * stride + base + tid];
    v1 += xp[(size_t)s * stride + base + tid + 256];
  }
  float su = lnReduceSum(v0 + v1, red);
  float sq = lnReduceSum(v0 * v0 + v1 * v1, red);
  float mean = su * (1.f / 512.f);
  float var = sq * (1.f / 512.f) - mean * mean;
  float inv = rsqrtf(var + 1e-5f);
  float o0 = (v0 - mean) * inv * g[tid] + bta[tid];
  float o1 = (v1 - mean) * inv * g[tid + 256] + bta[tid + 256];
  out[base + tid]       = o0;
  out[base + tid + 256] = o1;
  if (out_bf) {
    out_bf[base + tid]       = __float2bfloat16(o0);
    out_bf[base + tid + 256] = __float2bfloat16(o1);
  }
}

extern "C" void kernel_launch(void* const* d_in, const int* in_sizes, int n_in,
                              void* d_out, int out_size, void* d_ws, size_t ws_size,
                              hipStream_t stream) {
  const float* s     = (const float*)d_in[0];
  const int*   masks = (const int*)d_in[1];
  const float* wq = (const float*)d_in[2];
  const float* wk = (const float*)d_in[3];
  const float* wv = (const float*)d_in[4];
  const float* wb = (const float*)d_in[5];
  const float* wo = (const float*)d_in[6];
  const float* bo = (const float*)d_in[7];
  const float* ln1_g = (const float*)d_in[8];
  const float* ln1_b = (const float*)d_in[9];
  const float* w1 = (const float*)d_in[10];
  const float* b1 = (const float*)d_in[11];
  const float* w2 = (const float*)d_in[12];
  const float* b2 = (const float*)d_in[13];
  const float* ln2_g = (const float*)d_in[14];
  const float* ln2_b = (const float*)d_in[15];

  float* out_x = (float*)d_out;              // [8,256,512]
  float* out_a = out_x + 1048576;            // [8,8,256,256]

  // disjoint workspace layout (float offsets); ws >= ~268 MB per fill size
  float* ws = (float*)d_ws;
  float* embd_part = ws + 0;                               // [4][2048,512]
  float* xbuf      = ws + 4194304;
  float* ff_part   = ws + 5242880;                         // [4][2048,512]
  float* obuf      = ws + 9437184;
  float* opair     = ws + 10485760;                        // [64,256,65]
  ushort* qkv_bf   = (ushort*)(ws + 11550720);             // q|k [B,H,N,D], v [B,H,D,N]
  ushort* q_bf = qkv_bf;
  ushort* k_bf = qkv_bf + 1048576;
  ushort* v_bf = qkv_bf + 2097152;
  ushort* a_bf     = (ushort*)(ws + 13123584);             // [64,256,256]
  __hip_bfloat16* h_bf   = (__hip_bfloat16*)(ws + 15220736);  // [2048,2048]
  __hip_bfloat16* s_bf   = (__hip_bfloat16*)(ws + 17317888);  // [2048,512]
  __hip_bfloat16* x_bf   = (__hip_bfloat16*)(ws + 17842176);  // [2048,512]
  __hip_bfloat16* cat_bf = (__hip_bfloat16*)(ws + 18366464);  // [2048,1088]
  __hip_bfloat16* wqkvT  = (__hip_bfloat16*)(ws + 19480576);  // [1536,512]
  __hip_bfloat16* wopT   = (__hip_bfloat16*)(ws + 19873792);  // [512,1088]
  __hip_bfloat16* w1T    = (__hip_bfloat16*)(ws + 20152320);  // [2048,512]
  __hip_bfloat16* w2T    = (__hip_bfloat16*)(ws + 20676608);  // [512,2048]

  dim3 blk(256);
  // 0. prep: s -> bf16; all weight transposes in one dispatch
  cvt_bf16<<<dim3(1024), blk, 0, stream>>>(s, s_bf, 262144);
  transpose_all<<<dim3(3360), blk, 0, stream>>>(wq, wk, wv, wo, w1, w2,
                                                wqkvT, wopT, w1T, w2T);
  // 1. QKV projection -> bf16 head layout (q,k) + transposed v
  gemm_bf16<<<dim3(12, 16, 1), blk, 0, stream>>>(
      (const ushort*)s_bf, (const ushort*)wqkvT, nullptr, nullptr,
      qkv_bf, 2048, 1536, 512, 16);
  // 2. attention -> a (f32 out + bf16), o_pair
  attn_mfma<<<dim3(256), blk, 0, stream>>>(q_bf, k_bf, masks, wb,
                                           out_a, a_bf, opair);
  // 3. o = a @ v via MFMA
  av_mfma<<<dim3(2, 64), blk, 0, stream>>>(a_bf, v_bf, obuf);
  // 4. concat pack + output projection (split-K=4)
  pack_cat<<<dim3(8704), blk, 0, stream>>>(opair, obuf, cat_bf);
  gemm_bf16<<<dim3(4, 16, 4), blk, 0, stream>>>(
      (const ushort*)cat_bf, (const ushort*)wopT, bo, embd_part, nullptr,
      2048, 512, 1088, 1 | 8);
  // 5. x = LN(s + sum embd_part)
  ln_sum<<<dim3(2048), blk, 0, stream>>>(s, embd_part, 4, 1048576,
                                         ln1_g, ln1_b, xbuf, x_bf);
  // 6. FFN
  gemm_bf16<<<dim3(16, 16, 1), blk, 0, stream>>>(
      (const ushort*)x_bf, (const ushort*)w1T, b1, nullptr, (ushort*)h_bf,
      2048, 2048, 512, 1 | 2 | 4);
  gemm_bf16<<<dim3(4, 16, 4), blk, 0, stream>>>(
      (const ushort*)h_bf, (const ushort*)w2T, b2, ff_part, nullptr,
      2048, 512, 2048, 1 | 8);
  // 7. out = LN(x + sum ff_part)
  ln_sum<<<dim3(2048), blk, 0, stream>>>(xbuf, ff_part, 4, 1048576,
                                         ln2_g, ln2_b, out_x, nullptr);
}

// Round 7
// 197.093 us; speedup vs baseline: 2.8464x; 1.0515x over previous
//
#include <hip/hip_runtime.h>
#include <hip/hip_bf16.h>
#include <cstdint>

#define B_ 8
#define N_ 256
#define CS_ 512
#define H_ 8
#define D_ 64
#define K_ 32
#define NB_ 65
#define CT_ 2048
#define WL_ 0.70710678118654752f

typedef __attribute__((ext_vector_type(8))) short bf16x8;
typedef __attribute__((ext_vector_type(4))) float f32x4;

#define GLOBAL_AS __attribute__((address_space(1)))
#define LDS_AS __attribute__((address_space(3)))

__device__ __forceinline__ void async16(void* lds, const void* g) {
  __builtin_amdgcn_global_load_lds((const GLOBAL_AS uint32_t*)g,
                                   (LDS_AS uint32_t*)lds, 16, 0, 0);
}

__device__ __forceinline__ ushort f2bf(float v) {
  __hip_bfloat16 hb = __float2bfloat16(v);
  return *(ushort*)&hb;
}

// ---------------- bf16 MFMA GEMM: C[M,N] = A[M,K] @ Bt[N,K]^T -------------
// flags: 1=+bias[col] (slice 0 only), 2=relu, 4=write bf16 Cb, 8=write f32 C
//        (offset by slice z*M*Nc), 16=qkv scatter with permuted cols
//        (col = which*512 + h*64 + d); q,k -> [B,H,N,D], v -> [B,H,D,N].
// Split-K via gridDim.z.
__global__ __launch_bounds__(256) void gemm_bf16(
    const ushort* __restrict__ A, const ushort* __restrict__ Bt,
    const float* __restrict__ bias, float* __restrict__ C,
    ushort* __restrict__ Cb, int M, int Nc, int Kd, int flags) {
  __shared__ ushort As[128 * 64];
  __shared__ ushort Bs[128 * 64];
  int tid = threadIdx.x;
  int bm = blockIdx.y * 128, bn = blockIdx.x * 128;
  int S = gridDim.z, z = blockIdx.z;
  int T = Kd >> 6;
  int it0 = (z * T) / S, it1 = ((z + 1) * T) / S;
  if (flags & 8) C += (size_t)z * M * Nc;
  int w = tid >> 6, l = tid & 63;
  int wr = (w >> 1) * 64, wc = (w & 1) * 64;
  int lm = l & 15, lq = l >> 4;
  int srow = tid >> 3;
  int sg = tid & 7;

  f32x4 acc[4][4];
#pragma unroll
  for (int i = 0; i < 4; ++i)
#pragma unroll
    for (int j = 0; j < 4; ++j) acc[i][j] = (f32x4){0.f, 0.f, 0.f, 0.f};

  for (int it = it0; it < it1; ++it) {
    int k0 = it << 6;
    __syncthreads();
#pragma unroll
    for (int r = 0; r < 4; ++r) {
      int row = r * 32 + srow;
      int gl = sg ^ (row & 7);
      async16(&As[row * 64 + sg * 8],
              A + (size_t)(bm + row) * Kd + k0 + gl * 8);
      async16(&Bs[row * 64 + sg * 8],
              Bt + (size_t)(bn + row) * Kd + k0 + gl * 8);
    }
    __syncthreads();
#pragma unroll
    for (int kk = 0; kk < 2; ++kk) {
      bf16x8 af[4], bfr[4];
#pragma unroll
      for (int i = 0; i < 4; ++i) {
        int ma = wr + 16 * i + lm;
        af[i] = *(const bf16x8*)&As[ma * 64 + ((kk * 4 + lq) ^ (ma & 7)) * 8];
        int nb = wc + 16 * i + lm;
        bfr[i] = *(const bf16x8*)&Bs[nb * 64 + ((kk * 4 + lq) ^ (nb & 7)) * 8];
      }
#pragma unroll
      for (int i = 0; i < 4; ++i)
#pragma unroll
        for (int j = 0; j < 4; ++j)
          acc[i][j] = __builtin_amdgcn_mfma_f32_16x16x32_bf16(
              af[i], bfr[j], acc[i][j], 0, 0, 0);
    }
  }
#pragma unroll
  for (int j = 0; j < 4; ++j) {
    int col = bn + wc + 16 * j + lm;
    float bv = ((flags & 1) && z == 0) ? bias[col] : 0.f;
#pragma unroll
    for (int i = 0; i < 4; ++i) {
#pragma unroll
      for (int r = 0; r < 4; ++r) {
        int row = bm + wr + 16 * i + lq * 4 + r;
        float v = acc[i][j][r] + bv;
        if (flags & 2) v = fmaxf(v, 0.f);
        if (flags & 8) C[(size_t)row * Nc + col] = v;
        if (flags & 4) Cb[(size_t)row * Nc + col] = f2bf(v);
        if (flags & 16) {
          int which = col >> 9, c = col & 511;
          int hh = c >> 6, d2 = c & 63;
          int bb = row >> 8, nn = row & 255;
          size_t dst;
          if (which == 2)  // v transposed [B,H,D,N]
            dst = (size_t)2 * 1048576 + (((size_t)(bb * 8 + hh) * 64) + d2) * 256 + nn;
          else
            dst = (size_t)which * 1048576 + (((size_t)(bb * 8 + hh) * 256) + nn) * 64 + d2;
          Cb[dst] = f2bf(v);
        }
      }
    }
  }
}

// ---------------- prep: s->bf16 + all weight transposes, one dispatch -----
// blocks [0,1024): cvt s; [1024,1792): wq/wk/wv (col-permuted h*64+d);
// [1792,2336): wo; [2336,3360): w1; [3360,4384): w2
__global__ __launch_bounds__(256) void prep_all(
    const float* __restrict__ s, __hip_bfloat16* __restrict__ s_bf,
    const float* __restrict__ wq, const float* __restrict__ wk,
    const float* __restrict__ wv, const float* __restrict__ wo,
    const float* __restrict__ w1, const float* __restrict__ w2,
    __hip_bfloat16* __restrict__ wqkvT, __hip_bfloat16* __restrict__ wopT,
    __hip_bfloat16* __restrict__ w1T, __hip_bfloat16* __restrict__ w2T) {
  int blk = blockIdx.x;
  if (blk < 1024) {
    int i = blk * 256 + threadIdx.x;
    float4 v = ((const float4*)s)[i];
    s_bf[i * 4 + 0] = __float2bfloat16(v.x);
    s_bf[i * 4 + 1] = __float2bfloat16(v.y);
    s_bf[i * 4 + 2] = __float2bfloat16(v.z);
    s_bf[i * 4 + 3] = __float2bfloat16(v.w);
    return;
  }
  blk -= 1024;
  __shared__ float tile[32][33];
  const float* src;
  __hip_bfloat16* dst;
  int R, C, Kpad, tX, tIdx, whichBase = -1;
  if (blk < 768) {
    int zz = blk >> 8; tIdx = blk & 255;
    src = zz == 0 ? wq : zz == 1 ? wk : wv;
    dst = wqkvT; whichBase = zz * 512; R = 512; C = 512; Kpad = 512; tX = 16;
  } else if (blk < 1312) {
    tIdx = blk - 768; src = wo; dst = wopT; R = 1032; C = 512; Kpad = 1088; tX = 16;
  } else if (blk < 2336) {
    tIdx = blk - 1312; src = w1; dst = w1T; R = 512; C = 2048; Kpad = 512; tX = 64;
  } else {
    tIdx = blk - 2336; src = w2; dst = w2T; R = 2048; C = 512; Kpad = 2048; tX = 16;
  }
  int c0 = (tIdx % tX) * 32, r0 = (tIdx / tX) * 32;
  int tx = threadIdx.x & 31, ty = threadIdx.x >> 5;
#pragma unroll
  for (int yy = 0; yy < 32; yy += 8) {
    int r = r0 + ty + yy, c = c0 + tx;
    tile[ty + yy][tx] = (r < R && c < C) ? src[(size_t)r * C + c] : 0.f;
  }
  __syncthreads();
#pragma unroll
  for (int yy = 0; yy < 32; yy += 8) {
    int cc = c0 + ty + yy, k = r0 + tx;
    if (cc < C && k < Kpad) {
      int n = (whichBase >= 0) ? (whichBase + (cc & 7) * 64 + (cc >> 3)) : cc;
      dst[(size_t)n * Kpad + k] = __float2bfloat16(tile[tx][ty + yy]);
    }
  }
}

// ---------------- fused attention: QK^T+softmax -> a, PV -> o, o_pair -----
// 256 blocks = (bh:64) x (64-row strip:4); wave w owns 16 full rows.
// Epilogue writes o and o_pair straight into cat_bf [2048,1088] bf16.
__global__ __launch_bounds__(256) void attn_fused(
    const ushort* __restrict__ qh, const ushort* __restrict__ kh,
    const ushort* __restrict__ vT, const int* __restrict__ masks,
    const float* __restrict__ wb, float* __restrict__ a_out,
    ushort* __restrict__ cat) {
  int strip = blockIdx.x & 3, bh = blockIdx.x >> 2;
  int h = bh & 7, b = bh >> 3;
  __shared__ ushort lds[20480];   // 40 KB: Ks[16384] + Qs[4096]; reused as Vh+Ps
  __shared__ float wbs[NB_];
  __shared__ float mfj[256];
  ushort* Ks = lds;
  ushort* Qs = lds + 16384;
  ushort* Vh = lds;               // overlay after QK^T
  ushort* Ps = lds + 8192;
  int tid = threadIdx.x;
  int srow = tid >> 3, sg = tid & 7;
#pragma unroll
  for (int rr = 0; rr < 8; ++rr) {
    int row = rr * 32 + srow;
    int gl = sg ^ (row & 7);
    async16(&Ks[row * 64 + sg * 8],
            kh + ((size_t)bh * 256 + row) * 64 + gl * 8);
  }
#pragma unroll
  for (int rr = 0; rr < 2; ++rr) {
    int row = rr * 32 + srow;
    int gl = sg ^ (row & 7);
    async16(&Qs[row * 64 + sg * 8],
            qh + ((size_t)bh * 256 + strip * 64 + row) * 64 + gl * 8);
  }
  if (tid < NB_) wbs[tid] = wb[tid * H_ + h];
  mfj[tid] = (masks[b * 256 + tid] != 0) ? 1.f : 0.f;
  __syncthreads();

  int w = tid >> 6, l = tid & 63, lm = l & 15, lq = l >> 4;
  bf16x8 qf[2];
#pragma unroll
  for (int kk = 0; kk < 2; ++kk) {
    int qrow = w * 16 + lm;
    qf[kk] = *(const bf16x8*)&Qs[qrow * 64 + ((kk * 4 + lq) ^ (qrow & 7)) * 8];
  }
  f32x4 acc[16];
#pragma unroll
  for (int ct = 0; ct < 16; ++ct) {
    int krow = ct * 16 + lm;
    bf16x8 kf0 = *(const bf16x8*)&Ks[krow * 64 + ((lq) ^ (krow & 7)) * 8];
    bf16x8 kf1 = *(const bf16x8*)&Ks[krow * 64 + ((4 + lq) ^ (krow & 7)) * 8];
    f32x4 zf = (f32x4){0.f, 0.f, 0.f, 0.f};
    zf = __builtin_amdgcn_mfma_f32_16x16x32_bf16(qf[0], kf0, zf, 0, 0, 0);
    acc[ct] = __builtin_amdgcn_mfma_f32_16x16x32_bf16(qf[1], kf1, zf, 0, 0, 0);
  }
  int ibase = strip * 64 + w * 16 + lq * 4;   // global row i of element r
  float mfi[4];
#pragma unroll
  for (int r = 0; r < 4; ++r) mfi[r] = mfj[ibase + r];
#pragma unroll
  for (int ct = 0; ct < 16; ++ct) {
    int j = ct * 16 + lm;
    float mj = mfj[j];
#pragma unroll
    for (int r = 0; r < 4; ++r) {
      int i = ibase + r;
      int diff = i - j;
      int cb = diff < -K_ ? 0 : (diff > K_ ? 2 * K_ : diff + K_);
      float sq = mfi[r] * mj;
      acc[ct][r] = WL_ * (acc[ct][r] * 0.125f + wbs[cb] * sq) - 1e9f * (1.f - sq);
    }
  }
  float mx[4], sm[4];
#pragma unroll
  for (int r = 0; r < 4; ++r) {
    float m = acc[0][r];
#pragma unroll
    for (int ct = 1; ct < 16; ++ct) m = fmaxf(m, acc[ct][r]);
#pragma unroll
    for (int o = 1; o < 16; o <<= 1) m = fmaxf(m, __shfl_xor(m, o, 64));
    mx[r] = m;
  }
#pragma unroll
  for (int ct = 0; ct < 16; ++ct)
#pragma unroll
    for (int r = 0; r < 4; ++r) acc[ct][r] = __expf(acc[ct][r] - mx[r]);
#pragma unroll
  for (int r = 0; r < 4; ++r) {
    float s = 0.f;
#pragma unroll
    for (int ct = 0; ct < 16; ++ct) s += acc[ct][r];
#pragma unroll
    for (int o = 1; o < 16; o <<= 1) s += __shfl_xor(s, o, 64);
    sm[r] = 1.f / s;
  }
  // ---- a stores (f32) + o_pair into cat (bf16) ----
  float p0[4] = {0.f, 0.f, 0.f, 0.f}, p64[4] = {0.f, 0.f, 0.f, 0.f};
#pragma unroll
  for (int ct = 0; ct < 16; ++ct) {
    int j = ct * 16 + lm;
    float mj = mfj[j];
#pragma unroll
    for (int r = 0; r < 4; ++r) {
      int i = ibase + r;
      float aval = acc[ct][r] * sm[r];
      a_out[((size_t)bh * 256 + i) * 256 + j] = aval;
      float val = aval * mfi[r] * mj;
      int diff = i - j;
      if (diff <= -K_)      p0[r] += val;
      else if (diff >= K_)  p64[r] += val;
      else cat[((size_t)(b * 256 + i)) * 1088 + h * 65 + diff + K_] = f2bf(val);
    }
  }
#pragma unroll
  for (int r = 0; r < 4; ++r)
#pragma unroll
    for (int o = 1; o < 16; o <<= 1) {
      p0[r]  += __shfl_xor(p0[r], o, 64);
      p64[r] += __shfl_xor(p64[r], o, 64);
    }
  if (lm == 0) {
#pragma unroll
    for (int r = 0; r < 4; ++r) {
      int i = ibase + r;
      cat[((size_t)(b * 256 + i)) * 1088 + h * 65 + 0]      = f2bf(p0[r]);
      cat[((size_t)(b * 256 + i)) * 1088 + h * 65 + 2 * K_] = f2bf(p64[r]);
    }
  }
  // interior bins with out-of-range source j -> 0
#pragma unroll
  for (int r = 0; r < 4; ++r) {
    int i = ibase + r;
#pragma unroll
    for (int t = 0; t < 4; ++t) {
      int c = 1 + lm + 16 * t;
      if (c < 64) {
        int j = i - c + K_;
        if (j < 0 || j > 255)
          cat[((size_t)(b * 256 + i)) * 1088 + h * 65 + c] = 0;
      }
    }
  }
  // pad cols 1032..1088 zeroed once per (b,strip) by h==0 blocks
  if (h == 0) {
    for (int idx = tid; idx < 64 * 56; idx += 256) {
      int r = idx / 56, c = 1032 + idx - r * 56 * 1 - (idx / 56) * 0;  // c = 1032 + idx%56
      c = 1032 + (idx - r * 56);
      cat[((size_t)(b * 256 + strip * 64 + r)) * 1088 + c] = 0;
    }
  }
  // ---- PV: o = a @ V, two K-halves through reused LDS ----
  __syncthreads();   // everyone done reading Ks/Qs
  f32x4 acc2[4];
#pragma unroll
  for (int nt = 0; nt < 4; ++nt) acc2[nt] = (f32x4){0.f, 0.f, 0.f, 0.f};
  int vrow_ = tid >> 4, vsg = tid & 15;   // V staging: 16 rows x 16 granules/round
#pragma unroll
  for (int hf = 0; hf < 2; ++hf) {
    if (hf == 1) __syncthreads();   // done reading previous half
    // stage V half: Vh[d][0..128) = vT[bh][d][hf*128 ..)
#pragma unroll
    for (int rr = 0; rr < 4; ++rr) {
      int d = rr * 16 + vrow_;
      int gl = vsg ^ (d & 7);
      async16(&Vh[d * 128 + vsg * 8],
              vT + (size_t)bh * 16384 + d * 256 + hf * 128 + gl * 8);
    }
    // write own P rows (bf16, swizzled) — no cross-wave dependency
#pragma unroll
    for (int cl = 0; cl < 8; ++cl) {
      int ct = hf * 8 + cl;
#pragma unroll
      for (int r = 0; r < 4; ++r) {
        int rowl = w * 16 + lq * 4 + r;                 // local row 0..63
        float aval = acc[ct][r] * sm[r];
        int g = cl * 2 + (lm >> 3);
        Ps[rowl * 128 + ((g ^ (rowl & 7)) << 3) + (lm & 7)] = f2bf(aval);
      }
    }
    __syncthreads();   // V staged (vmcnt) + P written (lgkm)
#pragma unroll
    for (int kst = 0; kst < 4; ++kst) {
      int prow = w * 16 + lm;
      bf16x8 af = *(const bf16x8*)&Ps[prow * 128 + (((kst * 4 + lq) ^ (prow & 7)) << 3)];
#pragma unroll
      for (int nt = 0; nt < 4; ++nt) {
        int d = nt * 16 + lm;
        bf16x8 bfr = *(const bf16x8*)&Vh[d * 128 + (((kst * 4 + lq) ^ (d & 7)) << 3)];
        acc2[nt] = __builtin_amdgcn_mfma_f32_16x16x32_bf16(af, bfr, acc2[nt], 0, 0, 0);
      }
    }
  }
  // o -> cat[row][520 + h*64 + d]
#pragma unroll
  for (int nt = 0; nt < 4; ++nt) {
    int d = nt * 16 + lm;
#pragma unroll
    for (int r = 0; r < 4; ++r) {
      int i = ibase + r;
      cat[((size_t)(b * 256 + i)) * 1088 + 520 + h * 64 + d] = f2bf(acc2[nt][r]);
    }
  }
}

__device__ __forceinline__ float lnReduceSum(float v, float* red) {
#pragma unroll
  for (int o = 32; o > 0; o >>= 1) v += __shfl_xor(v, o, 64);
  int w = threadIdx.x >> 6;
  __syncthreads();
  if ((threadIdx.x & 63) == 0) red[w] = v;
  __syncthreads();
  return red[0] + red[1] + red[2] + red[3];
}

// ---------------- out = LayerNorm(x1 + sum_s xp[s]) * g + b ---------------
__global__ __launch_bounds__(256) void ln_sum(
    const float* __restrict__ x1, const float* __restrict__ xp,
    int S, int stride, const float* __restrict__ g,
    const float* __restrict__ bta, float* __restrict__ out,
    __hip_bfloat16* __restrict__ out_bf) {
  __shared__ float red[4];
  int row = blockIdx.x, tid = threadIdx.x;
  size_t base = (size_t)row * 512;
  float v0 = x1[base + tid];
  float v1 = x1[base + tid + 256];
  for (int s = 0; s < S; ++s) {
    v0 += xp[(size_t)s * stride + base + tid];
    v1 += xp[(size_t)s * stride + base + tid + 256];
  }
  float su = lnReduceSum(v0 + v1, red);
  float sq = lnReduceSum(v0 * v0 + v1 * v1, red);
  float mean = su * (1.f / 512.f);
  float var = sq * (1.f / 512.f) - mean * mean;
  float inv = rsqrtf(var + 1e-5f);
  float o0 = (v0 - mean) * inv * g[tid] + bta[tid];
  float o1 = (v1 - mean) * inv * g[tid + 256] + bta[tid + 256];
  out[base + tid]       = o0;
  out[base + tid + 256] = o1;
  if (out_bf) {
    out_bf[base + tid]       = __float2bfloat16(o0);
    out_bf[base + tid + 256] = __float2bfloat16(o1);
  }
}

extern "C" void kernel_launch(void* const* d_in, const int* in_sizes, int n_in,
                              void* d_out, int out_size, void* d_ws, size_t ws_size,
                              hipStream_t stream) {
  const float* s     = (const float*)d_in[0];
  const int*   masks = (const int*)d_in[1];
  const float* wq = (const float*)d_in[2];
  const float* wk = (const float*)d_in[3];
  const float* wv = (const float*)d_in[4];
  const float* wb = (const float*)d_in[5];
  const float* wo = (const float*)d_in[6];
  const float* bo = (const float*)d_in[7];
  const float* ln1_g = (const float*)d_in[8];
  const float* ln1_b = (const float*)d_in[9];
  const float* w1 = (const float*)d_in[10];
  const float* b1 = (const float*)d_in[11];
  const float* w2 = (const float*)d_in[12];
  const float* b2 = (const float*)d_in[13];
  const float* ln2_g = (const float*)d_in[14];
  const float* ln2_b = (const float*)d_in[15];

  float* out_x = (float*)d_out;              // [8,256,512]
  float* out_a = out_x + 1048576;            // [8,8,256,256]

  // disjoint workspace (float offsets)
  float* ws = (float*)d_ws;
  float* embd_part = ws + 0;                               // [4][2048,512]
  float* xbuf      = ws + 4194304;
  float* ff_part   = ws + 5242880;                         // [4][2048,512]
  ushort* qkv_bf   = (ushort*)(ws + 9437184);              // q|k [B,H,N,D], v [B,H,D,N]
  ushort* q_bf = qkv_bf;
  ushort* k_bf = qkv_bf + 1048576;
  ushort* v_bf = qkv_bf + 2097152;
  ushort* cat_bf = (ushort*)(ws + 10223616);               // [2048,1088]
  __hip_bfloat16* h_bf  = (__hip_bfloat16*)(ws + 11337728);  // [2048,2048]
  __hip_bfloat16* s_bf  = (__hip_bfloat16*)(ws + 13434880);  // [2048,512]
  __hip_bfloat16* x_bf  = (__hip_bfloat16*)(ws + 13959168);  // [2048,512]
  __hip_bfloat16* wqkvT = (__hip_bfloat16*)(ws + 14483456);  // [1536,512]
  __hip_bfloat16* wopT  = (__hip_bfloat16*)(ws + 14876672);  // [512,1088]
  __hip_bfloat16* w1T   = (__hip_bfloat16*)(ws + 15155200);  // [2048,512]
  __hip_bfloat16* w2T   = (__hip_bfloat16*)(ws + 15679488);  // [512,2048]

  dim3 blk(256);
  // 0. prep: s cvt + all weight transposes, one dispatch
  prep_all<<<dim3(4384), blk, 0, stream>>>(s, s_bf, wq, wk, wv, wo, w1, w2,
                                           wqkvT, wopT, w1T, w2T);
  // 1. QKV projection -> bf16 head layout (q,k) + transposed v
  gemm_bf16<<<dim3(12, 16, 1), blk, 0, stream>>>(
      (const ushort*)s_bf, (const ushort*)wqkvT, nullptr, nullptr,
      qkv_bf, 2048, 1536, 512, 16);
  // 2. fused attention: a -> d_out, o + o_pair -> cat_bf
  attn_fused<<<dim3(256), blk, 0, stream>>>(q_bf, k_bf, v_bf, masks, wb,
                                            out_a, cat_bf);
  // 3. output projection (split-K=4)
  gemm_bf16<<<dim3(4, 16, 4), blk, 0, stream>>>(
      cat_bf, (const ushort*)wopT, bo, embd_part, nullptr,
      2048, 512, 1088, 1 | 8);
  // 4. x = LN(s + sum embd_part)
  ln_sum<<<dim3(2048), blk, 0, stream>>>(s, embd_part, 4, 1048576,
                                         ln1_g, ln1_b, xbuf, x_bf);
  // 5. FFN
  gemm_bf16<<<dim3(16, 16, 1), blk, 0, stream>>>(
      (const ushort*)x_bf, (const ushort*)w1T, b1, nullptr, (ushort*)h_bf,
      2048, 2048, 512, 1 | 2 | 4);
  gemm_bf16<<<dim3(4, 16, 4), blk, 0, stream>>>(
      (const ushort*)h_bf, (const ushort*)w2T, b2, ff_part, nullptr,
      2048, 512, 2048, 1 | 8);
  // 6. out = LN(x + sum ff_part)
  ln_sum<<<dim3(2048), blk, 0, stream>>>(xbuf, ff_part, 4, 1048576,
                                         ln2_g, ln2_b, out_x, nullptr);
}

// Round 8
// 194.692 us; speedup vs baseline: 2.8815x; 1.0123x over previous
//
#include <hip/hip_runtime.h>
#include <hip/hip_bf16.h>
#include <cstdint>

#define B_ 8
#define N_ 256
#define CS_ 512
#define H_ 8
#define D_ 64
#define K_ 32
#define NB_ 65
#define CT_ 2048
#define WL_ 0.70710678118654752f

typedef __attribute__((ext_vector_type(8))) short bf16x8;
typedef __attribute__((ext_vector_type(4))) float f32x4;

#define GLOBAL_AS __attribute__((address_space(1)))
#define LDS_AS __attribute__((address_space(3)))

__device__ __forceinline__ void async16(void* lds, const void* g) {
  __builtin_amdgcn_global_load_lds((const GLOBAL_AS uint32_t*)g,
                                   (LDS_AS uint32_t*)lds, 16, 0, 0);
}

__device__ __forceinline__ ushort f2bf(float v) {
  __hip_bfloat16 hb = __float2bfloat16(v);
  return *(ushort*)&hb;
}

// ---------------- bf16 MFMA GEMM: C[M,N] = A[M,K] @ Bt[N,K]^T -------------
// 64x128 tile, 128 threads (2 waves) -> 2 blocks/CU for barrier overlap.
// flags: 1=+bias[col] (slice 0 only), 2=relu, 4=write bf16 Cb, 8=write f32 C
//        (offset z*M*Nc), 16=qkv scatter (col = which*512 + h*64 + d);
//        q,k -> [B,H,N,D], v -> [B,H,D,N].  Split-K via gridDim.z.
__global__ __launch_bounds__(128) void gemm_bf16(
    const ushort* __restrict__ A, const ushort* __restrict__ Bt,
    const float* __restrict__ bias, float* __restrict__ C,
    ushort* __restrict__ Cb, int M, int Nc, int Kd, int flags) {
  __shared__ ushort As[64 * 64];    // 8 KB
  __shared__ ushort Bs[128 * 64];   // 16 KB
  int tid = threadIdx.x;
  int bm = blockIdx.y * 64, bn = blockIdx.x * 128;
  int S = gridDim.z, z = blockIdx.z;
  int T = Kd >> 6;
  int it0 = (z * T) / S, it1 = ((z + 1) * T) / S;
  if (flags & 8) C += (size_t)z * M * Nc;
  int w = tid >> 6, l = tid & 63;
  int lm = l & 15, lq = l >> 4;
  int srow = tid >> 3;       // 0..15
  int sg = tid & 7;

  f32x4 acc[4][4];           // i: 16-row tile (rows 16i), j: 16-col tile in wave's 64
#pragma unroll
  for (int i = 0; i < 4; ++i)
#pragma unroll
    for (int j = 0; j < 4; ++j) acc[i][j] = (f32x4){0.f, 0.f, 0.f, 0.f};

  for (int it = it0; it < it1; ++it) {
    int k0 = it << 6;
    __syncthreads();
#pragma unroll
    for (int r = 0; r < 4; ++r) {
      int row = r * 16 + srow;
      int gl = sg ^ (row & 7);
      async16(&As[row * 64 + sg * 8],
              A + (size_t)(bm + row) * Kd + k0 + gl * 8);
    }
#pragma unroll
    for (int r = 0; r < 8; ++r) {
      int row = r * 16 + srow;
      int gl = sg ^ (row & 7);
      async16(&Bs[row * 64 + sg * 8],
              Bt + (size_t)(bn + row) * Kd + k0 + gl * 8);
    }
    __syncthreads();
#pragma unroll
    for (int kk = 0; kk < 2; ++kk) {
      bf16x8 af[4], bfr[4];
#pragma unroll
      for (int i = 0; i < 4; ++i) {
        int ma = 16 * i + lm;
        af[i] = *(const bf16x8*)&As[ma * 64 + ((kk * 4 + lq) ^ (ma & 7)) * 8];
        int nb = w * 64 + 16 * i + lm;
        bfr[i] = *(const bf16x8*)&Bs[nb * 64 + ((kk * 4 + lq) ^ (nb & 7)) * 8];
      }
#pragma unroll
      for (int i = 0; i < 4; ++i)
#pragma unroll
        for (int j = 0; j < 4; ++j)
          acc[i][j] = __builtin_amdgcn_mfma_f32_16x16x32_bf16(
              af[i], bfr[j], acc[i][j], 0, 0, 0);
    }
  }
#pragma unroll
  for (int j = 0; j < 4; ++j) {
    int col = bn + w * 64 + 16 * j + lm;
    float bv = ((flags & 1) && z == 0) ? bias[col] : 0.f;
#pragma unroll
    for (int i = 0; i < 4; ++i) {
#pragma unroll
      for (int r = 0; r < 4; ++r) {
        int row = bm + 16 * i + lq * 4 + r;
        float v = acc[i][j][r] + bv;
        if (flags & 2) v = fmaxf(v, 0.f);
        if (flags & 8) C[(size_t)row * Nc + col] = v;
        if (flags & 4) Cb[(size_t)row * Nc + col] = f2bf(v);
        if (flags & 16) {
          int which = col >> 9, c = col & 511;
          int hh = c >> 6, d2 = c & 63;
          int bb = row >> 8, nn = row & 255;
          size_t dst;
          if (which == 2)  // v transposed [B,H,D,N]
            dst = (size_t)2 * 1048576 + (((size_t)(bb * 8 + hh) * 64) + d2) * 256 + nn;
          else
            dst = (size_t)which * 1048576 + (((size_t)(bb * 8 + hh) * 256) + nn) * 64 + d2;
          Cb[dst] = f2bf(v);
        }
      }
    }
  }
}

// ---------------- prep: s->bf16 + all weight transposes, one dispatch -----
__global__ __launch_bounds__(256) void prep_all(
    const float* __restrict__ s, __hip_bfloat16* __restrict__ s_bf,
    const float* __restrict__ wq, const float* __restrict__ wk,
    const float* __restrict__ wv, const float* __restrict__ wo,
    const float* __restrict__ w1, const float* __restrict__ w2,
    __hip_bfloat16* __restrict__ wqkvT, __hip_bfloat16* __restrict__ wopT,
    __hip_bfloat16* __restrict__ w1T, __hip_bfloat16* __restrict__ w2T) {
  int blk = blockIdx.x;
  if (blk < 1024) {
    int i = blk * 256 + threadIdx.x;
    float4 v = ((const float4*)s)[i];
    s_bf[i * 4 + 0] = __float2bfloat16(v.x);
    s_bf[i * 4 + 1] = __float2bfloat16(v.y);
    s_bf[i * 4 + 2] = __float2bfloat16(v.z);
    s_bf[i * 4 + 3] = __float2bfloat16(v.w);
    return;
  }
  blk -= 1024;
  __shared__ float tile[32][33];
  const float* src;
  __hip_bfloat16* dst;
  int R, C, Kpad, tX, tIdx, whichBase = -1;
  if (blk < 768) {
    int zz = blk >> 8; tIdx = blk & 255;
    src = zz == 0 ? wq : zz == 1 ? wk : wv;
    dst = wqkvT; whichBase = zz * 512; R = 512; C = 512; Kpad = 512; tX = 16;
  } else if (blk < 1312) {
    tIdx = blk - 768; src = wo; dst = wopT; R = 1032; C = 512; Kpad = 1088; tX = 16;
  } else if (blk < 2336) {
    tIdx = blk - 1312; src = w1; dst = w1T; R = 512; C = 2048; Kpad = 512; tX = 64;
  } else {
    tIdx = blk - 2336; src = w2; dst = w2T; R = 2048; C = 512; Kpad = 2048; tX = 16;
  }
  int c0 = (tIdx % tX) * 32, r0 = (tIdx / tX) * 32;
  int tx = threadIdx.x & 31, ty = threadIdx.x >> 5;
#pragma unroll
  for (int yy = 0; yy < 32; yy += 8) {
    int r = r0 + ty + yy, c = c0 + tx;
    tile[ty + yy][tx] = (r < R && c < C) ? src[(size_t)r * C + c] : 0.f;
  }
  __syncthreads();
#pragma unroll
  for (int yy = 0; yy < 32; yy += 8) {
    int cc = c0 + ty + yy, k = r0 + tx;
    if (cc < C && k < Kpad) {
      int n = (whichBase >= 0) ? (whichBase + (cc & 7) * 64 + (cc >> 3)) : cc;
      dst[(size_t)n * Kpad + k] = __float2bfloat16(tile[tx][ty + yy]);
    }
  }
}

// ---------------- fused attention: QK^T+softmax -> a, PV -> o, o_pair -----
// 256 blocks = (bh:64) x (64-row strip:4); wave w owns 16 full rows.
// ONE barrier: Q/V fragments loaded straight from global into registers;
// P->A-layout via per-wave-private 8 KB k-quarter Ps (no cross-wave deps).
__global__ __launch_bounds__(256) void attn_fused(
    const ushort* __restrict__ qh, const ushort* __restrict__ kh,
    const ushort* __restrict__ vT, const int* __restrict__ masks,
    const float* __restrict__ wb, float* __restrict__ a_out,
    ushort* __restrict__ cat) {
  int strip = blockIdx.x & 3, bh = blockIdx.x >> 2;
  int h = bh & 7, b = bh >> 3;
  __shared__ ushort Ks[256 * 64];   // 32 KB
  __shared__ ushort Ps[64 * 64];    // 8 KB, k-quarter P (wave-private rows)
  __shared__ float wbs[NB_];
  __shared__ float mfj[256];
  int tid = threadIdx.x;
  int srow = tid >> 3, sg = tid & 7;
#pragma unroll
  for (int rr = 0; rr < 8; ++rr) {
    int row = rr * 32 + srow;
    int gl = sg ^ (row & 7);
    async16(&Ks[row * 64 + sg * 8],
            kh + ((size_t)bh * 256 + row) * 64 + gl * 8);
  }
  int w = tid >> 6, l = tid & 63, lm = l & 15, lq = l >> 4;
  // Q fragments direct from global (row = this wave's m-row, 2x16B)
  bf16x8 qf[2];
  {
    const ushort* qrow =
        qh + ((size_t)bh * 256 + strip * 64 + w * 16 + lm) * 64 + lq * 8;
    qf[0] = *(const bf16x8*)qrow;
    qf[1] = *(const bf16x8*)(qrow + 32);
  }
  if (tid < NB_) wbs[tid] = wb[tid * H_ + h];
  mfj[tid] = (masks[b * 256 + tid] != 0) ? 1.f : 0.f;
  __syncthreads();   // the only barrier

  f32x4 acc[16];
#pragma unroll
  for (int ct = 0; ct < 16; ++ct) {
    int krow = ct * 16 + lm;
    bf16x8 kf0 = *(const bf16x8*)&Ks[krow * 64 + ((lq) ^ (krow & 7)) * 8];
    bf16x8 kf1 = *(const bf16x8*)&Ks[krow * 64 + ((4 + lq) ^ (krow & 7)) * 8];
    f32x4 zf = (f32x4){0.f, 0.f, 0.f, 0.f};
    zf = __builtin_amdgcn_mfma_f32_16x16x32_bf16(qf[0], kf0, zf, 0, 0, 0);
    acc[ct] = __builtin_amdgcn_mfma_f32_16x16x32_bf16(qf[1], kf1, zf, 0, 0, 0);
  }
  int ibase = strip * 64 + w * 16 + lq * 4;
  float mfi[4];
#pragma unroll
  for (int r = 0; r < 4; ++r) mfi[r] = mfj[ibase + r];
#pragma unroll
  for (int ct = 0; ct < 16; ++ct) {
    int j = ct * 16 + lm;
    float mj = mfj[j];
#pragma unroll
    for (int r = 0; r < 4; ++r) {
      int i = ibase + r;
      int diff = i - j;
      int cb = diff < -K_ ? 0 : (diff > K_ ? 2 * K_ : diff + K_);
      float sq = mfi[r] * mj;
      acc[ct][r] = WL_ * (acc[ct][r] * 0.125f + wbs[cb] * sq) - 1e9f * (1.f - sq);
    }
  }
  float mx[4], sm[4];
#pragma unroll
  for (int r = 0; r < 4; ++r) {
    float m = acc[0][r];
#pragma unroll
    for (int ct = 1; ct < 16; ++ct) m = fmaxf(m, acc[ct][r]);
#pragma unroll
    for (int o = 1; o < 16; o <<= 1) m = fmaxf(m, __shfl_xor(m, o, 64));
    mx[r] = m;
  }
#pragma unroll
  for (int ct = 0; ct < 16; ++ct)
#pragma unroll
    for (int r = 0; r < 4; ++r) acc[ct][r] = __expf(acc[ct][r] - mx[r]);
#pragma unroll
  for (int r = 0; r < 4; ++r) {
    float s = 0.f;
#pragma unroll
    for (int ct = 0; ct < 16; ++ct) s += acc[ct][r];
#pragma unroll
    for (int o = 1; o < 16; o <<= 1) s += __shfl_xor(s, o, 64);
    sm[r] = 1.f / s;
  }
  // ---- a stores (f32) + o_pair into cat (bf16) ----
  float p0[4] = {0.f, 0.f, 0.f, 0.f}, p64[4] = {0.f, 0.f, 0.f, 0.f};
#pragma unroll
  for (int ct = 0; ct < 16; ++ct) {
    int j = ct * 16 + lm;
    float mj = mfj[j];
#pragma unroll
    for (int r = 0; r < 4; ++r) {
      int i = ibase + r;
      float aval = acc[ct][r] * sm[r];
      a_out[((size_t)bh * 256 + i) * 256 + j] = aval;
      float val = aval * mfi[r] * mj;
      int diff = i - j;
      if (diff <= -K_)      p0[r] += val;
      else if (diff >= K_)  p64[r] += val;
      else cat[((size_t)(b * 256 + i)) * 1088 + h * 65 + diff + K_] = f2bf(val);
    }
  }
#pragma unroll
  for (int r = 0; r < 4; ++r)
#pragma unroll
    for (int o = 1; o < 16; o <<= 1) {
      p0[r]  += __shfl_xor(p0[r], o, 64);
      p64[r] += __shfl_xor(p64[r], o, 64);
    }
  if (lm == 0) {
#pragma unroll
    for (int r = 0; r < 4; ++r) {
      int i = ibase + r;
      cat[((size_t)(b * 256 + i)) * 1088 + h * 65 + 0]      = f2bf(p0[r]);
      cat[((size_t)(b * 256 + i)) * 1088 + h * 65 + 2 * K_] = f2bf(p64[r]);
    }
  }
  // interior bins with out-of-range source j -> 0
#pragma unroll
  for (int r = 0; r < 4; ++r) {
    int i = ibase + r;
#pragma unroll
    for (int t = 0; t < 4; ++t) {
      int c = 1 + lm + 16 * t;
      if (c < 64) {
        int j = i - c + K_;
        if (j < 0 || j > 255)
          cat[((size_t)(b * 256 + i)) * 1088 + h * 65 + c] = 0;
      }
    }
  }
  // pad cols 1032..1088 zeroed once per (b,strip) by h==0 blocks
  if (h == 0) {
    for (int idx = tid; idx < 64 * 56; idx += 256) {
      int r = idx / 56, c = 1032 + (idx - r * 56);
      cat[((size_t)(b * 256 + strip * 64 + r)) * 1088 + c] = 0;
    }
  }
  // ---- PV: o = P @ V over 4 k-quarters; V frags direct from global ----
  f32x4 acc2[4];
#pragma unroll
  for (int nt = 0; nt < 4; ++nt) acc2[nt] = (f32x4){0.f, 0.f, 0.f, 0.f};
  const ushort* vbase = vT + (size_t)bh * 16384;
#pragma unroll
  for (int qt = 0; qt < 4; ++qt) {
    bf16x8 vf0[4], vf1[4];
#pragma unroll
    for (int nt = 0; nt < 4; ++nt) {
      const ushort* vrow = vbase + (size_t)(nt * 16 + lm) * 256 + qt * 64 + lq * 8;
      vf0[nt] = *(const bf16x8*)vrow;
      vf1[nt] = *(const bf16x8*)(vrow + 32);
    }
    // write own P rows for this quarter (wave-private region of Ps)
#pragma unroll
    for (int ctl = 0; ctl < 4; ++ctl) {
      int ct = qt * 4 + ctl;
#pragma unroll
      for (int r = 0; r < 4; ++r) {
        int rowl = w * 16 + lq * 4 + r;
        int g = ctl * 2 + (lm >> 3);
        Ps[rowl * 64 + ((g ^ (rowl & 7)) << 3) + (lm & 7)] =
            f2bf(acc[ct][r] * sm[r]);
      }
    }
    int prow = w * 16 + lm;
#pragma unroll
    for (int kst = 0; kst < 2; ++kst) {
      bf16x8 af = *(const bf16x8*)&Ps[prow * 64 + (((kst * 4 + lq) ^ (prow & 7)) << 3)];
#pragma unroll
      for (int nt = 0; nt < 4; ++nt)
        acc2[nt] = __builtin_amdgcn_mfma_f32_16x16x32_bf16(
            af, kst ? vf1[nt] : vf0[nt], acc2[nt], 0, 0, 0);
    }
  }
  // o -> cat[row][520 + h*64 + d]
#pragma unroll
  for (int nt = 0; nt < 4; ++nt) {
    int d = nt * 16 + lm;
#pragma unroll
    for (int r = 0; r < 4; ++r) {
      int i = ibase + r;
      cat[((size_t)(b * 256 + i)) * 1088 + 520 + h * 64 + d] = f2bf(acc2[nt][r]);
    }
  }
}

__device__ __forceinline__ float lnReduceSum(float v, float* red) {
#pragma unroll
  for (int o = 32; o > 0; o >>= 1) v += __shfl_xor(v, o, 64);
  int w = threadIdx.x >> 6;
  __syncthreads();
  if ((threadIdx.x & 63) == 0) red[w] = v;
  __syncthreads();
  return red[0] + red[1] + red[2] + red[3];
}

// ---------------- out = LayerNorm(x1 + sum_s xp[s]) * g + b ---------------
__global__ __launch_bounds__(256) void ln_sum(
    const float* __restrict__ x1, const float* __restrict__ xp,
    int S, int stride, const float* __restrict__ g,
    const float* __restrict__ bta, float* __restrict__ out,
    __hip_bfloat16* __restrict__ out_bf) {
  __shared__ float red[4];
  int row = blockIdx.x, tid = threadIdx.x;
  size_t base = (size_t)row * 512;
  float v0 = x1[base + tid];
  float v1 = x1[base + tid + 256];
  for (int s = 0; s < S; ++s) {
    v0 += xp[(size_t)s * stride + base + tid];
    v1 += xp[(size_t)s * stride + base + tid + 256];
  }
  float su = lnReduceSum(v0 + v1, red);
  float sq = lnReduceSum(v0 * v0 + v1 * v1, red);
  float mean = su * (1.f / 512.f);
  float var = sq * (1.f / 512.f) - mean * mean;
  float inv = rsqrtf(var + 1e-5f);
  float o0 = (v0 - mean) * inv * g[tid] + bta[tid];
  float o1 = (v1 - mean) * inv * g[tid + 256] + bta[tid + 256];
  out[base + tid]       = o0;
  out[base + tid + 256] = o1;
  if (out_bf) {
    out_bf[base + tid]       = __float2bfloat16(o0);
    out_bf[base + tid + 256] = __float2bfloat16(o1);
  }
}

extern "C" void kernel_launch(void* const* d_in, const int* in_sizes, int n_in,
                              void* d_out, int out_size, void* d_ws, size_t ws_size,
                              hipStream_t stream) {
  const float* s     = (const float*)d_in[0];
  const int*   masks = (const int*)d_in[1];
  const float* wq = (const float*)d_in[2];
  const float* wk = (const float*)d_in[3];
  const float* wv = (const float*)d_in[4];
  const float* wb = (const float*)d_in[5];
  const float* wo = (const float*)d_in[6];
  const float* bo = (const float*)d_in[7];
  const float* ln1_g = (const float*)d_in[8];
  const float* ln1_b = (const float*)d_in[9];
  const float* w1 = (const float*)d_in[10];
  const float* b1 = (const float*)d_in[11];
  const float* w2 = (const float*)d_in[12];
  const float* b2 = (const float*)d_in[13];
  const float* ln2_g = (const float*)d_in[14];
  const float* ln2_b = (const float*)d_in[15];

  float* out_x = (float*)d_out;              // [8,256,512]
  float* out_a = out_x + 1048576;            // [8,8,256,256]

  // disjoint workspace (float offsets)
  float* ws = (float*)d_ws;
  float* embd_part = ws + 0;                               // [4][2048,512]
  float* xbuf      = ws + 4194304;
  float* ff_part   = ws + 5242880;                         // [4][2048,512]
  ushort* qkv_bf   = (ushort*)(ws + 9437184);              // q|k [B,H,N,D], v [B,H,D,N]
  ushort* q_bf = qkv_bf;
  ushort* k_bf = qkv_bf + 1048576;
  ushort* v_bf = qkv_bf + 2097152;
  ushort* cat_bf = (ushort*)(ws + 10223616);               // [2048,1088]
  __hip_bfloat16* h_bf  = (__hip_bfloat16*)(ws + 11337728);  // [2048,2048]
  __hip_bfloat16* s_bf  = (__hip_bfloat16*)(ws + 13434880);  // [2048,512]
  __hip_bfloat16* x_bf  = (__hip_bfloat16*)(ws + 13959168);  // [2048,512]
  __hip_bfloat16* wqkvT = (__hip_bfloat16*)(ws + 14483456);  // [1536,512]
  __hip_bfloat16* wopT  = (__hip_bfloat16*)(ws + 14876672);  // [512,1088]
  __hip_bfloat16* w1T   = (__hip_bfloat16*)(ws + 15155200);  // [2048,512]
  __hip_bfloat16* w2T   = (__hip_bfloat16*)(ws + 15679488);  // [512,2048]

  dim3 blk(256), blkg(128);
  // 0. prep: s cvt + all weight transposes, one dispatch
  prep_all<<<dim3(4384), blk, 0, stream>>>(s, s_bf, wq, wk, wv, wo, w1, w2,
                                           wqkvT, wopT, w1T, w2T);
  // 1. QKV projection -> bf16 head layout (q,k) + transposed v  [384 blocks]
  gemm_bf16<<<dim3(12, 32, 1), blkg, 0, stream>>>(
      (const ushort*)s_bf, (const ushort*)wqkvT, nullptr, nullptr,
      qkv_bf, 2048, 1536, 512, 16);
  // 2. fused attention: a -> d_out, o + o_pair -> cat_bf
  attn_fused<<<dim3(256), blk, 0, stream>>>(q_bf, k_bf, v_bf, masks, wb,
                                            out_a, cat_bf);
  // 3. output projection (split-K=4)  [512 blocks]
  gemm_bf16<<<dim3(4, 32, 4), blkg, 0, stream>>>(
      cat_bf, (const ushort*)wopT, bo, embd_part, nullptr,
      2048, 512, 1088, 1 | 8);
  // 4. x = LN(s + sum embd_part)
  ln_sum<<<dim3(2048), blk, 0, stream>>>(s, embd_part, 4, 1048576,
                                         ln1_g, ln1_b, xbuf, x_bf);
  // 5. FFN  [512 blocks each]
  gemm_bf16<<<dim3(16, 32, 1), blkg, 0, stream>>>(
      (const ushort*)x_bf, (const ushort*)w1T, b1, nullptr, (ushort*)h_bf,
      2048, 2048, 512, 1 | 2 | 4);
  gemm_bf16<<<dim3(4, 32, 4), blkg, 0, stream>>>(
      (const ushort*)h_bf, (const ushort*)w2T, b2, ff_part, nullptr,
      2048, 512, 2048, 1 | 8);
  // 6. out = LN(x + sum ff_part)
  ln_sum<<<dim3(2048), blk, 0, stream>>>(xbuf, ff_part, 4, 1048576,
                                         ln2_g, ln2_b, out_x, nullptr);
}

// Round 9
// 184.844 us; speedup vs baseline: 3.0350x; 1.0533x over previous
//
#include <hip/hip_runtime.h>
#include <hip/hip_bf16.h>
#include <cstdint>

#define B_ 8
#define N_ 256
#define CS_ 512
#define H_ 8
#define D_ 64
#define K_ 32
#define NB_ 65
#define CT_ 2048
#define WL_ 0.70710678118654752f

typedef __attribute__((ext_vector_type(8))) short bf16x8;
typedef __attribute__((ext_vector_type(4))) float f32x4;

#define GLOBAL_AS __attribute__((address_space(1)))
#define LDS_AS __attribute__((address_space(3)))

__device__ __forceinline__ void async16(void* lds, const void* g) {
  __builtin_amdgcn_global_load_lds((const GLOBAL_AS uint32_t*)g,
                                   (LDS_AS uint32_t*)lds, 16, 0, 0);
}

__device__ __forceinline__ ushort f2bf(float v) {
  __hip_bfloat16 hb = __float2bfloat16(v);
  return *(ushort*)&hb;
}

// ---------------- bf16 MFMA GEMM: C[M,N] = A[M,K] @ Bt[N,K]^T -------------
// 64x128 tile, 128 threads (2 waves). Split-K via gridDim.z.
// flags: 1=+bias[col] (slice 0), 2=relu, 4=bf16 out via LDS-coalesced blast,
//        8=f32 out (offset z*M*Nc), 16=qkv scatter (col = which*512+h*64+d);
//        q,k -> [B,H,N,D], v -> [B,H,D,N] — all via LDS bounce, 128B rows.
__global__ __launch_bounds__(128) void gemm_bf16(
    const ushort* __restrict__ A, const ushort* __restrict__ Bt,
    const float* __restrict__ bias, float* __restrict__ C,
    ushort* __restrict__ Cb, int M, int Nc, int Kd, int flags) {
  __shared__ ushort As[64 * 64];    // 8 KB
  __shared__ ushort Bs[128 * 64];   // 16 KB (reused as epilogue bounce)
  int tid = threadIdx.x;
  int bm = blockIdx.y * 64, bn = blockIdx.x * 128;
  int S = gridDim.z, z = blockIdx.z;
  int T = Kd >> 6;
  int it0 = (z * T) / S, it1 = ((z + 1) * T) / S;
  if (flags & 8) C += (size_t)z * M * Nc;
  int w = tid >> 6, l = tid & 63;
  int lm = l & 15, lq = l >> 4;
  int srow = tid >> 3;       // 0..15
  int sg = tid & 7;

  f32x4 acc[4][4];
#pragma unroll
  for (int i = 0; i < 4; ++i)
#pragma unroll
    for (int j = 0; j < 4; ++j) acc[i][j] = (f32x4){0.f, 0.f, 0.f, 0.f};

  for (int it = it0; it < it1; ++it) {
    int k0 = it << 6;
    __syncthreads();
#pragma unroll
    for (int r = 0; r < 4; ++r) {
      int row = r * 16 + srow;
      int gl = sg ^ (row & 7);
      async16(&As[row * 64 + sg * 8],
              A + (size_t)(bm + row) * Kd + k0 + gl * 8);
    }
#pragma unroll
    for (int r = 0; r < 8; ++r) {
      int row = r * 16 + srow;
      int gl = sg ^ (row & 7);
      async16(&Bs[row * 64 + sg * 8],
              Bt + (size_t)(bn + row) * Kd + k0 + gl * 8);
    }
    __syncthreads();
#pragma unroll
    for (int kk = 0; kk < 2; ++kk) {
      bf16x8 af[4], bfr[4];
#pragma unroll
      for (int i = 0; i < 4; ++i) {
        int ma = 16 * i + lm;
        af[i] = *(const bf16x8*)&As[ma * 64 + ((kk * 4 + lq) ^ (ma & 7)) * 8];
        int nb = w * 64 + 16 * i + lm;
        bfr[i] = *(const bf16x8*)&Bs[nb * 64 + ((kk * 4 + lq) ^ (nb & 7)) * 8];
      }
#pragma unroll
      for (int i = 0; i < 4; ++i)
#pragma unroll
        for (int j = 0; j < 4; ++j)
          acc[i][j] = __builtin_amdgcn_mfma_f32_16x16x32_bf16(
              af[i], bfr[j], acc[i][j], 0, 0, 0);
    }
  }

  int bcol0 = bn + w * 64;          // this wave's 64-col base
  int lr = l >> 3, lc = l & 7;      // blast: 8 lanes per 128B row
  ushort* Tb = &Bs[w * 4096];       // wave-private 64x64 bounce (in-order DS)

  if (flags & 16) {                 // QKV head-layout epilogue
    int which = bcol0 >> 9;
    int hh = (bcol0 & 511) >> 6;
    int b = bm >> 8, nn0 = bm & 255;
    if (which == 2) {               // v: transpose to [d][n]
#pragma unroll
      for (int j = 0; j < 4; ++j)
#pragma unroll
        for (int i = 0; i < 4; ++i) {
          ushort pk[4];
#pragma unroll
          for (int r = 0; r < 4; ++r) pk[r] = f2bf(acc[i][j][r]);
          *(uint2*)&Tb[(16 * j + lm) * 64 + 16 * i + lq * 4] = *(uint2*)pk;
        }
    } else {                        // q,k: [n][d]
#pragma unroll
      for (int j = 0; j < 4; ++j)
#pragma unroll
        for (int i = 0; i < 4; ++i)
#pragma unroll
          for (int r = 0; r < 4; ++r)
            Tb[(16 * i + lq * 4 + r) * 64 + 16 * j + lm] = f2bf(acc[i][j][r]);
    }
    __asm__ __volatile__("" ::: "memory");
    ushort* dstb = Cb + (size_t)which * 1048576 + (size_t)(b * 8 + hh) * 16384;
#pragma unroll
    for (int p = 0; p < 8; ++p) {
      int rowL = p * 8 + lr;
      bf16x8 vv = *(const bf16x8*)&Tb[rowL * 64 + lc * 8];
      if (which == 2)
        *(bf16x8*)(dstb + (size_t)rowL * 256 + nn0 + lc * 8) = vv;
      else
        *(bf16x8*)(dstb + (size_t)(nn0 + rowL) * 64 + lc * 8) = vv;
    }
    return;
  }
  if (flags & 4) {                  // bf16 output (FFN1): coalesced blast
#pragma unroll
    for (int j = 0; j < 4; ++j) {
      float bv = ((flags & 1) && z == 0) ? bias[bcol0 + 16 * j + lm] : 0.f;
#pragma unroll
      for (int i = 0; i < 4; ++i)
#pragma unroll
        for (int r = 0; r < 4; ++r) {
          float v = acc[i][j][r] + bv;
          if (flags & 2) v = fmaxf(v, 0.f);
          Tb[(16 * i + lq * 4 + r) * 64 + 16 * j + lm] = f2bf(v);
        }
    }
    __asm__ __volatile__("" ::: "memory");
#pragma unroll
    for (int p = 0; p < 8; ++p) {
      int rowL = p * 8 + lr;
      bf16x8 vv = *(const bf16x8*)&Tb[rowL * 64 + lc * 8];
      *(bf16x8*)(Cb + (size_t)(bm + rowL) * Nc + bcol0 + lc * 8) = vv;
    }
    return;
  }
  // f32 output (+bias, slice 0 only)
#pragma unroll
  for (int j = 0; j < 4; ++j) {
    int col = bcol0 + 16 * j + lm;
    float bv = ((flags & 1) && z == 0) ? bias[col] : 0.f;
#pragma unroll
    for (int i = 0; i < 4; ++i)
#pragma unroll
      for (int r = 0; r < 4; ++r) {
        int row = bm + 16 * i + lq * 4 + r;
        float v = acc[i][j][r] + bv;
        if (flags & 2) v = fmaxf(v, 0.f);
        C[(size_t)row * Nc + col] = v;
      }
  }
}

// ---------------- prep: s->bf16 + all weight transposes, one dispatch -----
// blocks [0,512): cvt s (8 elems/thread); then transpose jobs.
__global__ __launch_bounds__(256) void prep_all(
    const float* __restrict__ s, __hip_bfloat16* __restrict__ s_bf,
    const float* __restrict__ wq, const float* __restrict__ wk,
    const float* __restrict__ wv, const float* __restrict__ wo,
    const float* __restrict__ w1, const float* __restrict__ w2,
    __hip_bfloat16* __restrict__ wqkvT, __hip_bfloat16* __restrict__ wopT,
    __hip_bfloat16* __restrict__ w1T, __hip_bfloat16* __restrict__ w2T) {
  int blk = blockIdx.x;
  if (blk < 512) {
    int i = blk * 256 + threadIdx.x;   // 131072 threads x 8 elems
    float4 a = ((const float4*)s)[i * 2];
    float4 c = ((const float4*)s)[i * 2 + 1];
    ushort pk[8] = {f2bf(a.x), f2bf(a.y), f2bf(a.z), f2bf(a.w),
                    f2bf(c.x), f2bf(c.y), f2bf(c.z), f2bf(c.w)};
    *(uint4*)&((ushort*)s_bf)[i * 8] = *(uint4*)pk;
    return;
  }
  blk -= 512;
  __shared__ float tile[32][33];
  const float* src;
  __hip_bfloat16* dst;
  int R, C, Kpad, tX, tIdx, whichBase = -1;
  if (blk < 768) {
    int zz = blk >> 8; tIdx = blk & 255;
    src = zz == 0 ? wq : zz == 1 ? wk : wv;
    dst = wqkvT; whichBase = zz * 512; R = 512; C = 512; Kpad = 512; tX = 16;
  } else if (blk < 1312) {
    tIdx = blk - 768; src = wo; dst = wopT; R = 1032; C = 512; Kpad = 1088; tX = 16;
  } else if (blk < 2336) {
    tIdx = blk - 1312; src = w1; dst = w1T; R = 512; C = 2048; Kpad = 512; tX = 64;
  } else {
    tIdx = blk - 2336; src = w2; dst = w2T; R = 2048; C = 512; Kpad = 2048; tX = 16;
  }
  int c0 = (tIdx % tX) * 32, r0 = (tIdx / tX) * 32;
  int tx = threadIdx.x & 31, ty = threadIdx.x >> 5;
#pragma unroll
  for (int yy = 0; yy < 32; yy += 8) {
    int r = r0 + ty + yy, c = c0 + tx;
    tile[ty + yy][tx] = (r < R && c < C) ? src[(size_t)r * C + c] : 0.f;
  }
  __syncthreads();
#pragma unroll
  for (int yy = 0; yy < 32; yy += 8) {
    int cc = c0 + ty + yy, k = r0 + tx;
    if (cc < C && k < Kpad) {
      int n = (whichBase >= 0) ? (whichBase + (cc & 7) * 64 + (cc >> 3)) : cc;
      dst[(size_t)n * Kpad + k] = __float2bfloat16(tile[tx][ty + yy]);
    }
  }
}

// ---------------- fused attention: QK^T+softmax -> a, PV -> o, o_pair -----
// 512 blocks = (bh:64) x (32-row strip:8), 128 threads; wave w owns 16 rows.
// ONE barrier; Q/V frags from global; P via wave-private 4 KB Ps.
__global__ __launch_bounds__(128) void attn_fused(
    const ushort* __restrict__ qh, const ushort* __restrict__ kh,
    const ushort* __restrict__ vT, const int* __restrict__ masks,
    const float* __restrict__ wb, float* __restrict__ a_out,
    ushort* __restrict__ cat) {
  int strip = blockIdx.x & 7, bh = blockIdx.x >> 3;
  int h = bh & 7, b = bh >> 3;
  __shared__ ushort Ks[256 * 64];   // 32 KB
  __shared__ ushort Ps[32 * 64];    // 4 KB, k-quarter P (wave-private rows)
  __shared__ float wbs[NB_];
  __shared__ float mfj[256];
  int tid = threadIdx.x;
  int srow = tid >> 3, sg = tid & 7;
#pragma unroll
  for (int rr = 0; rr < 16; ++rr) {
    int row = rr * 16 + srow;
    int gl = sg ^ (row & 7);
    async16(&Ks[row * 64 + sg * 8],
            kh + ((size_t)bh * 256 + row) * 64 + gl * 8);
  }
  int w = tid >> 6, l = tid & 63, lm = l & 15, lq = l >> 4;
  bf16x8 qf[2];
  {
    const ushort* qrow =
        qh + ((size_t)bh * 256 + strip * 32 + w * 16 + lm) * 64 + lq * 8;
    qf[0] = *(const bf16x8*)qrow;
    qf[1] = *(const bf16x8*)(qrow + 32);
  }
  if (tid < NB_) wbs[tid] = wb[tid * H_ + h];
  mfj[tid]       = (masks[b * 256 + tid] != 0) ? 1.f : 0.f;
  mfj[tid + 128] = (masks[b * 256 + tid + 128] != 0) ? 1.f : 0.f;
  __syncthreads();   // the only barrier

  f32x4 acc[16];
#pragma unroll
  for (int ct = 0; ct < 16; ++ct) {
    int krow = ct * 16 + lm;
    bf16x8 kf0 = *(const bf16x8*)&Ks[krow * 64 + ((lq) ^ (krow & 7)) * 8];
    bf16x8 kf1 = *(const bf16x8*)&Ks[krow * 64 + ((4 + lq) ^ (krow & 7)) * 8];
    f32x4 zf = (f32x4){0.f, 0.f, 0.f, 0.f};
    zf = __builtin_amdgcn_mfma_f32_16x16x32_bf16(qf[0], kf0, zf, 0, 0, 0);
    acc[ct] = __builtin_amdgcn_mfma_f32_16x16x32_bf16(qf[1], kf1, zf, 0, 0, 0);
  }
  int ibase = strip * 32 + w * 16 + lq * 4;
  float mfi[4];
#pragma unroll
  for (int r = 0; r < 4; ++r) mfi[r] = mfj[ibase + r];
#pragma unroll
  for (int ct = 0; ct < 16; ++ct) {
    int j = ct * 16 + lm;
    float mj = mfj[j];
#pragma unroll
    for (int r = 0; r < 4; ++r) {
      int i = ibase + r;
      int diff = i - j;
      int cb = diff < -K_ ? 0 : (diff > K_ ? 2 * K_ : diff + K_);
      float sq = mfi[r] * mj;
      acc[ct][r] = WL_ * (acc[ct][r] * 0.125f + wbs[cb] * sq) - 1e9f * (1.f - sq);
    }
  }
  float mx[4], sm[4];
#pragma unroll
  for (int r = 0; r < 4; ++r) {
    float m = acc[0][r];
#pragma unroll
    for (int ct = 1; ct < 16; ++ct) m = fmaxf(m, acc[ct][r]);
#pragma unroll
    for (int o = 1; o < 16; o <<= 1) m = fmaxf(m, __shfl_xor(m, o, 64));
    mx[r] = m;
  }
#pragma unroll
  for (int ct = 0; ct < 16; ++ct)
#pragma unroll
    for (int r = 0; r < 4; ++r) acc[ct][r] = __expf(acc[ct][r] - mx[r]);
#pragma unroll
  for (int r = 0; r < 4; ++r) {
    float s = 0.f;
#pragma unroll
    for (int ct = 0; ct < 16; ++ct) s += acc[ct][r];
#pragma unroll
    for (int o = 1; o < 16; o <<= 1) s += __shfl_xor(s, o, 64);
    sm[r] = 1.f / s;
  }
  // ---- a stores (f32) + o_pair into cat (bf16) ----
  float p0[4] = {0.f, 0.f, 0.f, 0.f}, p64[4] = {0.f, 0.f, 0.f, 0.f};
#pragma unroll
  for (int ct = 0; ct < 16; ++ct) {
    int j = ct * 16 + lm;
    float mj = mfj[j];
#pragma unroll
    for (int r = 0; r < 4; ++r) {
      int i = ibase + r;
      float aval = acc[ct][r] * sm[r];
      a_out[((size_t)bh * 256 + i) * 256 + j] = aval;
      float val = aval * mfi[r] * mj;
      int diff = i - j;
      if (diff <= -K_)      p0[r] += val;
      else if (diff >= K_)  p64[r] += val;
      else cat[((size_t)(b * 256 + i)) * 1088 + h * 65 + diff + K_] = f2bf(val);
    }
  }
#pragma unroll
  for (int r = 0; r < 4; ++r)
#pragma unroll
    for (int o = 1; o < 16; o <<= 1) {
      p0[r]  += __shfl_xor(p0[r], o, 64);
      p64[r] += __shfl_xor(p64[r], o, 64);
    }
  if (lm == 0) {
#pragma unroll
    for (int r = 0; r < 4; ++r) {
      int i = ibase + r;
      cat[((size_t)(b * 256 + i)) * 1088 + h * 65 + 0]      = f2bf(p0[r]);
      cat[((size_t)(b * 256 + i)) * 1088 + h * 65 + 2 * K_] = f2bf(p64[r]);
    }
  }
  // interior bins with out-of-range source j -> 0
#pragma unroll
  for (int r = 0; r < 4; ++r) {
    int i = ibase + r;
#pragma unroll
    for (int t = 0; t < 4; ++t) {
      int c = 1 + lm + 16 * t;
      if (c < 64) {
        int j = i - c + K_;
        if (j < 0 || j > 255)
          cat[((size_t)(b * 256 + i)) * 1088 + h * 65 + c] = 0;
      }
    }
  }
  // pad cols 1032..1088 zeroed by h==0 blocks
  if (h == 0) {
    for (int idx = tid; idx < 32 * 56; idx += 128) {
      int r = idx / 56, c = 1032 + (idx - r * 56);
      cat[((size_t)(b * 256 + strip * 32 + r)) * 1088 + c] = 0;
    }
  }
  // ---- PV: o = P @ V over 4 k-quarters; V frags direct from global ----
  f32x4 acc2[4];
#pragma unroll
  for (int nt = 0; nt < 4; ++nt) acc2[nt] = (f32x4){0.f, 0.f, 0.f, 0.f};
  const ushort* vbase = vT + (size_t)bh * 16384;
#pragma unroll
  for (int qt = 0; qt < 4; ++qt) {
    bf16x8 vf0[4], vf1[4];
#pragma unroll
    for (int nt = 0; nt < 4; ++nt) {
      const ushort* vrow = vbase + (size_t)(nt * 16 + lm) * 256 + qt * 64 + lq * 8;
      vf0[nt] = *(const bf16x8*)vrow;
      vf1[nt] = *(const bf16x8*)(vrow + 32);
    }
#pragma unroll
    for (int ctl = 0; ctl < 4; ++ctl) {
      int ct = qt * 4 + ctl;
#pragma unroll
      for (int r = 0; r < 4; ++r) {
        int rowl = w * 16 + lq * 4 + r;
        int g = ctl * 2 + (lm >> 3);
        Ps[rowl * 64 + ((g ^ (rowl & 7)) << 3) + (lm & 7)] =
            f2bf(acc[ct][r] * sm[r]);
      }
    }
    int prow = w * 16 + lm;
#pragma unroll
    for (int kst = 0; kst < 2; ++kst) {
      bf16x8 af = *(const bf16x8*)&Ps[prow * 64 + (((kst * 4 + lq) ^ (prow & 7)) << 3)];
#pragma unroll
      for (int nt = 0; nt < 4; ++nt)
        acc2[nt] = __builtin_amdgcn_mfma_f32_16x16x32_bf16(
            af, kst ? vf1[nt] : vf0[nt], acc2[nt], 0, 0, 0);
    }
  }
#pragma unroll
  for (int nt = 0; nt < 4; ++nt) {
    int d = nt * 16 + lm;
#pragma unroll
    for (int r = 0; r < 4; ++r) {
      int i = ibase + r;
      cat[((size_t)(b * 256 + i)) * 1088 + 520 + h * 64 + d] = f2bf(acc2[nt][r]);
    }
  }
}

// ---------------- out = LayerNorm(x1 + sum_s xp[s]) * g + b ---------------
// 128 threads, float4 per thread (512 cols).
__global__ __launch_bounds__(128) void ln_sum(
    const float* __restrict__ x1, const float* __restrict__ xp,
    int S, int stride, const float* __restrict__ g,
    const float* __restrict__ bta, float* __restrict__ out,
    __hip_bfloat16* __restrict__ out_bf) {
  __shared__ float redA[2], redB[2];
  int row = blockIdx.x, tid = threadIdx.x;
  size_t base = (size_t)row * 512;
  float4 v = *(const float4*)(x1 + base + tid * 4);
  for (int s = 0; s < S; ++s) {
    float4 p = *(const float4*)(xp + (size_t)s * stride + base + tid * 4);
    v.x += p.x; v.y += p.y; v.z += p.z; v.w += p.w;
  }
  float su = v.x + v.y + v.z + v.w;
  float sq = v.x * v.x + v.y * v.y + v.z * v.z + v.w * v.w;
#pragma unroll
  for (int o = 32; o > 0; o >>= 1) {
    su += __shfl_xor(su, o, 64);
    sq += __shfl_xor(sq, o, 64);
  }
  int w = tid >> 6;
  if ((tid & 63) == 0) { redA[w] = su; redB[w] = sq; }
  __syncthreads();
  su = redA[0] + redA[1]; sq = redB[0] + redB[1];
  float mean = su * (1.f / 512.f);
  float var = sq * (1.f / 512.f) - mean * mean;
  float inv = rsqrtf(var + 1e-5f);
  float4 gv = *(const float4*)(g + tid * 4);
  float4 bv = *(const float4*)(bta + tid * 4);
  float4 o4;
  o4.x = (v.x - mean) * inv * gv.x + bv.x;
  o4.y = (v.y - mean) * inv * gv.y + bv.y;
  o4.z = (v.z - mean) * inv * gv.z + bv.z;
  o4.w = (v.w - mean) * inv * gv.w + bv.w;
  *(float4*)(out + base + tid * 4) = o4;
  if (out_bf) {
    ushort pk[4] = {f2bf(o4.x), f2bf(o4.y), f2bf(o4.z), f2bf(o4.w)};
    *(uint2*)&((ushort*)out_bf)[base + tid * 4] = *(uint2*)pk;
  }
}

extern "C" void kernel_launch(void* const* d_in, const int* in_sizes, int n_in,
                              void* d_out, int out_size, void* d_ws, size_t ws_size,
                              hipStream_t stream) {
  const float* s     = (const float*)d_in[0];
  const int*   masks = (const int*)d_in[1];
  const float* wq = (const float*)d_in[2];
  const float* wk = (const float*)d_in[3];
  const float* wv = (const float*)d_in[4];
  const float* wb = (const float*)d_in[5];
  const float* wo = (const float*)d_in[6];
  const float* bo = (const float*)d_in[7];
  const float* ln1_g = (const float*)d_in[8];
  const float* ln1_b = (const float*)d_in[9];
  const float* w1 = (const float*)d_in[10];
  const float* b1 = (const float*)d_in[11];
  const float* w2 = (const float*)d_in[12];
  const float* b2 = (const float*)d_in[13];
  const float* ln2_g = (const float*)d_in[14];
  const float* ln2_b = (const float*)d_in[15];

  float* out_x = (float*)d_out;              // [8,256,512]
  float* out_a = out_x + 1048576;            // [8,8,256,256]

  // disjoint workspace (float offsets)
  float* ws = (float*)d_ws;
  float* embd_part = ws + 0;                               // [4][2048,512]
  float* xbuf      = ws + 4194304;
  float* ff_part   = ws + 5242880;                         // [4][2048,512]
  ushort* qkv_bf   = (ushort*)(ws + 9437184);              // q|k [B,H,N,D], v [B,H,D,N]
  ushort* q_bf = qkv_bf;
  ushort* k_bf = qkv_bf + 1048576;
  ushort* v_bf = qkv_bf + 2097152;
  ushort* cat_bf = (ushort*)(ws + 10223616);               // [2048,1088]
  __hip_bfloat16* h_bf  = (__hip_bfloat16*)(ws + 11337728);  // [2048,2048]
  __hip_bfloat16* s_bf  = (__hip_bfloat16*)(ws + 13434880);  // [2048,512]
  __hip_bfloat16* x_bf  = (__hip_bfloat16*)(ws + 13959168);  // [2048,512]
  __hip_bfloat16* wqkvT = (__hip_bfloat16*)(ws + 14483456);  // [1536,512]
  __hip_bfloat16* wopT  = (__hip_bfloat16*)(ws + 14876672);  // [512,1088]
  __hip_bfloat16* w1T   = (__hip_bfloat16*)(ws + 15155200);  // [2048,512]
  __hip_bfloat16* w2T   = (__hip_bfloat16*)(ws + 15679488);  // [512,2048]

  dim3 blk(256), blkg(128);
  // 0. prep: s cvt (512 blocks) + weight transposes (3360 blocks)
  prep_all<<<dim3(3872), blk, 0, stream>>>(s, s_bf, wq, wk, wv, wo, w1, w2,
                                           wqkvT, wopT, w1T, w2T);
  // 1. QKV projection -> bf16 head layout (q,k) + transposed v, coalesced
  gemm_bf16<<<dim3(12, 32, 1), blkg, 0, stream>>>(
      (const ushort*)s_bf, (const ushort*)wqkvT, nullptr, nullptr,
      qkv_bf, 2048, 1536, 512, 16);
  // 2. fused attention: a -> d_out, o + o_pair -> cat_bf  [512 x 128thr]
  attn_fused<<<dim3(512), blkg, 0, stream>>>(q_bf, k_bf, v_bf, masks, wb,
                                             out_a, cat_bf);
  // 3. output projection (split-K=4)  [512 blocks]
  gemm_bf16<<<dim3(4, 32, 4), blkg, 0, stream>>>(
      cat_bf, (const ushort*)wopT, bo, embd_part, nullptr,
      2048, 512, 1088, 1 | 8);
  // 4. x = LN(s + sum embd_part)
  ln_sum<<<dim3(2048), blkg, 0, stream>>>(s, embd_part, 4, 1048576,
                                          ln1_g, ln1_b, xbuf, x_bf);
  // 5. FFN  [512 blocks each]
  gemm_bf16<<<dim3(16, 32, 1), blkg, 0, stream>>>(
      (const ushort*)x_bf, (const ushort*)w1T, b1, nullptr, (ushort*)h_bf,
      2048, 2048, 512, 1 | 2 | 4);
  gemm_bf16<<<dim3(4, 32, 4), blkg, 0, stream>>>(
      (const ushort*)h_bf, (const ushort*)w2T, b2, ff_part, nullptr,
      2048, 512, 2048, 1 | 8);
  // 6. out = LN(x + sum ff_part)
  ln_sum<<<dim3(2048), blkg, 0, stream>>>(xbuf, ff_part, 4, 1048576,
                                          ln2_g, ln2_b, out_x, nullptr);
}

// Round 10
// 180.529 us; speedup vs baseline: 3.1076x; 1.0239x over previous
//
#include <hip/hip_runtime.h>
#include <hip/hip_bf16.h>
#include <cstdint>

#define B_ 8
#define N_ 256
#define CS_ 512
#define H_ 8
#define D_ 64
#define K_ 32
#define NB_ 65
#define CT_ 2048
#define WL_ 0.70710678118654752f

typedef __attribute__((ext_vector_type(8))) short bf16x8;
typedef __attribute__((ext_vector_type(4))) float f32x4;

#define GLOBAL_AS __attribute__((address_space(1)))
#define LDS_AS __attribute__((address_space(3)))

__device__ __forceinline__ void async16(void* lds, const void* g) {
  __builtin_amdgcn_global_load_lds((const GLOBAL_AS uint32_t*)g,
                                   (LDS_AS uint32_t*)lds, 16, 0, 0);
}

__device__ __forceinline__ ushort f2bf(float v) {
  __hip_bfloat16 hb = __float2bfloat16(v);
  return *(ushort*)&hb;
}

// ---------------- bf16 MFMA GEMM: C[M,N] = A[M,K] @ Bt[N,K]^T -------------
// 64x128 tile, 128 threads (2 waves), DOUBLE-BUFFERED LDS (1 barrier/iter,
// prefetch issued a full compute-phase ahead). Split-K via gridDim.z.
// flags: 1=+bias[col] (slice 0), 2=relu, 4=bf16 out via LDS-coalesced blast,
//        8=f32 out (offset z*M*Nc), 16=qkv scatter (col = which*512+h*64+d);
//        q,k -> [B,H,N,D], v -> [B,H,D,N] — all via LDS bounce, 128B rows.
__global__ __launch_bounds__(128) void gemm_bf16(
    const ushort* __restrict__ A, const ushort* __restrict__ Bt,
    const float* __restrict__ bias, float* __restrict__ C,
    ushort* __restrict__ Cb, int M, int Nc, int Kd, int flags) {
  __shared__ ushort As[2][64 * 64];    // 16 KB
  __shared__ ushort Bs[2][128 * 64];   // 32 KB (buf reused as epilogue bounce)
  int tid = threadIdx.x;
  int bm = blockIdx.y * 64, bn = blockIdx.x * 128;
  int S = gridDim.z, z = blockIdx.z;
  int T = Kd >> 6;
  int it0 = (z * T) / S, it1 = ((z + 1) * T) / S;
  if (flags & 8) C += (size_t)z * M * Nc;
  int w = tid >> 6, l = tid & 63;
  int lm = l & 15, lq = l >> 4;
  int srow = tid >> 3;       // 0..15
  int sg = tid & 7;

  f32x4 acc[4][4];
#pragma unroll
  for (int i = 0; i < 4; ++i)
#pragma unroll
    for (int j = 0; j < 4; ++j) acc[i][j] = (f32x4){0.f, 0.f, 0.f, 0.f};

  // prologue: issue loads for first tile into buf 0
  {
    int k0 = it0 << 6;
#pragma unroll
    for (int r = 0; r < 4; ++r) {
      int row = r * 16 + srow;
      int gl = sg ^ (row & 7);
      async16(&As[0][row * 64 + sg * 8],
              A + (size_t)(bm + row) * Kd + k0 + gl * 8);
    }
#pragma unroll
    for (int r = 0; r < 8; ++r) {
      int row = r * 16 + srow;
      int gl = sg ^ (row & 7);
      async16(&Bs[0][row * 64 + sg * 8],
              Bt + (size_t)(bn + row) * Kd + k0 + gl * 8);
    }
  }
  for (int it = it0; it < it1; ++it) {
    int cur = (it - it0) & 1;
    __syncthreads();   // cur tile's loads complete; nxt buf's readers done
    if (it + 1 < it1) {
      int nxt = cur ^ 1;
      int k0 = (it + 1) << 6;
#pragma unroll
      for (int r = 0; r < 4; ++r) {
        int row = r * 16 + srow;
        int gl = sg ^ (row & 7);
        async16(&As[nxt][row * 64 + sg * 8],
                A + (size_t)(bm + row) * Kd + k0 + gl * 8);
      }
#pragma unroll
      for (int r = 0; r < 8; ++r) {
        int row = r * 16 + srow;
        int gl = sg ^ (row & 7);
        async16(&Bs[nxt][row * 64 + sg * 8],
                Bt + (size_t)(bn + row) * Kd + k0 + gl * 8);
      }
    }
#pragma unroll
    for (int kk = 0; kk < 2; ++kk) {
      bf16x8 af[4], bfr[4];
#pragma unroll
      for (int i = 0; i < 4; ++i) {
        int ma = 16 * i + lm;
        af[i] = *(const bf16x8*)&As[cur][ma * 64 + ((kk * 4 + lq) ^ (ma & 7)) * 8];
        int nb = w * 64 + 16 * i + lm;
        bfr[i] = *(const bf16x8*)&Bs[cur][nb * 64 + ((kk * 4 + lq) ^ (nb & 7)) * 8];
      }
#pragma unroll
      for (int i = 0; i < 4; ++i)
#pragma unroll
        for (int j = 0; j < 4; ++j)
          acc[i][j] = __builtin_amdgcn_mfma_f32_16x16x32_bf16(
              af[i], bfr[j], acc[i][j], 0, 0, 0);
    }
  }
  __syncthreads();   // all waves done with LDS before bounce reuse

  int bcol0 = bn + w * 64;          // this wave's 64-col base
  int lr = l >> 3, lc = l & 7;      // blast: 8 lanes per 128B row
  ushort* Tb = &Bs[0][w * 4096];    // wave-private 64x64 bounce (in-order DS)

  if (flags & 16) {                 // QKV head-layout epilogue
    int which = bcol0 >> 9;
    int hh = (bcol0 & 511) >> 6;
    int b = bm >> 8, nn0 = bm & 255;
    if (which == 2) {               // v: transpose to [d][n]
#pragma unroll
      for (int j = 0; j < 4; ++j)
#pragma unroll
        for (int i = 0; i < 4; ++i) {
          ushort pk[4];
#pragma unroll
          for (int r = 0; r < 4; ++r) pk[r] = f2bf(acc[i][j][r]);
          *(uint2*)&Tb[(16 * j + lm) * 64 + 16 * i + lq * 4] = *(uint2*)pk;
        }
    } else {                        // q,k: [n][d]
#pragma unroll
      for (int j = 0; j < 4; ++j)
#pragma unroll
        for (int i = 0; i < 4; ++i)
#pragma unroll
          for (int r = 0; r < 4; ++r)
            Tb[(16 * i + lq * 4 + r) * 64 + 16 * j + lm] = f2bf(acc[i][j][r]);
    }
    __asm__ __volatile__("" ::: "memory");
    ushort* dstb = Cb + (size_t)which * 1048576 + (size_t)(b * 8 + hh) * 16384;
#pragma unroll
    for (int p = 0; p < 8; ++p) {
      int rowL = p * 8 + lr;
      bf16x8 vv = *(const bf16x8*)&Tb[rowL * 64 + lc * 8];
      if (which == 2)
        *(bf16x8*)(dstb + (size_t)rowL * 256 + nn0 + lc * 8) = vv;
      else
        *(bf16x8*)(dstb + (size_t)(nn0 + rowL) * 64 + lc * 8) = vv;
    }
    return;
  }
  if (flags & 4) {                  // bf16 output (FFN1): coalesced blast
#pragma unroll
    for (int j = 0; j < 4; ++j) {
      float bv = ((flags & 1) && z == 0) ? bias[bcol0 + 16 * j + lm] : 0.f;
#pragma unroll
      for (int i = 0; i < 4; ++i)
#pragma unroll
        for (int r = 0; r < 4; ++r) {
          float v = acc[i][j][r] + bv;
          if (flags & 2) v = fmaxf(v, 0.f);
          Tb[(16 * i + lq * 4 + r) * 64 + 16 * j + lm] = f2bf(v);
        }
    }
    __asm__ __volatile__("" ::: "memory");
#pragma unroll
    for (int p = 0; p < 8; ++p) {
      int rowL = p * 8 + lr;
      bf16x8 vv = *(const bf16x8*)&Tb[rowL * 64 + lc * 8];
      *(bf16x8*)(Cb + (size_t)(bm + rowL) * Nc + bcol0 + lc * 8) = vv;
    }
    return;
  }
  // f32 output (+bias, slice 0 only)
#pragma unroll
  for (int j = 0; j < 4; ++j) {
    int col = bcol0 + 16 * j + lm;
    float bv = ((flags & 1) && z == 0) ? bias[col] : 0.f;
#pragma unroll
    for (int i = 0; i < 4; ++i)
#pragma unroll
      for (int r = 0; r < 4; ++r) {
        int row = bm + 16 * i + lq * 4 + r;
        float v = acc[i][j][r] + bv;
        if (flags & 2) v = fmaxf(v, 0.f);
        C[(size_t)row * Nc + col] = v;
      }
  }
}

// ---------------- prep: s->bf16 + all weight transposes, one dispatch -----
__global__ __launch_bounds__(256) void prep_all(
    const float* __restrict__ s, __hip_bfloat16* __restrict__ s_bf,
    const float* __restrict__ wq, const float* __restrict__ wk,
    const float* __restrict__ wv, const float* __restrict__ wo,
    const float* __restrict__ w1, const float* __restrict__ w2,
    __hip_bfloat16* __restrict__ wqkvT, __hip_bfloat16* __restrict__ wopT,
    __hip_bfloat16* __restrict__ w1T, __hip_bfloat16* __restrict__ w2T) {
  int blk = blockIdx.x;
  if (blk < 512) {
    int i = blk * 256 + threadIdx.x;   // 131072 threads x 8 elems
    float4 a = ((const float4*)s)[i * 2];
    float4 c = ((const float4*)s)[i * 2 + 1];
    ushort pk[8] = {f2bf(a.x), f2bf(a.y), f2bf(a.z), f2bf(a.w),
                    f2bf(c.x), f2bf(c.y), f2bf(c.z), f2bf(c.w)};
    *(uint4*)&((ushort*)s_bf)[i * 8] = *(uint4*)pk;
    return;
  }
  blk -= 512;
  __shared__ float tile[32][33];
  const float* src;
  __hip_bfloat16* dst;
  int R, C, Kpad, tX, tIdx, whichBase = -1;
  if (blk < 768) {
    int zz = blk >> 8; tIdx = blk & 255;
    src = zz == 0 ? wq : zz == 1 ? wk : wv;
    dst = wqkvT; whichBase = zz * 512; R = 512; C = 512; Kpad = 512; tX = 16;
  } else if (blk < 1312) {
    tIdx = blk - 768; src = wo; dst = wopT; R = 1032; C = 512; Kpad = 1088; tX = 16;
  } else if (blk < 2336) {
    tIdx = blk - 1312; src = w1; dst = w1T; R = 512; C = 2048; Kpad = 512; tX = 64;
  } else {
    tIdx = blk - 2336; src = w2; dst = w2T; R = 2048; C = 512; Kpad = 2048; tX = 16;
  }
  int c0 = (tIdx % tX) * 32, r0 = (tIdx / tX) * 32;
  int tx = threadIdx.x & 31, ty = threadIdx.x >> 5;
#pragma unroll
  for (int yy = 0; yy < 32; yy += 8) {
    int r = r0 + ty + yy, c = c0 + tx;
    tile[ty + yy][tx] = (r < R && c < C) ? src[(size_t)r * C + c] : 0.f;
  }
  __syncthreads();
#pragma unroll
  for (int yy = 0; yy < 32; yy += 8) {
    int cc = c0 + ty + yy, k = r0 + tx;
    if (cc < C && k < Kpad) {
      int n = (whichBase >= 0) ? (whichBase + (cc & 7) * 64 + (cc >> 3)) : cc;
      dst[(size_t)n * Kpad + k] = __float2bfloat16(tile[tx][ty + yy]);
    }
  }
}

// ---------------- fused attention: QK^T+softmax -> a, PV -> o, o_pair -----
// 512 blocks = (bh:64) x (32-row strip:8), 128 threads; wave w owns 16 rows.
// ONE barrier; Q/V frags from global; P via wave-private 4 KB Ps.
__global__ __launch_bounds__(128) void attn_fused(
    const ushort* __restrict__ qh, const ushort* __restrict__ kh,
    const ushort* __restrict__ vT, const int* __restrict__ masks,
    const float* __restrict__ wb, float* __restrict__ a_out,
    ushort* __restrict__ cat) {
  int strip = blockIdx.x & 7, bh = blockIdx.x >> 3;
  int h = bh & 7, b = bh >> 3;
  __shared__ ushort Ks[256 * 64];   // 32 KB
  __shared__ ushort Ps[32 * 64];    // 4 KB, k-quarter P (wave-private rows)
  __shared__ float wbs[NB_];
  __shared__ float mfj[256];
  int tid = threadIdx.x;
  int srow = tid >> 3, sg = tid & 7;
#pragma unroll
  for (int rr = 0; rr < 16; ++rr) {
    int row = rr * 16 + srow;
    int gl = sg ^ (row & 7);
    async16(&Ks[row * 64 + sg * 8],
            kh + ((size_t)bh * 256 + row) * 64 + gl * 8);
  }
  int w = tid >> 6, l = tid & 63, lm = l & 15, lq = l >> 4;
  bf16x8 qf[2];
  {
    const ushort* qrow =
        qh + ((size_t)bh * 256 + strip * 32 + w * 16 + lm) * 64 + lq * 8;
    qf[0] = *(const bf16x8*)qrow;
    qf[1] = *(const bf16x8*)(qrow + 32);
  }
  if (tid < NB_) wbs[tid] = wb[tid * H_ + h];
  mfj[tid]       = (masks[b * 256 + tid] != 0) ? 1.f : 0.f;
  mfj[tid + 128] = (masks[b * 256 + tid + 128] != 0) ? 1.f : 0.f;
  __syncthreads();   // the only barrier

  f32x4 acc[16];
#pragma unroll
  for (int ct = 0; ct < 16; ++ct) {
    int krow = ct * 16 + lm;
    bf16x8 kf0 = *(const bf16x8*)&Ks[krow * 64 + ((lq) ^ (krow & 7)) * 8];
    bf16x8 kf1 = *(const bf16x8*)&Ks[krow * 64 + ((4 + lq) ^ (krow & 7)) * 8];
    f32x4 zf = (f32x4){0.f, 0.f, 0.f, 0.f};
    zf = __builtin_amdgcn_mfma_f32_16x16x32_bf16(qf[0], kf0, zf, 0, 0, 0);
    acc[ct] = __builtin_amdgcn_mfma_f32_16x16x32_bf16(qf[1], kf1, zf, 0, 0, 0);
  }
  int ibase = strip * 32 + w * 16 + lq * 4;
  float mfi[4];
#pragma unroll
  for (int r = 0; r < 4; ++r) mfi[r] = mfj[ibase + r];
#pragma unroll
  for (int ct = 0; ct < 16; ++ct) {
    int j = ct * 16 + lm;
    float mj = mfj[j];
#pragma unroll
    for (int r = 0; r < 4; ++r) {
      int i = ibase + r;
      int diff = i - j;
      int cb = diff < -K_ ? 0 : (diff > K_ ? 2 * K_ : diff + K_);
      float sq = mfi[r] * mj;
      acc[ct][r] = WL_ * (acc[ct][r] * 0.125f + wbs[cb] * sq) - 1e9f * (1.f - sq);
    }
  }
  float mx[4], sm[4];
#pragma unroll
  for (int r = 0; r < 4; ++r) {
    float m = acc[0][r];
#pragma unroll
    for (int ct = 1; ct < 16; ++ct) m = fmaxf(m, acc[ct][r]);
#pragma unroll
    for (int o = 1; o < 16; o <<= 1) m = fmaxf(m, __shfl_xor(m, o, 64));
    mx[r] = m;
  }
#pragma unroll
  for (int ct = 0; ct < 16; ++ct)
#pragma unroll
    for (int r = 0; r < 4; ++r) acc[ct][r] = __expf(acc[ct][r] - mx[r]);
#pragma unroll
  for (int r = 0; r < 4; ++r) {
    float s = 0.f;
#pragma unroll
    for (int ct = 0; ct < 16; ++ct) s += acc[ct][r];
#pragma unroll
    for (int o = 1; o < 16; o <<= 1) s += __shfl_xor(s, o, 64);
    sm[r] = 1.f / s;
  }
  // ---- a stores (f32) + o_pair into cat (bf16) ----
  float p0[4] = {0.f, 0.f, 0.f, 0.f}, p64[4] = {0.f, 0.f, 0.f, 0.f};
#pragma unroll
  for (int ct = 0; ct < 16; ++ct) {
    int j = ct * 16 + lm;
    float mj = mfj[j];
#pragma unroll
    for (int r = 0; r < 4; ++r) {
      int i = ibase + r;
      float aval = acc[ct][r] * sm[r];
      a_out[((size_t)bh * 256 + i) * 256 + j] = aval;
      float val = aval * mfi[r] * mj;
      int diff = i - j;
      if (diff <= -K_)      p0[r] += val;
      else if (diff >= K_)  p64[r] += val;
      else cat[((size_t)(b * 256 + i)) * 1088 + h * 65 + diff + K_] = f2bf(val);
    }
  }
#pragma unroll
  for (int r = 0; r < 4; ++r)
#pragma unroll
    for (int o = 1; o < 16; o <<= 1) {
      p0[r]  += __shfl_xor(p0[r], o, 64);
      p64[r] += __shfl_xor(p64[r], o, 64);
    }
  if (lm == 0) {
#pragma unroll
    for (int r = 0; r < 4; ++r) {
      int i = ibase + r;
      cat[((size_t)(b * 256 + i)) * 1088 + h * 65 + 0]      = f2bf(p0[r]);
      cat[((size_t)(b * 256 + i)) * 1088 + h * 65 + 2 * K_] = f2bf(p64[r]);
    }
  }
  // interior bins with out-of-range source j -> 0
#pragma unroll
  for (int r = 0; r < 4; ++r) {
    int i = ibase + r;
#pragma unroll
    for (int t = 0; t < 4; ++t) {
      int c = 1 + lm + 16 * t;
      if (c < 64) {
        int j = i - c + K_;
        if (j < 0 || j > 255)
          cat[((size_t)(b * 256 + i)) * 1088 + h * 65 + c] = 0;
      }
    }
  }
  // pad cols 1032..1088 zeroed by h==0 blocks
  if (h == 0) {
    for (int idx = tid; idx < 32 * 56; idx += 128) {
      int r = idx / 56, c = 1032 + (idx - r * 56);
      cat[((size_t)(b * 256 + strip * 32 + r)) * 1088 + c] = 0;
    }
  }
  // ---- PV: o = P @ V over 4 k-quarters; V frags direct from global ----
  f32x4 acc2[4];
#pragma unroll
  for (int nt = 0; nt < 4; ++nt) acc2[nt] = (f32x4){0.f, 0.f, 0.f, 0.f};
  const ushort* vbase = vT + (size_t)bh * 16384;
#pragma unroll
  for (int qt = 0; qt < 4; ++qt) {
    bf16x8 vf0[4], vf1[4];
#pragma unroll
    for (int nt = 0; nt < 4; ++nt) {
      const ushort* vrow = vbase + (size_t)(nt * 16 + lm) * 256 + qt * 64 + lq * 8;
      vf0[nt] = *(const bf16x8*)vrow;
      vf1[nt] = *(const bf16x8*)(vrow + 32);
    }
#pragma unroll
    for (int ctl = 0; ctl < 4; ++ctl) {
      int ct = qt * 4 + ctl;
#pragma unroll
      for (int r = 0; r < 4; ++r) {
        int rowl = w * 16 + lq * 4 + r;
        int g = ctl * 2 + (lm >> 3);
        Ps[rowl * 64 + ((g ^ (rowl & 7)) << 3) + (lm & 7)] =
            f2bf(acc[ct][r] * sm[r]);
      }
    }
    int prow = w * 16 + lm;
#pragma unroll
    for (int kst = 0; kst < 2; ++kst) {
      bf16x8 af = *(const bf16x8*)&Ps[prow * 64 + (((kst * 4 + lq) ^ (prow & 7)) << 3)];
#pragma unroll
      for (int nt = 0; nt < 4; ++nt)
        acc2[nt] = __builtin_amdgcn_mfma_f32_16x16x32_bf16(
            af, kst ? vf1[nt] : vf0[nt], acc2[nt], 0, 0, 0);
    }
  }
#pragma unroll
  for (int nt = 0; nt < 4; ++nt) {
    int d = nt * 16 + lm;
#pragma unroll
    for (int r = 0; r < 4; ++r) {
      int i = ibase + r;
      cat[((size_t)(b * 256 + i)) * 1088 + 520 + h * 64 + d] = f2bf(acc2[nt][r]);
    }
  }
}

// ---------------- out = LayerNorm(x1 + sum_s xp[s]) * g + b ---------------
// 128 threads, float4 per thread (512 cols).
__global__ __launch_bounds__(128) void ln_sum(
    const float* __restrict__ x1, const float* __restrict__ xp,
    int S, int stride, const float* __restrict__ g,
    const float* __restrict__ bta, float* __restrict__ out,
    __hip_bfloat16* __restrict__ out_bf) {
  __shared__ float redA[2], redB[2];
  int row = blockIdx.x, tid = threadIdx.x;
  size_t base = (size_t)row * 512;
  float4 v = *(const float4*)(x1 + base + tid * 4);
  for (int s = 0; s < S; ++s) {
    float4 p = *(const float4*)(xp + (size_t)s * stride + base + tid * 4);
    v.x += p.x; v.y += p.y; v.z += p.z; v.w += p.w;
  }
  float su = v.x + v.y + v.z + v.w;
  float sq = v.x * v.x + v.y * v.y + v.z * v.z + v.w * v.w;
#pragma unroll
  for (int o = 32; o > 0; o >>= 1) {
    su += __shfl_xor(su, o, 64);
    sq += __shfl_xor(sq, o, 64);
  }
  int w = tid >> 6;
  if ((tid & 63) == 0) { redA[w] = su; redB[w] = sq; }
  __syncthreads();
  su = redA[0] + redA[1]; sq = redB[0] + redB[1];
  float mean = su * (1.f / 512.f);
  float var = sq * (1.f / 512.f) - mean * mean;
  float inv = rsqrtf(var + 1e-5f);
  float4 gv = *(const float4*)(g + tid * 4);
  float4 bv = *(const float4*)(bta + tid * 4);
  float4 o4;
  o4.x = (v.x - mean) * inv * gv.x + bv.x;
  o4.y = (v.y - mean) * inv * gv.y + bv.y;
  o4.z = (v.z - mean) * inv * gv.z + bv.z;
  o4.w = (v.w - mean) * inv * gv.w + bv.w;
  *(float4*)(out + base + tid * 4) = o4;
  if (out_bf) {
    ushort pk[4] = {f2bf(o4.x), f2bf(o4.y), f2bf(o4.z), f2bf(o4.w)};
    *(uint2*)&((ushort*)out_bf)[base + tid * 4] = *(uint2*)pk;
  }
}

extern "C" void kernel_launch(void* const* d_in, const int* in_sizes, int n_in,
                              void* d_out, int out_size, void* d_ws, size_t ws_size,
                              hipStream_t stream) {
  const float* s     = (const float*)d_in[0];
  const int*   masks = (const int*)d_in[1];
  const float* wq = (const float*)d_in[2];
  const float* wk = (const float*)d_in[3];
  const float* wv = (const float*)d_in[4];
  const float* wb = (const float*)d_in[5];
  const float* wo = (const float*)d_in[6];
  const float* bo = (const float*)d_in[7];
  const float* ln1_g = (const float*)d_in[8];
  const float* ln1_b = (const float*)d_in[9];
  const float* w1 = (const float*)d_in[10];
  const float* b1 = (const float*)d_in[11];
  const float* w2 = (const float*)d_in[12];
  const float* b2 = (const float*)d_in[13];
  const float* ln2_g = (const float*)d_in[14];
  const float* ln2_b = (const float*)d_in[15];

  float* out_x = (float*)d_out;              // [8,256,512]
  float* out_a = out_x + 1048576;            // [8,8,256,256]

  // disjoint workspace (float offsets)
  float* ws = (float*)d_ws;
  float* embd_part = ws + 0;                               // [4][2048,512]
  float* xbuf      = ws + 4194304;
  float* ff_part   = ws + 5242880;                         // [4][2048,512]
  ushort* qkv_bf   = (ushort*)(ws + 9437184);              // q|k [B,H,N,D], v [B,H,D,N]
  ushort* q_bf = qkv_bf;
  ushort* k_bf = qkv_bf + 1048576;
  ushort* v_bf = qkv_bf + 2097152;
  ushort* cat_bf = (ushort*)(ws + 10223616);               // [2048,1088]
  __hip_bfloat16* h_bf  = (__hip_bfloat16*)(ws + 11337728);  // [2048,2048]
  __hip_bfloat16* s_bf  = (__hip_bfloat16*)(ws + 13434880);  // [2048,512]
  __hip_bfloat16* x_bf  = (__hip_bfloat16*)(ws + 13959168);  // [2048,512]
  __hip_bfloat16* wqkvT = (__hip_bfloat16*)(ws + 14483456);  // [1536,512]
  __hip_bfloat16* wopT  = (__hip_bfloat16*)(ws + 14876672);  // [512,1088]
  __hip_bfloat16* w1T   = (__hip_bfloat16*)(ws + 15155200);  // [2048,512]
  __hip_bfloat16* w2T   = (__hip_bfloat16*)(ws + 15679488);  // [512,2048]

  dim3 blk(256), blkg(128);
  // 0. prep: s cvt (512 blocks) + weight transposes (3360 blocks)
  prep_all<<<dim3(3872), blk, 0, stream>>>(s, s_bf, wq, wk, wv, wo, w1, w2,
                                           wqkvT, wopT, w1T, w2T);
  // 1. QKV projection -> bf16 head layout (q,k) + transposed v, coalesced
  gemm_bf16<<<dim3(12, 32, 1), blkg, 0, stream>>>(
      (const ushort*)s_bf, (const ushort*)wqkvT, nullptr, nullptr,
      qkv_bf, 2048, 1536, 512, 16);
  // 2. fused attention: a -> d_out, o + o_pair -> cat_bf  [512 x 128thr]
  attn_fused<<<dim3(512), blkg, 0, stream>>>(q_bf, k_bf, v_bf, masks, wb,
                                             out_a, cat_bf);
  // 3. output projection (split-K=4)  [512 blocks]
  gemm_bf16<<<dim3(4, 32, 4), blkg, 0, stream>>>(
      cat_bf, (const ushort*)wopT, bo, embd_part, nullptr,
      2048, 512, 1088, 1 | 8);
  // 4. x = LN(s + sum embd_part)
  ln_sum<<<dim3(2048), blkg, 0, stream>>>(s, embd_part, 4, 1048576,
                                          ln1_g, ln1_b, xbuf, x_bf);
  // 5. FFN  [512 blocks each]
  gemm_bf16<<<dim3(16, 32, 1), blkg, 0, stream>>>(
      (const ushort*)x_bf, (const ushort*)w1T, b1, nullptr, (ushort*)h_bf,
      2048, 2048, 512, 1 | 2 | 4);
  gemm_bf16<<<dim3(4, 32, 4), blkg, 0, stream>>>(
      (const ushort*)h_bf, (const ushort*)w2T, b2, ff_part, nullptr,
      2048, 512, 2048, 1 | 8);
  // 6. out = LN(x + sum ff_part)
  ln_sum<<<dim3(2048), blkg, 0, stream>>>(xbuf, ff_part, 4, 1048576,
                                          ln2_g, ln2_b, out_x, nullptr);
}

// Round 11
// 176.950 us; speedup vs baseline: 3.1704x; 1.0202x over previous
//
#include <hip/hip_runtime.h>
#include <hip/hip_bf16.h>
#include <cstdint>

#define B_ 8
#define N_ 256
#define CS_ 512
#define H_ 8
#define D_ 64
#define K_ 32
#define NB_ 65
#define CT_ 2048
#define WL_ 0.70710678118654752f

typedef __attribute__((ext_vector_type(8))) short bf16x8;
typedef __attribute__((ext_vector_type(4))) float f32x4;

#define GLOBAL_AS __attribute__((address_space(1)))
#define LDS_AS __attribute__((address_space(3)))

__device__ __forceinline__ void async16(void* lds, const void* g) {
  __builtin_amdgcn_global_load_lds((const GLOBAL_AS uint32_t*)g,
                                   (LDS_AS uint32_t*)lds, 16, 0, 0);
}

__device__ __forceinline__ ushort f2bf(float v) {
  __hip_bfloat16 hb = __float2bfloat16(v);
  return *(ushort*)&hb;
}

__device__ __forceinline__ float bf2f(ushort u) {
  union { uint32_t ui; float f; } cv; cv.ui = (uint32_t)u << 16;
  return cv.f;
}

// ---------------- bf16 MFMA GEMM: C[M,N] = A[M,K] @ Bt[N,K]^T -------------
// 64x128 tile, 128 threads (2 waves), double-buffered LDS. Split-K gridDim.z.
// flags: 1=+bias[col] (slice 0), 2=relu, 4=bf16 out via LDS-coalesced blast,
//        8=f32 out (offset z*M*Nc), 16=qkv scatter (col = which*512+h*64+d),
//        32=offset bf16 out by z*M*Nc (bf16 split-K partials).
__global__ __launch_bounds__(128) void gemm_bf16(
    const ushort* __restrict__ A, const ushort* __restrict__ Bt,
    const float* __restrict__ bias, float* __restrict__ C,
    ushort* __restrict__ Cb, int M, int Nc, int Kd, int flags) {
  __shared__ ushort As[2][64 * 64];    // 16 KB
  __shared__ ushort Bs[2][128 * 64];   // 32 KB (buf reused as epilogue bounce)
  int tid = threadIdx.x;
  int bm = blockIdx.y * 64, bn = blockIdx.x * 128;
  int S = gridDim.z, z = blockIdx.z;
  int T = Kd >> 6;
  int it0 = (z * T) / S, it1 = ((z + 1) * T) / S;
  if (flags & 8)  C  += (size_t)z * M * Nc;
  if (flags & 32) Cb += (size_t)z * M * Nc;
  int w = tid >> 6, l = tid & 63;
  int lm = l & 15, lq = l >> 4;
  int srow = tid >> 3;       // 0..15
  int sg = tid & 7;

  f32x4 acc[4][4];
#pragma unroll
  for (int i = 0; i < 4; ++i)
#pragma unroll
    for (int j = 0; j < 4; ++j) acc[i][j] = (f32x4){0.f, 0.f, 0.f, 0.f};

  // prologue: issue loads for first tile into buf 0
  {
    int k0 = it0 << 6;
#pragma unroll
    for (int r = 0; r < 4; ++r) {
      int row = r * 16 + srow;
      int gl = sg ^ (row & 7);
      async16(&As[0][row * 64 + sg * 8],
              A + (size_t)(bm + row) * Kd + k0 + gl * 8);
    }
#pragma unroll
    for (int r = 0; r < 8; ++r) {
      int row = r * 16 + srow;
      int gl = sg ^ (row & 7);
      async16(&Bs[0][row * 64 + sg * 8],
              Bt + (size_t)(bn + row) * Kd + k0 + gl * 8);
    }
  }
  for (int it = it0; it < it1; ++it) {
    int cur = (it - it0) & 1;
    __syncthreads();   // cur tile's loads complete; nxt buf's readers done
    if (it + 1 < it1) {
      int nxt = cur ^ 1;
      int k0 = (it + 1) << 6;
#pragma unroll
      for (int r = 0; r < 4; ++r) {
        int row = r * 16 + srow;
        int gl = sg ^ (row & 7);
        async16(&As[nxt][row * 64 + sg * 8],
                A + (size_t)(bm + row) * Kd + k0 + gl * 8);
      }
#pragma unroll
      for (int r = 0; r < 8; ++r) {
        int row = r * 16 + srow;
        int gl = sg ^ (row & 7);
        async16(&Bs[nxt][row * 64 + sg * 8],
                Bt + (size_t)(bn + row) * Kd + k0 + gl * 8);
      }
    }
#pragma unroll
    for (int kk = 0; kk < 2; ++kk) {
      bf16x8 af[4], bfr[4];
#pragma unroll
      for (int i = 0; i < 4; ++i) {
        int ma = 16 * i + lm;
        af[i] = *(const bf16x8*)&As[cur][ma * 64 + ((kk * 4 + lq) ^ (ma & 7)) * 8];
        int nb = w * 64 + 16 * i + lm;
        bfr[i] = *(const bf16x8*)&Bs[cur][nb * 64 + ((kk * 4 + lq) ^ (nb & 7)) * 8];
      }
#pragma unroll
      for (int i = 0; i < 4; ++i)
#pragma unroll
        for (int j = 0; j < 4; ++j)
          acc[i][j] = __builtin_amdgcn_mfma_f32_16x16x32_bf16(
              af[i], bfr[j], acc[i][j], 0, 0, 0);
    }
  }
  __syncthreads();   // all waves done with LDS before bounce reuse

  int bcol0 = bn + w * 64;          // this wave's 64-col base
  int lr = l >> 3, lc = l & 7;      // blast: 8 lanes per 128B row
  ushort* Tb = &Bs[0][w * 4096];    // wave-private 64x64 bounce (in-order DS)

  if (flags & 16) {                 // QKV head-layout epilogue
    int which = bcol0 >> 9;
    int hh = (bcol0 & 511) >> 6;
    int b = bm >> 8, nn0 = bm & 255;
    if (which == 2) {               // v: transpose to [d][n]
#pragma unroll
      for (int j = 0; j < 4; ++j)
#pragma unroll
        for (int i = 0; i < 4; ++i) {
          ushort pk[4];
#pragma unroll
          for (int r = 0; r < 4; ++r) pk[r] = f2bf(acc[i][j][r]);
          *(uint2*)&Tb[(16 * j + lm) * 64 + 16 * i + lq * 4] = *(uint2*)pk;
        }
    } else {                        // q,k: [n][d]
#pragma unroll
      for (int j = 0; j < 4; ++j)
#pragma unroll
        for (int i = 0; i < 4; ++i)
#pragma unroll
          for (int r = 0; r < 4; ++r)
            Tb[(16 * i + lq * 4 + r) * 64 + 16 * j + lm] = f2bf(acc[i][j][r]);
    }
    __asm__ __volatile__("" ::: "memory");
    ushort* dstb = Cb + (size_t)which * 1048576 + (size_t)(b * 8 + hh) * 16384;
#pragma unroll
    for (int p = 0; p < 8; ++p) {
      int rowL = p * 8 + lr;
      bf16x8 vv = *(const bf16x8*)&Tb[rowL * 64 + lc * 8];
      if (which == 2)
        *(bf16x8*)(dstb + (size_t)rowL * 256 + nn0 + lc * 8) = vv;
      else
        *(bf16x8*)(dstb + (size_t)(nn0 + rowL) * 64 + lc * 8) = vv;
    }
    return;
  }
  if (flags & 4) {                  // bf16 output: coalesced blast
#pragma unroll
    for (int j = 0; j < 4; ++j) {
      float bv = ((flags & 1) && z == 0) ? bias[bcol0 + 16 * j + lm] : 0.f;
#pragma unroll
      for (int i = 0; i < 4; ++i)
#pragma unroll
        for (int r = 0; r < 4; ++r) {
          float v = acc[i][j][r] + bv;
          if (flags & 2) v = fmaxf(v, 0.f);
          Tb[(16 * i + lq * 4 + r) * 64 + 16 * j + lm] = f2bf(v);
        }
    }
    __asm__ __volatile__("" ::: "memory");
#pragma unroll
    for (int p = 0; p < 8; ++p) {
      int rowL = p * 8 + lr;
      bf16x8 vv = *(const bf16x8*)&Tb[rowL * 64 + lc * 8];
      *(bf16x8*)(Cb + (size_t)(bm + rowL) * Nc + bcol0 + lc * 8) = vv;
    }
    return;
  }
  // f32 output (+bias, slice 0 only)
#pragma unroll
  for (int j = 0; j < 4; ++j) {
    int col = bcol0 + 16 * j + lm;
    float bv = ((flags & 1) && z == 0) ? bias[col] : 0.f;
#pragma unroll
    for (int i = 0; i < 4; ++i)
#pragma unroll
      for (int r = 0; r < 4; ++r) {
        int row = bm + 16 * i + lq * 4 + r;
        float v = acc[i][j][r] + bv;
        if (flags & 2) v = fmaxf(v, 0.f);
        C[(size_t)row * Nc + col] = v;
      }
  }
}

// ---------------- prep: s->bf16 + all weight transposes, one dispatch -----
__global__ __launch_bounds__(256) void prep_all(
    const float* __restrict__ s, __hip_bfloat16* __restrict__ s_bf,
    const float* __restrict__ wq, const float* __restrict__ wk,
    const float* __restrict__ wv, const float* __restrict__ wo,
    const float* __restrict__ w1, const float* __restrict__ w2,
    __hip_bfloat16* __restrict__ wqkvT, __hip_bfloat16* __restrict__ wopT,
    __hip_bfloat16* __restrict__ w1T, __hip_bfloat16* __restrict__ w2T) {
  int blk = blockIdx.x;
  if (blk < 512) {
    int i = blk * 256 + threadIdx.x;   // 131072 threads x 8 elems
    float4 a = ((const float4*)s)[i * 2];
    float4 c = ((const float4*)s)[i * 2 + 1];
    ushort pk[8] = {f2bf(a.x), f2bf(a.y), f2bf(a.z), f2bf(a.w),
                    f2bf(c.x), f2bf(c.y), f2bf(c.z), f2bf(c.w)};
    *(uint4*)&((ushort*)s_bf)[i * 8] = *(uint4*)pk;
    return;
  }
  blk -= 512;
  __shared__ float tile[32][33];
  const float* src;
  __hip_bfloat16* dst;
  int R, C, Kpad, tX, tIdx, whichBase = -1;
  if (blk < 768) {
    int zz = blk >> 8; tIdx = blk & 255;
    src = zz == 0 ? wq : zz == 1 ? wk : wv;
    dst = wqkvT; whichBase = zz * 512; R = 512; C = 512; Kpad = 512; tX = 16;
  } else if (blk < 1312) {
    tIdx = blk - 768; src = wo; dst = wopT; R = 1032; C = 512; Kpad = 1088; tX = 16;
  } else if (blk < 2336) {
    tIdx = blk - 1312; src = w1; dst = w1T; R = 512; C = 2048; Kpad = 512; tX = 64;
  } else {
    tIdx = blk - 2336; src = w2; dst = w2T; R = 2048; C = 512; Kpad = 2048; tX = 16;
  }
  int c0 = (tIdx % tX) * 32, r0 = (tIdx / tX) * 32;
  int tx = threadIdx.x & 31, ty = threadIdx.x >> 5;
#pragma unroll
  for (int yy = 0; yy < 32; yy += 8) {
    int r = r0 + ty + yy, c = c0 + tx;
    tile[ty + yy][tx] = (r < R && c < C) ? src[(size_t)r * C + c] : 0.f;
  }
  __syncthreads();
#pragma unroll
  for (int yy = 0; yy < 32; yy += 8) {
    int cc = c0 + ty + yy, k = r0 + tx;
    if (cc < C && k < Kpad) {
      int n = (whichBase >= 0) ? (whichBase + (cc & 7) * 64 + (cc >> 3)) : cc;
      dst[(size_t)n * Kpad + k] = __float2bfloat16(tile[tx][ty + yy]);
    }
  }
}

// ---------------- fused attention: QK^T+softmax -> a, PV -> o, o_pair -----
// 512 blocks = (bh:64) x (32-row strip:8), 128 threads; wave w owns 16 rows.
// ONE barrier; Q/V frags from global; P via wave-private 4 KB Ps.
__global__ __launch_bounds__(128) void attn_fused(
    const ushort* __restrict__ qh, const ushort* __restrict__ kh,
    const ushort* __restrict__ vT, const int* __restrict__ masks,
    const float* __restrict__ wb, float* __restrict__ a_out,
    ushort* __restrict__ cat) {
  int strip = blockIdx.x & 7, bh = blockIdx.x >> 3;
  int h = bh & 7, b = bh >> 3;
  __shared__ ushort Ks[256 * 64];   // 32 KB
  __shared__ ushort Ps[32 * 64];    // 4 KB, k-quarter P (wave-private rows)
  __shared__ float wbs[NB_];
  __shared__ float mfj[256];
  int tid = threadIdx.x;
  int srow = tid >> 3, sg = tid & 7;
#pragma unroll
  for (int rr = 0; rr < 16; ++rr) {
    int row = rr * 16 + srow;
    int gl = sg ^ (row & 7);
    async16(&Ks[row * 64 + sg * 8],
            kh + ((size_t)bh * 256 + row) * 64 + gl * 8);
  }
  int w = tid >> 6, l = tid & 63, lm = l & 15, lq = l >> 4;
  bf16x8 qf[2];
  {
    const ushort* qrow =
        qh + ((size_t)bh * 256 + strip * 32 + w * 16 + lm) * 64 + lq * 8;
    qf[0] = *(const bf16x8*)qrow;
    qf[1] = *(const bf16x8*)(qrow + 32);
  }
  if (tid < NB_) wbs[tid] = wb[tid * H_ + h];
  mfj[tid]       = (masks[b * 256 + tid] != 0) ? 1.f : 0.f;
  mfj[tid + 128] = (masks[b * 256 + tid + 128] != 0) ? 1.f : 0.f;
  __syncthreads();   // the only barrier

  f32x4 acc[16];
#pragma unroll
  for (int ct = 0; ct < 16; ++ct) {
    int krow = ct * 16 + lm;
    bf16x8 kf0 = *(const bf16x8*)&Ks[krow * 64 + ((lq) ^ (krow & 7)) * 8];
    bf16x8 kf1 = *(const bf16x8*)&Ks[krow * 64 + ((4 + lq) ^ (krow & 7)) * 8];
    f32x4 zf = (f32x4){0.f, 0.f, 0.f, 0.f};
    zf = __builtin_amdgcn_mfma_f32_16x16x32_bf16(qf[0], kf0, zf, 0, 0, 0);
    acc[ct] = __builtin_amdgcn_mfma_f32_16x16x32_bf16(qf[1], kf1, zf, 0, 0, 0);
  }
  int ibase = strip * 32 + w * 16 + lq * 4;
  float mfi[4];
#pragma unroll
  for (int r = 0; r < 4; ++r) mfi[r] = mfj[ibase + r];
#pragma unroll
  for (int ct = 0; ct < 16; ++ct) {
    int j = ct * 16 + lm;
    float mj = mfj[j];
#pragma unroll
    for (int r = 0; r < 4; ++r) {
      int i = ibase + r;
      int diff = i - j;
      int cb = diff < -K_ ? 0 : (diff > K_ ? 2 * K_ : diff + K_);
      float sq = mfi[r] * mj;
      acc[ct][r] = WL_ * (acc[ct][r] * 0.125f + wbs[cb] * sq) - 1e9f * (1.f - sq);
    }
  }
  float mx[4], sm[4];
#pragma unroll
  for (int r = 0; r < 4; ++r) {
    float m = acc[0][r];
#pragma unroll
    for (int ct = 1; ct < 16; ++ct) m = fmaxf(m, acc[ct][r]);
#pragma unroll
    for (int o = 1; o < 16; o <<= 1) m = fmaxf(m, __shfl_xor(m, o, 64));
    mx[r] = m;
  }
#pragma unroll
  for (int ct = 0; ct < 16; ++ct)
#pragma unroll
    for (int r = 0; r < 4; ++r) acc[ct][r] = __expf(acc[ct][r] - mx[r]);
#pragma unroll
  for (int r = 0; r < 4; ++r) {
    float s = 0.f;
#pragma unroll
    for (int ct = 0; ct < 16; ++ct) s += acc[ct][r];
#pragma unroll
    for (int o = 1; o < 16; o <<= 1) s += __shfl_xor(s, o, 64);
    sm[r] = 1.f / s;
  }
  // ---- a stores (f32) + o_pair into cat (bf16) ----
  float p0[4] = {0.f, 0.f, 0.f, 0.f}, p64[4] = {0.f, 0.f, 0.f, 0.f};
#pragma unroll
  for (int ct = 0; ct < 16; ++ct) {
    int j = ct * 16 + lm;
    float mj = mfj[j];
#pragma unroll
    for (int r = 0; r < 4; ++r) {
      int i = ibase + r;
      float aval = acc[ct][r] * sm[r];
      a_out[((size_t)bh * 256 + i) * 256 + j] = aval;
      float val = aval * mfi[r] * mj;
      int diff = i - j;
      if (diff <= -K_)      p0[r] += val;
      else if (diff >= K_)  p64[r] += val;
      else cat[((size_t)(b * 256 + i)) * 1088 + h * 65 + diff + K_] = f2bf(val);
    }
  }
#pragma unroll
  for (int r = 0; r < 4; ++r)
#pragma unroll
    for (int o = 1; o < 16; o <<= 1) {
      p0[r]  += __shfl_xor(p0[r], o, 64);
      p64[r] += __shfl_xor(p64[r], o, 64);
    }
  if (lm == 0) {
#pragma unroll
    for (int r = 0; r < 4; ++r) {
      int i = ibase + r;
      cat[((size_t)(b * 256 + i)) * 1088 + h * 65 + 0]      = f2bf(p0[r]);
      cat[((size_t)(b * 256 + i)) * 1088 + h * 65 + 2 * K_] = f2bf(p64[r]);
    }
  }
  // interior bins with out-of-range source j -> 0
#pragma unroll
  for (int r = 0; r < 4; ++r) {
    int i = ibase + r;
#pragma unroll
    for (int t = 0; t < 4; ++t) {
      int c = 1 + lm + 16 * t;
      if (c < 64) {
        int j = i - c + K_;
        if (j < 0 || j > 255)
          cat[((size_t)(b * 256 + i)) * 1088 + h * 65 + c] = 0;
      }
    }
  }
  // pad cols 1032..1088 zeroed by h==0 blocks
  if (h == 0) {
    for (int idx = tid; idx < 32 * 56; idx += 128) {
      int r = idx / 56, c = 1032 + (idx - r * 56);
      cat[((size_t)(b * 256 + strip * 32 + r)) * 1088 + c] = 0;
    }
  }
  // ---- PV: o = P @ V over 4 k-quarters; V frags direct from global ----
  f32x4 acc2[4];
#pragma unroll
  for (int nt = 0; nt < 4; ++nt) acc2[nt] = (f32x4){0.f, 0.f, 0.f, 0.f};
  const ushort* vbase = vT + (size_t)bh * 16384;
#pragma unroll
  for (int qt = 0; qt < 4; ++qt) {
    bf16x8 vf0[4], vf1[4];
#pragma unroll
    for (int nt = 0; nt < 4; ++nt) {
      const ushort* vrow = vbase + (size_t)(nt * 16 + lm) * 256 + qt * 64 + lq * 8;
      vf0[nt] = *(const bf16x8*)vrow;
      vf1[nt] = *(const bf16x8*)(vrow + 32);
    }
#pragma unroll
    for (int ctl = 0; ctl < 4; ++ctl) {
      int ct = qt * 4 + ctl;
#pragma unroll
      for (int r = 0; r < 4; ++r) {
        int rowl = w * 16 + lq * 4 + r;
        int g = ctl * 2 + (lm >> 3);
        Ps[rowl * 64 + ((g ^ (rowl & 7)) << 3) + (lm & 7)] =
            f2bf(acc[ct][r] * sm[r]);
      }
    }
    int prow = w * 16 + lm;
#pragma unroll
    for (int kst = 0; kst < 2; ++kst) {
      bf16x8 af = *(const bf16x8*)&Ps[prow * 64 + (((kst * 4 + lq) ^ (prow & 7)) << 3)];
#pragma unroll
      for (int nt = 0; nt < 4; ++nt)
        acc2[nt] = __builtin_amdgcn_mfma_f32_16x16x32_bf16(
            af, kst ? vf1[nt] : vf0[nt], acc2[nt], 0, 0, 0);
    }
  }
#pragma unroll
  for (int nt = 0; nt < 4; ++nt) {
    int d = nt * 16 + lm;
#pragma unroll
    for (int r = 0; r < 4; ++r) {
      int i = ibase + r;
      cat[((size_t)(b * 256 + i)) * 1088 + 520 + h * 64 + d] = f2bf(acc2[nt][r]);
    }
  }
}

// ---------------- out = LayerNorm(x1 + sum_s xp_bf16[s]) * g + b ----------
// 128 threads, float4 per thread (512 cols); partials are bf16.
__global__ __launch_bounds__(128) void ln_sum(
    const float* __restrict__ x1, const ushort* __restrict__ xp,
    int S, int stride, const float* __restrict__ g,
    const float* __restrict__ bta, float* __restrict__ out,
    __hip_bfloat16* __restrict__ out_bf) {
  __shared__ float redA[2], redB[2];
  int row = blockIdx.x, tid = threadIdx.x;
  size_t base = (size_t)row * 512;
  float4 v = *(const float4*)(x1 + base + tid * 4);
  for (int s = 0; s < S; ++s) {
    uint2 p = *(const uint2*)(xp + (size_t)s * stride + base + tid * 4);
    v.x += bf2f((ushort)(p.x & 0xffff));
    v.y += bf2f((ushort)(p.x >> 16));
    v.z += bf2f((ushort)(p.y & 0xffff));
    v.w += bf2f((ushort)(p.y >> 16));
  }
  float su = v.x + v.y + v.z + v.w;
  float sq = v.x * v.x + v.y * v.y + v.z * v.z + v.w * v.w;
#pragma unroll
  for (int o = 32; o > 0; o >>= 1) {
    su += __shfl_xor(su, o, 64);
    sq += __shfl_xor(sq, o, 64);
  }
  int w = tid >> 6;
  if ((tid & 63) == 0) { redA[w] = su; redB[w] = sq; }
  __syncthreads();
  su = redA[0] + redA[1]; sq = redB[0] + redB[1];
  float mean = su * (1.f / 512.f);
  float var = sq * (1.f / 512.f) - mean * mean;
  float inv = rsqrtf(var + 1e-5f);
  float4 gv = *(const float4*)(g + tid * 4);
  float4 bv = *(const float4*)(bta + tid * 4);
  float4 o4;
  o4.x = (v.x - mean) * inv * gv.x + bv.x;
  o4.y = (v.y - mean) * inv * gv.y + bv.y;
  o4.z = (v.z - mean) * inv * gv.z + bv.z;
  o4.w = (v.w - mean) * inv * gv.w + bv.w;
  *(float4*)(out + base + tid * 4) = o4;
  if (out_bf) {
    ushort pk[4] = {f2bf(o4.x), f2bf(o4.y), f2bf(o4.z), f2bf(o4.w)};
    *(uint2*)&((ushort*)out_bf)[base + tid * 4] = *(uint2*)pk;
  }
}

extern "C" void kernel_launch(void* const* d_in, const int* in_sizes, int n_in,
                              void* d_out, int out_size, void* d_ws, size_t ws_size,
                              hipStream_t stream) {
  const float* s     = (const float*)d_in[0];
  const int*   masks = (const int*)d_in[1];
  const float* wq = (const float*)d_in[2];
  const float* wk = (const float*)d_in[3];
  const float* wv = (const float*)d_in[4];
  const float* wb = (const float*)d_in[5];
  const float* wo = (const float*)d_in[6];
  const float* bo = (const float*)d_in[7];
  const float* ln1_g = (const float*)d_in[8];
  const float* ln1_b = (const float*)d_in[9];
  const float* w1 = (const float*)d_in[10];
  const float* b1 = (const float*)d_in[11];
  const float* w2 = (const float*)d_in[12];
  const float* b2 = (const float*)d_in[13];
  const float* ln2_g = (const float*)d_in[14];
  const float* ln2_b = (const float*)d_in[15];

  float* out_x = (float*)d_out;              // [8,256,512]
  float* out_a = out_x + 1048576;            // [8,8,256,256]

  // disjoint workspace (float offsets)
  float* ws = (float*)d_ws;
  ushort* embd_part = (ushort*)(ws + 0);                   // [4][2048,512] bf16
  float* xbuf       = ws + 4194304;
  ushort* ff_part   = (ushort*)(ws + 5242880);             // [4][2048,512] bf16
  ushort* qkv_bf    = (ushort*)(ws + 9437184);             // q|k [B,H,N,D], v [B,H,D,N]
  ushort* q_bf = qkv_bf;
  ushort* k_bf = qkv_bf + 1048576;
  ushort* v_bf = qkv_bf + 2097152;
  ushort* cat_bf = (ushort*)(ws + 10223616);               // [2048,1088]
  __hip_bfloat16* h_bf  = (__hip_bfloat16*)(ws + 11337728);  // [2048,2048]
  __hip_bfloat16* s_bf  = (__hip_bfloat16*)(ws + 13434880);  // [2048,512]
  __hip_bfloat16* x_bf  = (__hip_bfloat16*)(ws + 13959168);  // [2048,512]
  __hip_bfloat16* wqkvT = (__hip_bfloat16*)(ws + 14483456);  // [1536,512]
  __hip_bfloat16* wopT  = (__hip_bfloat16*)(ws + 14876672);  // [512,1088]
  __hip_bfloat16* w1T   = (__hip_bfloat16*)(ws + 15155200);  // [2048,512]
  __hip_bfloat16* w2T   = (__hip_bfloat16*)(ws + 15679488);  // [512,2048]

  dim3 blk(256), blkg(128);
  // 0. prep: s cvt (512 blocks) + weight transposes (3360 blocks)
  prep_all<<<dim3(3872), blk, 0, stream>>>(s, s_bf, wq, wk, wv, wo, w1, w2,
                                           wqkvT, wopT, w1T, w2T);
  // 1. QKV projection -> bf16 head layout (q,k) + transposed v, coalesced
  gemm_bf16<<<dim3(12, 32, 1), blkg, 0, stream>>>(
      (const ushort*)s_bf, (const ushort*)wqkvT, nullptr, nullptr,
      qkv_bf, 2048, 1536, 512, 16);
  // 2. fused attention: a -> d_out, o + o_pair -> cat_bf  [512 x 128thr]
  attn_fused<<<dim3(512), blkg, 0, stream>>>(q_bf, k_bf, v_bf, masks, wb,
                                             out_a, cat_bf);
  // 3. output projection (split-K=4, bf16 partials)  [512 blocks]
  gemm_bf16<<<dim3(4, 32, 4), blkg, 0, stream>>>(
      cat_bf, (const ushort*)wopT, bo, nullptr, embd_part,
      2048, 512, 1088, 1 | 4 | 32);
  // 4. x = LN(s + sum embd_part)
  ln_sum<<<dim3(2048), blkg, 0, stream>>>(s, embd_part, 4, 1048576,
                                          ln1_g, ln1_b, xbuf, x_bf);
  // 5. FFN  [512 blocks each]
  gemm_bf16<<<dim3(16, 32, 1), blkg, 0, stream>>>(
      (const ushort*)x_bf, (const ushort*)w1T, b1, nullptr, (ushort*)h_bf,
      2048, 2048, 512, 1 | 2 | 4);
  gemm_bf16<<<dim3(4, 32, 4), blkg, 0, stream>>>(
      (const ushort*)h_bf, (const ushort*)w2T, b2, nullptr, ff_part,
      2048, 512, 2048, 1 | 4 | 32);
  // 6. out = LN(x + sum ff_part)
  ln_sum<<<dim3(2048), blkg, 0, stream>>>(xbuf, ff_part, 4, 1048576,
                                          ln2_g, ln2_b, out_x, nullptr);
}